// Round 11
// baseline (1429.029 us; speedup 1.0000x reference)
//
#include <hip/hip_runtime.h>
#include <math.h>

#define BB 64
#define EMB 256
#define N0 1023
#define N1 513
#define NTOK0 (BB * N0)   // 65472
#define NTOK1 (BB * N1)   // 32832
#define GCH 16            // gather chunks per batch

__device__ __forceinline__ float gelu_f(float x) {
    return 0.5f * x * (1.0f + erff(x * 0.7071067811865476f));
}

__device__ __forceinline__ float4 gelu4(float4 v) {
    return make_float4(gelu_f(v.x), gelu_f(v.y), gelu_f(v.z), gelu_f(v.w));
}

__device__ __forceinline__ float wave_reduce(float v) {
#pragma unroll
    for (int o = 32; o > 0; o >>= 1) v += __shfl_down(v, o, 64);
    return v;
}

// ---------------- fused weight transposes: in[o][ik] -> out[ik*O + o] ----------------
__global__ void transpose_fused(const float* __restrict__ embw, float* __restrict__ wtE,
                                const float* __restrict__ bott, float* __restrict__ bwt0,
                                float* __restrict__ bwt1,
                                const float* __restrict__ mpw, float* __restrict__ mwt0,
                                float* __restrict__ mwt1,
                                const float* __restrict__ cw39, float* __restrict__ c39t0,
                                float* __restrict__ c39t1,
                                const float* __restrict__ cw19, float* __restrict__ c19t0,
                                float* __restrict__ c19t1,
                                const float* __restrict__ cw9, float* __restrict__ c9t0,
                                float* __restrict__ c9t1) {
    int idx = blockIdx.x * 256 + threadIdx.x;
    const float* src; float* dst; int O, IK, base;
    if (idx < 32768)       { src = embw;         dst = wtE;   O = 256; IK = 128;  base = 0; }
    else if (idx < 40960)  { src = bott;         dst = bwt0;  O = 32;  IK = 256;  base = 32768; }
    else if (idx < 49152)  { src = bott + 8192;  dst = bwt1;  O = 32;  IK = 256;  base = 40960; }
    else if (idx < 57344)  { src = mpw;          dst = mwt0;  O = 32;  IK = 256;  base = 49152; }
    else if (idx < 65536)  { src = mpw + 8192;   dst = mwt1;  O = 32;  IK = 256;  base = 57344; }
    else if (idx < 105472) { src = cw39;         dst = c39t0; O = 32;  IK = 1248; base = 65536; }
    else if (idx < 145408) { src = cw39 + 39936; dst = c39t1; O = 32;  IK = 1248; base = 105472; }
    else if (idx < 164864) { src = cw19;         dst = c19t0; O = 32;  IK = 608;  base = 145408; }
    else if (idx < 184320) { src = cw19 + 19456; dst = c19t1; O = 32;  IK = 608;  base = 164864; }
    else if (idx < 193536) { src = cw9;          dst = c9t0;  O = 32;  IK = 288;  base = 184320; }
    else if (idx < 202752) { src = cw9 + 9216;   dst = c9t1;  O = 32;  IK = 288;  base = 193536; }
    else return;
    int local = idx - base;
    int o = local / IK, ik = local % IK;
    dst[ik * O + o] = src[local];
}

// ---------------- zero accumulators ----------------
__global__ void zero_kernel(float* __restrict__ imp, int* __restrict__ counts) {
    int i = threadIdx.x;
    if (i < 4) { imp[i] = 0.0f; counts[i] = 0; }
}

// ---------------- embedding conv (stride 4, K=8, C=16) + bias + pos ----------------
__global__ void embed_kernel(const float* __restrict__ x, const float* __restrict__ wt,
                             const float* __restrict__ emb_b, const float* __restrict__ pos,
                             float* __restrict__ A) {
    int b = blockIdx.y;
    int n0 = blockIdx.x * 16;
    __shared__ float xl[16][68];
    int l0 = 4 * n0;
    for (int idx = threadIdx.x; idx < 16 * 68; idx += 256) {
        int c = idx / 68, j = idx % 68;
        int l = l0 + j;
        xl[c][j] = (l < 4096) ? x[((size_t)b * 16 + c) * 4096 + l] : 0.0f;
    }
    __syncthreads();
    int e = threadIdx.x;
    float acc[16];
#pragma unroll
    for (int i = 0; i < 16; i++) acc[i] = 0.0f;
    for (int k = 0; k < 128; k++) {
        float w = wt[k * 256 + e];
        int c = k >> 3, s = k & 7;
#pragma unroll
        for (int i = 0; i < 16; i++) acc[i] += xl[c][4 * i + s] * w;
    }
    float bb = emb_b[e];
    for (int i = 0; i < 16; i++) {
        int n = n0 + i;
        if (n < N0)
            A[((size_t)b * N0 + n) * 256 + e] = acc[i] + bb + pos[(size_t)n * 256 + e];
    }
}

// ---------------- wave-per-token: rmsnorm + attn score (+pregelu, +second norm) ------
__global__ void norm_attn_kernel(const float* __restrict__ in, float* __restrict__ outv,
                                 float* __restrict__ score_out, const float* __restrict__ g,
                                 const float* __restrict__ w1, const float* __restrict__ b1,
                                 const float* __restrict__ w2, const float* __restrict__ b2,
                                 int scale_out, int pregelu,
                                 float* __restrict__ outv2, const float* __restrict__ g2,
                                 int T) {
    int wid = threadIdx.x >> 6, lane = threadIdx.x & 63;
    int t = blockIdx.x * 4 + wid;
    if (t >= T) return;
    float4 v = ((const float4*)(in + (size_t)t * 256))[lane];
    if (pregelu) v = gelu4(v);
    float4 xn = v;
    if (g != nullptr) {
        float ss = v.x * v.x + v.y * v.y + v.z * v.z + v.w * v.w;
        ss = wave_reduce(ss);
        ss = __shfl(ss, 0, 64);
        float inv = 16.0f / fmaxf(sqrtf(ss), 1e-12f);
        float4 g4 = ((const float4*)g)[lane];
        xn.x = v.x * inv * g4.x; xn.y = v.y * inv * g4.y;
        xn.z = v.z * inv * g4.z; xn.w = v.w * inv * g4.w;
    }
    float p[8];
#pragma unroll
    for (int j = 0; j < 8; j++) p[j] = 0.0f;
    const float xv[4] = {xn.x, xn.y, xn.z, xn.w};
#pragma unroll
    for (int c = 0; c < 4; c++) {
        const float4* wr = (const float4*)(w1 + (4 * lane + c) * 8);
        float4 wa = wr[0], wb = wr[1];
        float xx = xv[c];
        p[0] += xx * wa.x; p[1] += xx * wa.y; p[2] += xx * wa.z; p[3] += xx * wa.w;
        p[4] += xx * wb.x; p[5] += xx * wb.y; p[6] += xx * wb.z; p[7] += xx * wb.w;
    }
#pragma unroll
    for (int j = 0; j < 8; j++) p[j] = wave_reduce(p[j]);
    float sc = 0.0f;
    if (lane == 0) {
        float z = b2[0];
#pragma unroll
        for (int j = 0; j < 8; j++) z += tanhf(p[j] + b1[j]) * w2[j];
        sc = 1.0f / (1.0f + expf(-z));
        if (score_out) score_out[t] = sc;
    }
    sc = __shfl(sc, 0, 64);
    if (outv) {
        float m = scale_out ? sc : 1.0f;
        float4 o = make_float4(xn.x * m, xn.y * m, xn.z * m, xn.w * m);
        ((float4*)(outv + (size_t)t * 256))[lane] = o;
    }
    if (outv2) {
        float ss2 = xn.x * xn.x + xn.y * xn.y + xn.z * xn.z + xn.w * xn.w;
        ss2 = wave_reduce(ss2);
        ss2 = __shfl(ss2, 0, 64);
        float inv2 = 16.0f / fmaxf(sqrtf(ss2), 1e-12f);
        float4 q4 = ((const float4*)g2)[lane];
        float4 o;
        o.x = xn.x * inv2 * q4.x; o.y = xn.y * inv2 * q4.y;
        o.z = xn.z * inv2 * q4.z; o.w = xn.w * inv2 * q4.w;
        ((float4*)(outv2 + (size_t)t * 256))[lane] = o;
    }
}

// ---------------- wave-per-token rmsnorm ----------------
__global__ void rmsnorm_kernel(const float* __restrict__ in, float* __restrict__ out,
                               const float* __restrict__ g, int T) {
    int wid = threadIdx.x >> 6, lane = threadIdx.x & 63;
    int t = blockIdx.x * 4 + wid;
    if (t >= T) return;
    float4 v = ((const float4*)(in + (size_t)t * 256))[lane];
    float ss = v.x * v.x + v.y * v.y + v.z * v.z + v.w * v.w;
    ss = wave_reduce(ss);
    ss = __shfl(ss, 0, 64);
    float inv = 16.0f / fmaxf(sqrtf(ss), 1e-12f);
    float4 g4 = ((const float4*)g)[lane];
    float4 o;
    o.x = v.x * inv * g4.x; o.y = v.y * inv * g4.y;
    o.z = v.z * inv * g4.z; o.w = v.w * inv * g4.w;
    ((float4*)(out + (size_t)t * 256))[lane] = o;
}

// ---------------- pointwise: bottleneck + maxpool path (round-5 proven version) -------
__global__ void pw_kernel(const float* __restrict__ xn, const float* __restrict__ bwt,
                          const float* __restrict__ mwt, const float* __restrict__ bng,
                          const float* __restrict__ bnb, float* __restrict__ xb,
                          float* __restrict__ cat, int N) {
    int b = blockIdx.y;
    int t0 = blockIdx.x * 16;
    const float* xbase = xn + (size_t)b * N * 256;
    __shared__ float xt[18][256];
    __shared__ float xm[16][256];
    for (int idx = threadIdx.x; idx < 18 * 256; idx += 256) {
        int r = idx >> 8, d = idx & 255;
        int t = t0 + r - 1;
        xt[r][d] = (t >= 0 && t < N) ? xbase[(size_t)t * 256 + d] : -INFINITY;
    }
    __syncthreads();
    for (int idx = threadIdx.x; idx < 16 * 256; idx += 256) {
        int r = idx >> 8, d = idx & 255;
        xm[r][d] = fmaxf(fmaxf(xt[r][d], xt[r + 1][d]), xt[r + 2][d]);
    }
    __syncthreads();
    int f = threadIdx.x & 31;
    int gI = threadIdx.x >> 5;
    float accb[2] = {0.0f, 0.0f}, accm[2] = {0.0f, 0.0f};
    for (int d0 = 0; d0 < 256; d0++) {
        float wb = bwt[d0 * 32 + f];
        float wm = mwt[d0 * 32 + f];
#pragma unroll
        for (int i = 0; i < 2; i++) {
            int tt = gI * 2 + i;
            accb[i] += xt[1 + tt][d0] * wb;
            accm[i] += xm[tt][d0] * wm;
        }
    }
    const float BN_DIV = 1.0000050f;
    float scl = bng[96 + f] / BN_DIV;
    float sh = bnb[96 + f];
    for (int i = 0; i < 2; i++) {
        int t = t0 + gI * 2 + i;
        if (t < N) {
            xb[((size_t)b * N + t) * 32 + f] = accb[i];
            cat[((size_t)b * N + t) * 128 + 96 + f] = gelu_f(accm[i] * scl + sh);
        }
    }
}

// ---------------- time conv: 128 tokens/block, 4 f-cols x 4 tokens per thread ---------
template <int K, int P, int COFF>
__global__ void conv_kernel(const float* __restrict__ xb, const float* __restrict__ wt,
                            const float* __restrict__ bng, const float* __restrict__ bnb,
                            float* __restrict__ cat, int N) {
    int b = blockIdx.y;
    int t0 = blockIdx.x * 128;
    const float* xbase = xb + (size_t)b * N * 32;
    const int ROWS = 128 + K;
    __shared__ float xl[ROWS][33];
    for (int idx = threadIdx.x; idx < ROWS * 32; idx += 256) {
        int r = idx >> 5, f = idx & 31;
        int t = t0 - P + r;
        xl[r][f] = (t >= 0 && t < N) ? xbase[(size_t)t * 32 + f] : 0.0f;
    }
    __syncthreads();
    int fg = threadIdx.x & 7;
    int tg = threadIdx.x >> 3;
    float acc[4][4];
#pragma unroll
    for (int j = 0; j < 4; j++)
#pragma unroll
        for (int c = 0; c < 4; c++) acc[j][c] = 0.0f;
    for (int fi = 0; fi < 32; fi++) {
        float win[4];
#pragma unroll
        for (int j = 0; j < 4; j++) win[j] = xl[tg * 4 + j][fi];
#pragma unroll
        for (int k = 0; k < K; k++) {
            float4 w = ((const float4*)(wt + (fi * K + k) * 32))[fg];
#pragma unroll
            for (int j = 0; j < 4; j++) {
                float xv = win[j];
                acc[j][0] += xv * w.x; acc[j][1] += xv * w.y;
                acc[j][2] += xv * w.z; acc[j][3] += xv * w.w;
            }
#pragma unroll
            for (int j = 0; j < 3; j++) win[j] = win[j + 1];
            win[3] = xl[tg * 4 + k + 4][fi];
        }
    }
    const float BN_DIV = 1.0000050f;
    float4 g4 = ((const float4*)(bng + COFF))[fg];
    float4 b4 = ((const float4*)(bnb + COFF))[fg];
    float sx = g4.x / BN_DIV, sy = g4.y / BN_DIV, sz = g4.z / BN_DIV, sw = g4.w / BN_DIV;
#pragma unroll
    for (int j = 0; j < 4; j++) {
        int t = t0 + tg * 4 + j;
        if (t < N) {
            float4 o;
            o.x = gelu_f(acc[j][0] * sx + b4.x);
            o.y = gelu_f(acc[j][1] * sy + b4.y);
            o.z = gelu_f(acc[j][2] * sz + b4.z);
            o.w = gelu_f(acc[j][3] * sw + b4.w);
            ((float4*)(cat + ((size_t)b * N + t) * 128 + COFF))[fg] = o;
        }
    }
}

// ---------------- proj: 32 tokens/block, 8 tok x 4 cols per thread,
// weights LDS-staged (64 rows x 2 stages) so each block reads pw from global ONCE ------
__global__ __launch_bounds__(256, 2)
void proj_kernel(const float* __restrict__ cat, const float* __restrict__ pw,
                 const float* __restrict__ pb, float* __restrict__ A, int TN) {
    int t0 = blockIdx.x * 32;
    __shared__ float cl[32][128];   // 16 KB tokens
    __shared__ float ws[64][256];   // 64 KB weight stage
    for (int v = threadIdx.x; v < 32 * 32; v += 256) {
        int r = v >> 5, c4 = v & 31;
        int t = t0 + r;
        ((float4*)cl[r])[c4] = (t < TN) ? ((const float4*)(cat + (size_t)t * 128))[c4]
                                        : make_float4(0.f, 0.f, 0.f, 0.f);
    }
    int c0 = threadIdx.x & 63;
    int g = threadIdx.x >> 6;
    float acc[8][4];
#pragma unroll
    for (int i = 0; i < 8; i++)
#pragma unroll
        for (int j = 0; j < 4; j++) acc[i][j] = 0.0f;
    for (int s = 0; s < 128; s += 64) {
        __syncthreads();  // cl ready (1st iter) / previous stage consumed (2nd)
        for (int v = threadIdx.x; v < 64 * 64; v += 256) {
            int r = v >> 6, c4 = v & 63;
            ((float4*)ws[r])[c4] = ((const float4*)(pw + (size_t)(s + r) * 256))[c4];
        }
        __syncthreads();
        for (int f = 0; f < 64; f++) {
            float4 w = ((const float4*)ws[f])[c0];
            float v0 = cl[g * 8 + 0][s + f], v1 = cl[g * 8 + 1][s + f];
            float v2 = cl[g * 8 + 2][s + f], v3 = cl[g * 8 + 3][s + f];
            float v4 = cl[g * 8 + 4][s + f], v5 = cl[g * 8 + 5][s + f];
            float v6 = cl[g * 8 + 6][s + f], v7 = cl[g * 8 + 7][s + f];
            acc[0][0] += v0 * w.x; acc[0][1] += v0 * w.y; acc[0][2] += v0 * w.z; acc[0][3] += v0 * w.w;
            acc[1][0] += v1 * w.x; acc[1][1] += v1 * w.y; acc[1][2] += v1 * w.z; acc[1][3] += v1 * w.w;
            acc[2][0] += v2 * w.x; acc[2][1] += v2 * w.y; acc[2][2] += v2 * w.z; acc[2][3] += v2 * w.w;
            acc[3][0] += v3 * w.x; acc[3][1] += v3 * w.y; acc[3][2] += v3 * w.z; acc[3][3] += v3 * w.w;
            acc[4][0] += v4 * w.x; acc[4][1] += v4 * w.y; acc[4][2] += v4 * w.z; acc[4][3] += v4 * w.w;
            acc[5][0] += v5 * w.x; acc[5][1] += v5 * w.y; acc[5][2] += v5 * w.z; acc[5][3] += v5 * w.w;
            acc[6][0] += v6 * w.x; acc[6][1] += v6 * w.y; acc[6][2] += v6 * w.z; acc[6][3] += v6 * w.w;
            acc[7][0] += v7 * w.x; acc[7][1] += v7 * w.y; acc[7][2] += v7 * w.z; acc[7][3] += v7 * w.w;
        }
    }
    float4 bias = ((const float4*)pb)[c0];
#pragma unroll
    for (int i = 0; i < 8; i++) {
        int t = t0 + g * 8 + i;
        if (t < TN) {
            float4* ap = (float4*)(A + (size_t)t * 256) + c0;
            float4 a = *ap;
            a.x += acc[i][0] + bias.x; a.y += acc[i][1] + bias.y;
            a.z += acc[i][2] + bias.z; a.w += acc[i][3] + bias.w;
            *ap = a;
        }
    }
}

// ---------------- top-512-of-1023 per batch ----------------
__global__ __launch_bounds__(1024) void topk_kernel(const float* __restrict__ s,
                                                    int* __restrict__ selpos) {
    int b = blockIdx.x;
    int tid = threadIdx.x;
    __shared__ float srt[1024];
    __shared__ int buf[1024];
    __shared__ int Gtot_s;
    float val = (tid < N0) ? s[(size_t)b * N0 + tid] : -INFINITY;
    srt[tid] = val;
    __syncthreads();
    for (int ksz = 2; ksz <= 1024; ksz <<= 1) {
        for (int j = ksz >> 1; j > 0; j >>= 1) {
            int ixj = tid ^ j;
            if (ixj > tid) {
                float a = srt[tid], c = srt[ixj];
                bool up = ((tid & ksz) == 0);
                if ((a > c) == up) { srt[tid] = c; srt[ixj] = a; }
            }
            __syncthreads();
        }
    }
    float thr = srt[512];
    __syncthreads();
    int isG = (val > thr) ? 1 : 0;
    int isE = (val == thr) ? 1 : 0;
    buf[tid] = isG;
    __syncthreads();
    for (int off = 1; off < 1024; off <<= 1) {
        int cur = buf[tid];
        int add = (tid >= off) ? buf[tid - off] : 0;
        __syncthreads();
        buf[tid] = cur + add;
        __syncthreads();
    }
    if (tid == 0) Gtot_s = buf[1023];
    __syncthreads();
    int Gtot = Gtot_s;
    int Eneed = 512 - Gtot;
    buf[tid] = isE;
    __syncthreads();
    for (int off = 1; off < 1024; off <<= 1) {
        int cur = buf[tid];
        int add = (tid >= off) ? buf[tid - off] : 0;
        __syncthreads();
        buf[tid] = cur + add;
        __syncthreads();
    }
    int eqExcl = buf[tid] - isE;
    int sel = (isG || (isE && eqExcl < Eneed)) ? 1 : 0;
    __syncthreads();
    buf[tid] = sel;
    __syncthreads();
    for (int off = 1; off < 1024; off <<= 1) {
        int cur = buf[tid];
        int add = (tid >= off) ? buf[tid - off] : 0;
        __syncthreads();
        buf[tid] = cur + add;
        __syncthreads();
    }
    int pos = buf[tid] - sel;
    selpos[b * 1024 + tid] = sel ? pos : -1;
}

// ---------------- scatter: 4 token-groups x float4; 4 partials per chunk ----------------
__global__ void scatter_kernel(const float* __restrict__ xn, const float* __restrict__ s,
                               const int* __restrict__ selpos, float* __restrict__ A,
                               float* __restrict__ part) {
    int b = blockIdx.y;
    int chunk = blockIdx.x;
    int wid = threadIdx.x >> 6, lane = threadIdx.x & 63;
    int t0 = chunk * 64;
    __shared__ float sl[64];
    __shared__ int pl[64];
    if (threadIdx.x < 64) {
        int t = t0 + threadIdx.x;
        sl[threadIdx.x] = (t < N0) ? s[(size_t)b * N0 + t] : 0.0f;
        pl[threadIdx.x] = (t < N0) ? selpos[b * 1024 + t] : -1;
    }
    __syncthreads();
    const float* xbase = xn + ((size_t)b * N0 + t0) * 256;
    float* obase = A + (size_t)b * N1 * 256;
    float4 nonsel = make_float4(0.f, 0.f, 0.f, 0.f);
    int tmax = (t0 + 64 <= N0) ? 64 : (N0 - t0);
    for (int i = wid; i < tmax; i += 4) {
        float sc = sl[i];
        float4 v = ((const float4*)(xbase + (size_t)i * 256))[lane];
        v.x *= sc; v.y *= sc; v.z *= sc; v.w *= sc;
        int p = pl[i];
        if (p >= 0) ((float4*)(obase + (size_t)p * 256))[lane] = v;
        else { nonsel.x += v.x; nonsel.y += v.y; nonsel.z += v.z; nonsel.w += v.w; }
    }
    ((float4*)(part + ((size_t)(b * GCH + chunk) * 4 + wid) * 256))[lane] = nonsel;
}

// ---------------- reduce chunk partials (64 per batch) -> extra row ----------------
__global__ void extra_kernel(const float* __restrict__ part, float* __restrict__ A) {
    int b = blockIdx.x, d = threadIdx.x;
    float acc = 0.0f;
    for (int c = 0; c < GCH * 4; c++) acc += part[((size_t)b * GCH * 4 + c) * 256 + d];
    A[((size_t)b * N1 + 512) * 256 + d] = acc;
}

// ---------------- gate: one token per thread, block-aggregated routing ----------------
__global__ void gate_kernel(const float* __restrict__ xn2, const float* __restrict__ gw,
                            const float* __restrict__ gb, float* __restrict__ topval,
                            int* __restrict__ buckets, int* __restrict__ counts,
                            float* __restrict__ imp, int T) {
    int tid = threadIdx.x;
    int t = blockIdx.x * 256 + tid;
    __shared__ float4 gws[256];
    __shared__ int lcount[4];
    __shared__ int lbase[4];
    __shared__ float limp[4];
    gws[tid] = ((const float4*)gw)[tid];
    if (tid < 4) { lcount[tid] = 0; limp[tid] = 0.0f; }
    __syncthreads();
    bool valid = (t < T);
    float a0 = 0, a1 = 0, a2 = 0, a3 = 0;
    if (valid) {
        const float4* xb4 = (const float4*)(xn2 + (size_t)t * 256);
#pragma unroll 8
        for (int d4 = 0; d4 < 64; d4++) {
            float4 xv = xb4[d4];
            float4 w0 = gws[4 * d4], w1 = gws[4 * d4 + 1];
            float4 w2 = gws[4 * d4 + 2], w3 = gws[4 * d4 + 3];
            a0 += xv.x * w0.x + xv.y * w1.x + xv.z * w2.x + xv.w * w3.x;
            a1 += xv.x * w0.y + xv.y * w1.y + xv.z * w2.y + xv.w * w3.y;
            a2 += xv.x * w0.z + xv.y * w1.z + xv.z * w2.z + xv.w * w3.z;
            a3 += xv.x * w0.w + xv.y * w1.w + xv.z * w2.w + xv.w * w3.w;
        }
    }
    float q0 = 0, q1 = 0, q2 = 0, q3 = 0;
    int eid = 0;
    int lrank = 0;
    if (valid) {
        float l0 = a0 + gb[0], l1 = a1 + gb[1], l2 = a2 + gb[2], l3 = a3 + gb[3];
        float m = fmaxf(fmaxf(l0, l1), fmaxf(l2, l3));
        float e0 = expf(l0 - m), e1 = expf(l1 - m), e2 = expf(l2 - m), e3 = expf(l3 - m);
        float ssum = e0 + e1 + e2 + e3;
        q0 = e0 / ssum; q1 = e1 / ssum; q2 = e2 / ssum; q3 = e3 / ssum;
        float bv = q0;
        if (q1 > bv) { bv = q1; eid = 1; }
        if (q2 > bv) { bv = q2; eid = 2; }
        if (q3 > bv) { bv = q3; eid = 3; }
        topval[t] = bv;
        lrank = atomicAdd(&lcount[eid], 1);
    }
    float r0 = wave_reduce(q0), r1 = wave_reduce(q1);
    float r2 = wave_reduce(q2), r3 = wave_reduce(q3);
    if ((tid & 63) == 0) {
        atomicAdd(&limp[0], r0); atomicAdd(&limp[1], r1);
        atomicAdd(&limp[2], r2); atomicAdd(&limp[3], r3);
    }
    __syncthreads();
    if (tid < 4) {
        lbase[tid] = atomicAdd(&counts[tid], lcount[tid]);
        atomicAdd(&imp[tid], limp[tid]);
    }
    __syncthreads();
    if (valid) buckets[eid * T + lbase[eid] + lrank] = t;
}

// ---------------- expert FFN: 64 tokens/block, wave = 16 tokens x 4 cols.
// Weights LDS-staged 16 rows at a time -> each block streams W1/W2 from global ONCE
// (was: per WAVE = 4x the L1 traffic, the measured occupancy-invariant bottleneck). ----
__global__ __launch_bounds__(256, 1)
void ffn_kernel(const float* __restrict__ xn2, const float* __restrict__ w1,
                const float* __restrict__ b1, const float* __restrict__ w2,
                const float* __restrict__ b2, const float* __restrict__ topval,
                const int* __restrict__ buckets, const int* __restrict__ counts,
                float* __restrict__ C, int T) {
    int e = blockIdx.y;
    int cnt = counts[e];
    int base = blockIdx.x * 64;
    if (base >= cnt) return;
    __shared__ float tok[64][256];   // 64 KB; mid overwrites after barrier
    __shared__ float wst[16][256];   // 16 KB weight stage
    __shared__ int tids[64];
    if (threadIdx.x < 64) {
        int idx = base + threadIdx.x;
        tids[threadIdx.x] = (idx < cnt) ? buckets[e * T + idx] : -1;
    }
    __syncthreads();
    for (int v = threadIdx.x; v < 64 * 64; v += 256) {
        int i = v >> 6, c4 = v & 63;
        int t = tids[i];
        ((float4*)tok[i])[c4] = (t >= 0) ? ((const float4*)(xn2 + (size_t)t * 256))[c4]
                                         : make_float4(0.f, 0.f, 0.f, 0.f);
    }
    int c0 = threadIdx.x & 63;   // cols 4*c0 .. 4*c0+3
    int g = threadIdx.x >> 6;    // wave id; tokens 16*g .. 16*g+15
    const float* W1 = w1 + (size_t)e * 65536;
    const float* W2 = w2 + (size_t)e * 65536;
    float acc[16][4];
#pragma unroll
    for (int i = 0; i < 16; i++)
#pragma unroll
        for (int j = 0; j < 4; j++) acc[i][j] = 0.0f;
    for (int s = 0; s < 256; s += 16) {
        __syncthreads();  // tok ready (1st) / previous weight stage consumed
        for (int v = threadIdx.x; v < 16 * 64; v += 256) {
            int r = v >> 6, c4 = v & 63;
            ((float4*)wst[r])[c4] = ((const float4*)(W1 + (size_t)(s + r) * 256))[c4];
        }
        __syncthreads();
        for (int d0 = 0; d0 < 16; d0 += 4) {
            float4 w[4];
#pragma unroll
            for (int u = 0; u < 4; u++) w[u] = ((const float4*)wst[d0 + u])[c0];
#pragma unroll
            for (int i = 0; i < 16; i++) {
                float4 v = *((const float4*)&tok[g * 16 + i][s + d0]);  // broadcast
                acc[i][0] += v.x * w[0].x; acc[i][1] += v.x * w[0].y;
                acc[i][2] += v.x * w[0].z; acc[i][3] += v.x * w[0].w;
                acc[i][0] += v.y * w[1].x; acc[i][1] += v.y * w[1].y;
                acc[i][2] += v.y * w[1].z; acc[i][3] += v.y * w[1].w;
                acc[i][0] += v.z * w[2].x; acc[i][1] += v.z * w[2].y;
                acc[i][2] += v.z * w[2].z; acc[i][3] += v.z * w[2].w;
                acc[i][0] += v.w * w[3].x; acc[i][1] += v.w * w[3].y;
                acc[i][2] += v.w * w[3].z; acc[i][3] += v.w * w[3].w;
            }
        }
    }
    float4 bb = ((const float4*)(b1 + (size_t)e * 256))[c0];
    __syncthreads();  // phase-1 tok reads complete before overwriting with mid
#pragma unroll
    for (int i = 0; i < 16; i++) {
        float4 m;
        m.x = gelu_f(acc[i][0] + bb.x); m.y = gelu_f(acc[i][1] + bb.y);
        m.z = gelu_f(acc[i][2] + bb.z); m.w = gelu_f(acc[i][3] + bb.w);
        ((float4*)tok[g * 16 + i])[c0] = m;
    }
#pragma unroll
    for (int i = 0; i < 16; i++)
#pragma unroll
        for (int j = 0; j < 4; j++) acc[i][j] = 0.0f;
    for (int s = 0; s < 256; s += 16) {
        __syncthreads();  // mid written (1st) / previous weight stage consumed
        for (int v = threadIdx.x; v < 16 * 64; v += 256) {
            int r = v >> 6, c4 = v & 63;
            ((float4*)wst[r])[c4] = ((const float4*)(W2 + (size_t)(s + r) * 256))[c4];
        }
        __syncthreads();
        for (int d0 = 0; d0 < 16; d0 += 4) {
            float4 w[4];
#pragma unroll
            for (int u = 0; u < 4; u++) w[u] = ((const float4*)wst[d0 + u])[c0];
#pragma unroll
            for (int i = 0; i < 16; i++) {
                float4 v = *((const float4*)&tok[g * 16 + i][s + d0]);
                acc[i][0] += v.x * w[0].x; acc[i][1] += v.x * w[0].y;
                acc[i][2] += v.x * w[0].z; acc[i][3] += v.x * w[0].w;
                acc[i][0] += v.y * w[1].x; acc[i][1] += v.y * w[1].y;
                acc[i][2] += v.y * w[1].z; acc[i][3] += v.y * w[1].w;
                acc[i][0] += v.z * w[2].x; acc[i][1] += v.z * w[2].y;
                acc[i][2] += v.z * w[2].z; acc[i][3] += v.z * w[2].w;
                acc[i][0] += v.w * w[3].x; acc[i][1] += v.w * w[3].y;
                acc[i][2] += v.w * w[3].z; acc[i][3] += v.w * w[3].w;
            }
        }
    }
    float4 bb2 = ((const float4*)(b2 + (size_t)e * 256))[c0];
#pragma unroll
    for (int i = 0; i < 16; i++) {
        int t = tids[g * 16 + i];
        if (t >= 0) {
            float tv = topval[t];
            float4 xv = ((const float4*)(xn2 + (size_t)t * 256))[c0];  // residual re-read (L2)
            float4 o;
            o.x = xv.x + (acc[i][0] + bb2.x) * tv;
            o.y = xv.y + (acc[i][1] + bb2.y) * tv;
            o.z = xv.z + (acc[i][2] + bb2.z) * tv;
            o.w = xv.w + (acc[i][3] + bb2.w) * tv;
            ((float4*)(C + (size_t)t * 256))[c0] = o;
        }
    }
}

// ---------------- wave-per-token: A += gelu(rmsnorm(C, moe_gamma)) ----------------
__global__ void moe_add_kernel(const float* __restrict__ C, float* __restrict__ A,
                               const float* __restrict__ gamma, int T) {
    int wid = threadIdx.x >> 6, lane = threadIdx.x & 63;
    int t = blockIdx.x * 4 + wid;
    if (t >= T) return;
    float4 v = ((const float4*)(C + (size_t)t * 256))[lane];
    float ss = v.x * v.x + v.y * v.y + v.z * v.z + v.w * v.w;
    ss = wave_reduce(ss);
    ss = __shfl(ss, 0, 64);
    float inv = 16.0f / fmaxf(sqrtf(ss), 1e-12f);
    float4 g4 = ((const float4*)gamma)[lane];
    float4* ap = (float4*)(A + (size_t)t * 256) + lane;
    float4 a = *ap;
    a.x += gelu_f(v.x * inv * g4.x); a.y += gelu_f(v.y * inv * g4.y);
    a.z += gelu_f(v.z * inv * g4.z); a.w += gelu_f(v.w * inv * g4.w);
    *ap = a;
}

// ---------------- wave-per-token: end-score attn + head dot -> contribution ----------------
__global__ void endhead_kernel(const float* __restrict__ A, const float* __restrict__ w1,
                               const float* __restrict__ b1, const float* __restrict__ w2,
                               const float* __restrict__ b2, const float* __restrict__ hw,
                               const float* __restrict__ hb, float* __restrict__ contrib,
                               int T) {
    int wid = threadIdx.x >> 6, lane = threadIdx.x & 63;
    int t = blockIdx.x * 4 + wid;
    if (t >= T) return;
    float4 v = ((const float4*)(A + (size_t)t * 256))[lane];
    float p[8];
#pragma unroll
    for (int j = 0; j < 8; j++) p[j] = 0.0f;
    const float xv[4] = {v.x, v.y, v.z, v.w};
#pragma unroll
    for (int c = 0; c < 4; c++) {
        const float4* wr = (const float4*)(w1 + (4 * lane + c) * 8);
        float4 wa = wr[0], wb = wr[1];
        float xx = xv[c];
        p[0] += xx * wa.x; p[1] += xx * wa.y; p[2] += xx * wa.z; p[3] += xx * wa.w;
        p[4] += xx * wb.x; p[5] += xx * wb.y; p[6] += xx * wb.z; p[7] += xx * wb.w;
    }
    float4 h4 = ((const float4*)hw)[lane];
    float hp = gelu_f(v.x) * h4.x + gelu_f(v.y) * h4.y + gelu_f(v.z) * h4.z + gelu_f(v.w) * h4.w;
#pragma unroll
    for (int j = 0; j < 8; j++) p[j] = wave_reduce(p[j]);
    hp = wave_reduce(hp);
    if (lane == 0) {
        float z = b2[0];
#pragma unroll
        for (int j = 0; j < 8; j++) z += tanhf(p[j] + b1[j]) * w2[j];
        float sc = 1.0f / (1.0f + expf(-z));
        contrib[t] = (hp + hb[0]) * sc * (1.0f / (float)N1);
    }
}

// ---------------- deterministic per-batch sum of contributions ----------------
__global__ void finalsum_kernel(const float* __restrict__ contrib, float* __restrict__ out) {
    int b = blockIdx.x, tid = threadIdx.x;
    __shared__ float red[4];
    const float* cb = contrib + (size_t)b * N1;
    float v = cb[tid] + cb[256 + tid];
    if (tid == 0) v += cb[512];
    float s = wave_reduce(v);
    int wid = tid >> 6, lane = tid & 63;
    if (lane == 0) red[wid] = s;
    __syncthreads();
    if (tid == 0) out[b] = red[0] + red[1] + red[2] + red[3];
}

// ---------------- load-balance loss ----------------
__global__ void loss_kernel(const float* __restrict__ imp, float* __restrict__ out) {
    if (threadIdx.x == 0 && blockIdx.x == 0) {
        float i0 = imp[0], i1 = imp[1], i2 = imp[2], i3 = imp[3];
        float mean = (i0 + i1 + i2 + i3) * 0.25f;
        float v = ((i0 - mean) * (i0 - mean) + (i1 - mean) * (i1 - mean) +
                   (i2 - mean) * (i2 - mean) + (i3 - mean) * (i3 - mean)) / 3.0f;
        out[64] = v / (mean * mean + 1e-10f);
    }
}

extern "C" void kernel_launch(void* const* d_in, const int* in_sizes, int n_in,
                              void* d_out, int out_size, void* d_ws, size_t ws_size,
                              hipStream_t stream) {
    const float* x    = (const float*)d_in[0];
    const float* embw = (const float*)d_in[3];
    const float* embb = (const float*)d_in[4];
    const float* pos  = (const float*)d_in[5];
    const float* aw1  = (const float*)d_in[6];
    const float* ab1  = (const float*)d_in[7];
    const float* aw2  = (const float*)d_in[8];
    const float* ab2  = (const float*)d_in[9];
    const float* gw   = (const float*)d_in[10];
    const float* gb   = (const float*)d_in[11];
    const float* ew1  = (const float*)d_in[12];
    const float* eb1  = (const float*)d_in[13];
    const float* ew2  = (const float*)d_in[14];
    const float* eb2  = (const float*)d_in[15];
    const float* mg   = (const float*)d_in[16];
    const float* n1g  = (const float*)d_in[17];
    const float* n2g  = (const float*)d_in[18];
    const float* bott = (const float*)d_in[19];
    const float* cw39 = (const float*)d_in[20];
    const float* cw19 = (const float*)d_in[21];
    const float* cw9  = (const float*)d_in[22];
    const float* mpw  = (const float*)d_in[23];
    const float* bng  = (const float*)d_in[24];
    const float* bnb  = (const float*)d_in[25];
    const float* pjw  = (const float*)d_in[26];
    const float* pjb  = (const float*)d_in[27];
    const float* hw   = (const float*)d_in[28];
    const float* hb   = (const float*)d_in[29];
    float* out = (float*)d_out;

    float* W = (float*)d_ws;
    size_t off = 0;
    auto alloc = [&](size_t n) { float* p = W + off; off += n; return p; };
    float* A    = alloc((size_t)NTOK0 * 256);
    float* Bb   = alloc((size_t)NTOK0 * 256);
    float* CD   = alloc((size_t)NTOK1 * 256);
    float* XB   = alloc((size_t)NTOK0 * 32);
    float* sS   = alloc(NTOK0);
    float* ctb  = alloc(NTOK1);
    float* tval = alloc(NTOK1);
    float* imp  = alloc(4);
    float* part = alloc((size_t)BB * GCH * 4 * 256);
    float* wtE  = alloc(128 * 256);
    float* bwt0 = alloc(256 * 32);  float* bwt1 = alloc(256 * 32);
    float* mwt0 = alloc(256 * 32);  float* mwt1 = alloc(256 * 32);
    float* c39t0 = alloc(1248 * 32); float* c39t1 = alloc(1248 * 32);
    float* c19t0 = alloc(608 * 32);  float* c19t1 = alloc(608 * 32);
    float* c9t0  = alloc(288 * 32);  float* c9t1  = alloc(288 * 32);
    int* selpos  = (int*)(W + off); off += (size_t)BB * 1024;
    int* buckets = (int*)(W + off); off += (size_t)4 * NTOK1;
    int* counts  = (int*)(W + off); off += 4;

    zero_kernel<<<1, 64, 0, stream>>>(imp, counts);
    transpose_fused<<<792, 256, 0, stream>>>(embw, wtE, bott, bwt0, bwt1, mpw, mwt0, mwt1,
                                             cw39, c39t0, c39t1, cw19, c19t0, c19t1,
                                             cw9, c9t0, c9t1);

    // ===== layer 0 (N=1023) =====
    embed_kernel<<<dim3(64, BB), 256, 0, stream>>>(x, wtE, embb, pos, A);
    norm_attn_kernel<<<NTOK0 / 4, 256, 0, stream>>>(A, A, nullptr, n1g, aw1, ab1, aw2, ab2,
                                                    1, 0, Bb, n2g, NTOK0);
    pw_kernel<<<dim3(64, BB), 256, 0, stream>>>(Bb, bwt0, mwt0, bng, bnb, XB, CD, N0);
    conv_kernel<39, 19, 0><<<dim3(8, BB), 256, 0, stream>>>(XB, c39t0, bng, bnb, CD, N0);
    conv_kernel<19, 9, 32><<<dim3(8, BB), 256, 0, stream>>>(XB, c19t0, bng, bnb, CD, N0);
    conv_kernel<9, 4, 64><<<dim3(8, BB), 256, 0, stream>>>(XB, c9t0, bng, bnb, CD, N0);
    proj_kernel<<<(NTOK0 + 31) / 32, 256, 0, stream>>>(CD, pjw, pjb, A, NTOK0);

    // ===== layer 1 (prune to 513 tokens); gelu fused into load =====
    norm_attn_kernel<<<NTOK0 / 4, 256, 0, stream>>>(A, Bb, sS, n1g + 256, aw1, ab1, aw2, ab2,
                                                    0, 1, nullptr, nullptr, NTOK0);
    topk_kernel<<<BB, 1024, 0, stream>>>(sS, selpos);
    scatter_kernel<<<dim3(GCH, BB), 256, 0, stream>>>(Bb, sS, selpos, A, part);
    extra_kernel<<<BB, 256, 0, stream>>>(part, A);
    rmsnorm_kernel<<<NTOK1 / 4, 256, 0, stream>>>(A, Bb, n2g + 256, NTOK1);
    gate_kernel<<<(NTOK1 + 255) / 256, 256, 0, stream>>>(Bb, gw, gb, tval, buckets, counts, imp,
                                                         NTOK1);
    ffn_kernel<<<dim3((NTOK1 + 63) / 64, 4), 256, 0, stream>>>(Bb, ew1, eb1, ew2, eb2, tval,
                                                               buckets, counts, CD, NTOK1);
    moe_add_kernel<<<NTOK1 / 4, 256, 0, stream>>>(CD, A, mg, NTOK1);
    loss_kernel<<<1, 64, 0, stream>>>(imp, out);
    pw_kernel<<<dim3((N1 + 15) / 16, BB), 256, 0, stream>>>(Bb, bwt1, mwt1, bng + 128, bnb + 128,
                                                            XB, CD, N1);
    conv_kernel<39, 19, 0><<<dim3(5, BB), 256, 0, stream>>>(XB, c39t1, bng + 128, bnb + 128,
                                                            CD, N1);
    conv_kernel<19, 9, 32><<<dim3(5, BB), 256, 0, stream>>>(XB, c19t1, bng + 128, bnb + 128,
                                                            CD, N1);
    conv_kernel<9, 4, 64><<<dim3(5, BB), 256, 0, stream>>>(XB, c9t1, bng + 128, bnb + 128,
                                                           CD, N1);
    proj_kernel<<<(NTOK1 + 31) / 32, 256, 0, stream>>>(CD, pjw + 32768, pjb + 256, A, NTOK1);
    endhead_kernel<<<NTOK1 / 4, 256, 0, stream>>>(A, aw1, ab1, aw2, ab2, hw, hb, ctb, NTOK1);
    finalsum_kernel<<<BB, 256, 0, stream>>>(ctb, out);
}

// Round 12
// 1226.934 us; speedup vs baseline: 1.1647x; 1.1647x over previous
//
#include <hip/hip_runtime.h>
#include <math.h>

#define BB 64
#define EMB 256
#define N0 1023
#define N1 513
#define NTOK0 (BB * N0)   // 65472
#define NTOK1 (BB * N1)   // 32832
#define GCH 16            // gather chunks per batch

__device__ __forceinline__ float gelu_f(float x) {
    return 0.5f * x * (1.0f + erff(x * 0.7071067811865476f));
}

__device__ __forceinline__ float4 gelu4(float4 v) {
    return make_float4(gelu_f(v.x), gelu_f(v.y), gelu_f(v.z), gelu_f(v.w));
}

__device__ __forceinline__ float wave_reduce(float v) {
#pragma unroll
    for (int o = 32; o > 0; o >>= 1) v += __shfl_down(v, o, 64);
    return v;
}

// ---------------- fused weight transposes: in[o][ik] -> out[ik*O + o] ----------------
__global__ void transpose_fused(const float* __restrict__ embw, float* __restrict__ wtE,
                                const float* __restrict__ bott, float* __restrict__ bwt0,
                                float* __restrict__ bwt1,
                                const float* __restrict__ mpw, float* __restrict__ mwt0,
                                float* __restrict__ mwt1,
                                const float* __restrict__ cw39, float* __restrict__ c39t0,
                                float* __restrict__ c39t1,
                                const float* __restrict__ cw19, float* __restrict__ c19t0,
                                float* __restrict__ c19t1,
                                const float* __restrict__ cw9, float* __restrict__ c9t0,
                                float* __restrict__ c9t1) {
    int idx = blockIdx.x * 256 + threadIdx.x;
    const float* src; float* dst; int O, IK, base;
    if (idx < 32768)       { src = embw;         dst = wtE;   O = 256; IK = 128;  base = 0; }
    else if (idx < 40960)  { src = bott;         dst = bwt0;  O = 32;  IK = 256;  base = 32768; }
    else if (idx < 49152)  { src = bott + 8192;  dst = bwt1;  O = 32;  IK = 256;  base = 40960; }
    else if (idx < 57344)  { src = mpw;          dst = mwt0;  O = 32;  IK = 256;  base = 49152; }
    else if (idx < 65536)  { src = mpw + 8192;   dst = mwt1;  O = 32;  IK = 256;  base = 57344; }
    else if (idx < 105472) { src = cw39;         dst = c39t0; O = 32;  IK = 1248; base = 65536; }
    else if (idx < 145408) { src = cw39 + 39936; dst = c39t1; O = 32;  IK = 1248; base = 105472; }
    else if (idx < 164864) { src = cw19;         dst = c19t0; O = 32;  IK = 608;  base = 145408; }
    else if (idx < 184320) { src = cw19 + 19456; dst = c19t1; O = 32;  IK = 608;  base = 164864; }
    else if (idx < 193536) { src = cw9;          dst = c9t0;  O = 32;  IK = 288;  base = 184320; }
    else if (idx < 202752) { src = cw9 + 9216;   dst = c9t1;  O = 32;  IK = 288;  base = 193536; }
    else return;
    int local = idx - base;
    int o = local / IK, ik = local % IK;
    dst[ik * O + o] = src[local];
}

// ---------------- zero accumulators ----------------
__global__ void zero_kernel(float* __restrict__ imp, int* __restrict__ counts) {
    int i = threadIdx.x;
    if (i < 4) { imp[i] = 0.0f; counts[i] = 0; }
}

// ---------------- embedding conv (stride 4, K=8, C=16) + bias + pos ----------------
__global__ void embed_kernel(const float* __restrict__ x, const float* __restrict__ wt,
                             const float* __restrict__ emb_b, const float* __restrict__ pos,
                             float* __restrict__ A) {
    int b = blockIdx.y;
    int n0 = blockIdx.x * 16;
    __shared__ float xl[16][68];
    int l0 = 4 * n0;
    for (int idx = threadIdx.x; idx < 16 * 68; idx += 256) {
        int c = idx / 68, j = idx % 68;
        int l = l0 + j;
        xl[c][j] = (l < 4096) ? x[((size_t)b * 16 + c) * 4096 + l] : 0.0f;
    }
    __syncthreads();
    int e = threadIdx.x;
    float acc[16];
#pragma unroll
    for (int i = 0; i < 16; i++) acc[i] = 0.0f;
    for (int k = 0; k < 128; k++) {
        float w = wt[k * 256 + e];
        int c = k >> 3, s = k & 7;
#pragma unroll
        for (int i = 0; i < 16; i++) acc[i] += xl[c][4 * i + s] * w;
    }
    float bb = emb_b[e];
    for (int i = 0; i < 16; i++) {
        int n = n0 + i;
        if (n < N0)
            A[((size_t)b * N0 + n) * 256 + e] = acc[i] + bb + pos[(size_t)n * 256 + e];
    }
}

// ---------------- wave-per-token: rmsnorm + attn score (+pregelu, +second norm) ------
__global__ void norm_attn_kernel(const float* __restrict__ in, float* __restrict__ outv,
                                 float* __restrict__ score_out, const float* __restrict__ g,
                                 const float* __restrict__ w1, const float* __restrict__ b1,
                                 const float* __restrict__ w2, const float* __restrict__ b2,
                                 int scale_out, int pregelu,
                                 float* __restrict__ outv2, const float* __restrict__ g2,
                                 int T) {
    int wid = threadIdx.x >> 6, lane = threadIdx.x & 63;
    int t = blockIdx.x * 4 + wid;
    if (t >= T) return;
    float4 v = ((const float4*)(in + (size_t)t * 256))[lane];
    if (pregelu) v = gelu4(v);
    float4 xn = v;
    if (g != nullptr) {
        float ss = v.x * v.x + v.y * v.y + v.z * v.z + v.w * v.w;
        ss = wave_reduce(ss);
        ss = __shfl(ss, 0, 64);
        float inv = 16.0f / fmaxf(sqrtf(ss), 1e-12f);
        float4 g4 = ((const float4*)g)[lane];
        xn.x = v.x * inv * g4.x; xn.y = v.y * inv * g4.y;
        xn.z = v.z * inv * g4.z; xn.w = v.w * inv * g4.w;
    }
    float p[8];
#pragma unroll
    for (int j = 0; j < 8; j++) p[j] = 0.0f;
    const float xv[4] = {xn.x, xn.y, xn.z, xn.w};
#pragma unroll
    for (int c = 0; c < 4; c++) {
        const float4* wr = (const float4*)(w1 + (4 * lane + c) * 8);
        float4 wa = wr[0], wb = wr[1];
        float xx = xv[c];
        p[0] += xx * wa.x; p[1] += xx * wa.y; p[2] += xx * wa.z; p[3] += xx * wa.w;
        p[4] += xx * wb.x; p[5] += xx * wb.y; p[6] += xx * wb.z; p[7] += xx * wb.w;
    }
#pragma unroll
    for (int j = 0; j < 8; j++) p[j] = wave_reduce(p[j]);
    float sc = 0.0f;
    if (lane == 0) {
        float z = b2[0];
#pragma unroll
        for (int j = 0; j < 8; j++) z += tanhf(p[j] + b1[j]) * w2[j];
        sc = 1.0f / (1.0f + expf(-z));
        if (score_out) score_out[t] = sc;
    }
    sc = __shfl(sc, 0, 64);
    if (outv) {
        float m = scale_out ? sc : 1.0f;
        float4 o = make_float4(xn.x * m, xn.y * m, xn.z * m, xn.w * m);
        ((float4*)(outv + (size_t)t * 256))[lane] = o;
    }
    if (outv2) {
        float ss2 = xn.x * xn.x + xn.y * xn.y + xn.z * xn.z + xn.w * xn.w;
        ss2 = wave_reduce(ss2);
        ss2 = __shfl(ss2, 0, 64);
        float inv2 = 16.0f / fmaxf(sqrtf(ss2), 1e-12f);
        float4 q4 = ((const float4*)g2)[lane];
        float4 o;
        o.x = xn.x * inv2 * q4.x; o.y = xn.y * inv2 * q4.y;
        o.z = xn.z * inv2 * q4.z; o.w = xn.w * inv2 * q4.w;
        ((float4*)(outv2 + (size_t)t * 256))[lane] = o;
    }
}

// ---------------- wave-per-token rmsnorm ----------------
__global__ void rmsnorm_kernel(const float* __restrict__ in, float* __restrict__ out,
                               const float* __restrict__ g, int T) {
    int wid = threadIdx.x >> 6, lane = threadIdx.x & 63;
    int t = blockIdx.x * 4 + wid;
    if (t >= T) return;
    float4 v = ((const float4*)(in + (size_t)t * 256))[lane];
    float ss = v.x * v.x + v.y * v.y + v.z * v.z + v.w * v.w;
    ss = wave_reduce(ss);
    ss = __shfl(ss, 0, 64);
    float inv = 16.0f / fmaxf(sqrtf(ss), 1e-12f);
    float4 g4 = ((const float4*)g)[lane];
    float4 o;
    o.x = v.x * inv * g4.x; o.y = v.y * inv * g4.y;
    o.z = v.z * inv * g4.z; o.w = v.w * inv * g4.w;
    ((float4*)(out + (size_t)t * 256))[lane] = o;
}

// ---------------- pointwise: bottleneck + maxpool path (round-5 proven version) -------
__global__ void pw_kernel(const float* __restrict__ xn, const float* __restrict__ bwt,
                          const float* __restrict__ mwt, const float* __restrict__ bng,
                          const float* __restrict__ bnb, float* __restrict__ xb,
                          float* __restrict__ cat, int N) {
    int b = blockIdx.y;
    int t0 = blockIdx.x * 16;
    const float* xbase = xn + (size_t)b * N * 256;
    __shared__ float xt[18][256];
    __shared__ float xm[16][256];
    for (int idx = threadIdx.x; idx < 18 * 256; idx += 256) {
        int r = idx >> 8, d = idx & 255;
        int t = t0 + r - 1;
        xt[r][d] = (t >= 0 && t < N) ? xbase[(size_t)t * 256 + d] : -INFINITY;
    }
    __syncthreads();
    for (int idx = threadIdx.x; idx < 16 * 256; idx += 256) {
        int r = idx >> 8, d = idx & 255;
        xm[r][d] = fmaxf(fmaxf(xt[r][d], xt[r + 1][d]), xt[r + 2][d]);
    }
    __syncthreads();
    int f = threadIdx.x & 31;
    int gI = threadIdx.x >> 5;
    float accb[2] = {0.0f, 0.0f}, accm[2] = {0.0f, 0.0f};
    for (int d0 = 0; d0 < 256; d0++) {
        float wb = bwt[d0 * 32 + f];
        float wm = mwt[d0 * 32 + f];
#pragma unroll
        for (int i = 0; i < 2; i++) {
            int tt = gI * 2 + i;
            accb[i] += xt[1 + tt][d0] * wb;
            accm[i] += xm[tt][d0] * wm;
        }
    }
    const float BN_DIV = 1.0000050f;
    float scl = bng[96 + f] / BN_DIV;
    float sh = bnb[96 + f];
    for (int i = 0; i < 2; i++) {
        int t = t0 + gI * 2 + i;
        if (t < N) {
            xb[((size_t)b * N + t) * 32 + f] = accb[i];
            cat[((size_t)b * N + t) * 128 + 96 + f] = gelu_f(accm[i] * scl + sh);
        }
    }
}

// ---------------- time conv: 128 tokens/block, 4 f-cols x 4 tokens per thread ---------
template <int K, int P, int COFF>
__global__ void conv_kernel(const float* __restrict__ xb, const float* __restrict__ wt,
                            const float* __restrict__ bng, const float* __restrict__ bnb,
                            float* __restrict__ cat, int N) {
    int b = blockIdx.y;
    int t0 = blockIdx.x * 128;
    const float* xbase = xb + (size_t)b * N * 32;
    const int ROWS = 128 + K;
    __shared__ float xl[ROWS][33];
    for (int idx = threadIdx.x; idx < ROWS * 32; idx += 256) {
        int r = idx >> 5, f = idx & 31;
        int t = t0 - P + r;
        xl[r][f] = (t >= 0 && t < N) ? xbase[(size_t)t * 32 + f] : 0.0f;
    }
    __syncthreads();
    int fg = threadIdx.x & 7;
    int tg = threadIdx.x >> 3;
    float acc[4][4];
#pragma unroll
    for (int j = 0; j < 4; j++)
#pragma unroll
        for (int c = 0; c < 4; c++) acc[j][c] = 0.0f;
    for (int fi = 0; fi < 32; fi++) {
        float win[4];
#pragma unroll
        for (int j = 0; j < 4; j++) win[j] = xl[tg * 4 + j][fi];
#pragma unroll
        for (int k = 0; k < K; k++) {
            float4 w = ((const float4*)(wt + (fi * K + k) * 32))[fg];
#pragma unroll
            for (int j = 0; j < 4; j++) {
                float xv = win[j];
                acc[j][0] += xv * w.x; acc[j][1] += xv * w.y;
                acc[j][2] += xv * w.z; acc[j][3] += xv * w.w;
            }
#pragma unroll
            for (int j = 0; j < 3; j++) win[j] = win[j + 1];
            win[3] = xl[tg * 4 + k + 4][fi];
        }
    }
    const float BN_DIV = 1.0000050f;
    float4 g4 = ((const float4*)(bng + COFF))[fg];
    float4 b4 = ((const float4*)(bnb + COFF))[fg];
    float sx = g4.x / BN_DIV, sy = g4.y / BN_DIV, sz = g4.z / BN_DIV, sw = g4.w / BN_DIV;
#pragma unroll
    for (int j = 0; j < 4; j++) {
        int t = t0 + tg * 4 + j;
        if (t < N) {
            float4 o;
            o.x = gelu_f(acc[j][0] * sx + b4.x);
            o.y = gelu_f(acc[j][1] * sy + b4.y);
            o.z = gelu_f(acc[j][2] * sz + b4.z);
            o.w = gelu_f(acc[j][3] * sw + b4.w);
            ((float4*)(cat + ((size_t)b * N + t) * 128 + COFF))[fg] = o;
        }
    }
}

// ---------------- proj: 4 cols x 4 tokens per thread, float4 weights (R9 version) -----
__global__ void proj_kernel(const float* __restrict__ cat, const float* __restrict__ pw,
                            const float* __restrict__ pb, float* __restrict__ A, int TN) {
    int t0 = blockIdx.x * 16;
    __shared__ float cl[16][128];
    for (int v = threadIdx.x; v < 16 * 32; v += 256) {
        int r = v >> 5, c4 = v & 31;
        int t = t0 + r;
        ((float4*)cl[r])[c4] = (t < TN) ? ((const float4*)(cat + (size_t)t * 128))[c4]
                                        : make_float4(0.f, 0.f, 0.f, 0.f);
    }
    __syncthreads();
    int c0 = threadIdx.x & 63;
    int g = threadIdx.x >> 6;
    float acc[4][4];
#pragma unroll
    for (int i = 0; i < 4; i++)
#pragma unroll
        for (int j = 0; j < 4; j++) acc[i][j] = 0.0f;
    for (int f = 0; f < 128; f++) {
        float4 w = ((const float4*)(pw + f * 256))[c0];
        float v0 = cl[g * 4 + 0][f], v1 = cl[g * 4 + 1][f];
        float v2 = cl[g * 4 + 2][f], v3 = cl[g * 4 + 3][f];
        acc[0][0] += v0 * w.x; acc[0][1] += v0 * w.y; acc[0][2] += v0 * w.z; acc[0][3] += v0 * w.w;
        acc[1][0] += v1 * w.x; acc[1][1] += v1 * w.y; acc[1][2] += v1 * w.z; acc[1][3] += v1 * w.w;
        acc[2][0] += v2 * w.x; acc[2][1] += v2 * w.y; acc[2][2] += v2 * w.z; acc[2][3] += v2 * w.w;
        acc[3][0] += v3 * w.x; acc[3][1] += v3 * w.y; acc[3][2] += v3 * w.z; acc[3][3] += v3 * w.w;
    }
    float4 bias = ((const float4*)pb)[c0];
#pragma unroll
    for (int i = 0; i < 4; i++) {
        int t = t0 + g * 4 + i;
        if (t < TN) {
            float4* ap = (float4*)(A + (size_t)t * 256) + c0;
            float4 a = *ap;
            a.x += acc[i][0] + bias.x; a.y += acc[i][1] + bias.y;
            a.z += acc[i][2] + bias.z; a.w += acc[i][3] + bias.w;
            *ap = a;
        }
    }
}

// ---------------- top-512-of-1023 per batch ----------------
__global__ __launch_bounds__(1024) void topk_kernel(const float* __restrict__ s,
                                                    int* __restrict__ selpos) {
    int b = blockIdx.x;
    int tid = threadIdx.x;
    __shared__ float srt[1024];
    __shared__ int buf[1024];
    __shared__ int Gtot_s;
    float val = (tid < N0) ? s[(size_t)b * N0 + tid] : -INFINITY;
    srt[tid] = val;
    __syncthreads();
    for (int ksz = 2; ksz <= 1024; ksz <<= 1) {
        for (int j = ksz >> 1; j > 0; j >>= 1) {
            int ixj = tid ^ j;
            if (ixj > tid) {
                float a = srt[tid], c = srt[ixj];
                bool up = ((tid & ksz) == 0);
                if ((a > c) == up) { srt[tid] = c; srt[ixj] = a; }
            }
            __syncthreads();
        }
    }
    float thr = srt[512];
    __syncthreads();
    int isG = (val > thr) ? 1 : 0;
    int isE = (val == thr) ? 1 : 0;
    buf[tid] = isG;
    __syncthreads();
    for (int off = 1; off < 1024; off <<= 1) {
        int cur = buf[tid];
        int add = (tid >= off) ? buf[tid - off] : 0;
        __syncthreads();
        buf[tid] = cur + add;
        __syncthreads();
    }
    if (tid == 0) Gtot_s = buf[1023];
    __syncthreads();
    int Gtot = Gtot_s;
    int Eneed = 512 - Gtot;
    buf[tid] = isE;
    __syncthreads();
    for (int off = 1; off < 1024; off <<= 1) {
        int cur = buf[tid];
        int add = (tid >= off) ? buf[tid - off] : 0;
        __syncthreads();
        buf[tid] = cur + add;
        __syncthreads();
    }
    int eqExcl = buf[tid] - isE;
    int sel = (isG || (isE && eqExcl < Eneed)) ? 1 : 0;
    __syncthreads();
    buf[tid] = sel;
    __syncthreads();
    for (int off = 1; off < 1024; off <<= 1) {
        int cur = buf[tid];
        int add = (tid >= off) ? buf[tid - off] : 0;
        __syncthreads();
        buf[tid] = cur + add;
        __syncthreads();
    }
    int pos = buf[tid] - sel;
    selpos[b * 1024 + tid] = sel ? pos : -1;
}

// ---------------- scatter: 4 token-groups x float4; 4 partials per chunk ----------------
__global__ void scatter_kernel(const float* __restrict__ xn, const float* __restrict__ s,
                               const int* __restrict__ selpos, float* __restrict__ A,
                               float* __restrict__ part) {
    int b = blockIdx.y;
    int chunk = blockIdx.x;
    int wid = threadIdx.x >> 6, lane = threadIdx.x & 63;
    int t0 = chunk * 64;
    __shared__ float sl[64];
    __shared__ int pl[64];
    if (threadIdx.x < 64) {
        int t = t0 + threadIdx.x;
        sl[threadIdx.x] = (t < N0) ? s[(size_t)b * N0 + t] : 0.0f;
        pl[threadIdx.x] = (t < N0) ? selpos[b * 1024 + t] : -1;
    }
    __syncthreads();
    const float* xbase = xn + ((size_t)b * N0 + t0) * 256;
    float* obase = A + (size_t)b * N1 * 256;
    float4 nonsel = make_float4(0.f, 0.f, 0.f, 0.f);
    int tmax = (t0 + 64 <= N0) ? 64 : (N0 - t0);
    for (int i = wid; i < tmax; i += 4) {
        float sc = sl[i];
        float4 v = ((const float4*)(xbase + (size_t)i * 256))[lane];
        v.x *= sc; v.y *= sc; v.z *= sc; v.w *= sc;
        int p = pl[i];
        if (p >= 0) ((float4*)(obase + (size_t)p * 256))[lane] = v;
        else { nonsel.x += v.x; nonsel.y += v.y; nonsel.z += v.z; nonsel.w += v.w; }
    }
    ((float4*)(part + ((size_t)(b * GCH + chunk) * 4 + wid) * 256))[lane] = nonsel;
}

// ---------------- reduce chunk partials (64 per batch) -> extra row ----------------
__global__ void extra_kernel(const float* __restrict__ part, float* __restrict__ A) {
    int b = blockIdx.x, d = threadIdx.x;
    float acc = 0.0f;
    for (int c = 0; c < GCH * 4; c++) acc += part[((size_t)b * GCH * 4 + c) * 256 + d];
    A[((size_t)b * N1 + 512) * 256 + d] = acc;
}

// ---------------- gate: one token per thread, block-aggregated routing ----------------
__global__ void gate_kernel(const float* __restrict__ xn2, const float* __restrict__ gw,
                            const float* __restrict__ gb, float* __restrict__ topval,
                            int* __restrict__ buckets, int* __restrict__ counts,
                            float* __restrict__ imp, int T) {
    int tid = threadIdx.x;
    int t = blockIdx.x * 256 + tid;
    __shared__ float4 gws[256];
    __shared__ int lcount[4];
    __shared__ int lbase[4];
    __shared__ float limp[4];
    gws[tid] = ((const float4*)gw)[tid];
    if (tid < 4) { lcount[tid] = 0; limp[tid] = 0.0f; }
    __syncthreads();
    bool valid = (t < T);
    float a0 = 0, a1 = 0, a2 = 0, a3 = 0;
    if (valid) {
        const float4* xb4 = (const float4*)(xn2 + (size_t)t * 256);
#pragma unroll 8
        for (int d4 = 0; d4 < 64; d4++) {
            float4 xv = xb4[d4];
            float4 w0 = gws[4 * d4], w1 = gws[4 * d4 + 1];
            float4 w2 = gws[4 * d4 + 2], w3 = gws[4 * d4 + 3];
            a0 += xv.x * w0.x + xv.y * w1.x + xv.z * w2.x + xv.w * w3.x;
            a1 += xv.x * w0.y + xv.y * w1.y + xv.z * w2.y + xv.w * w3.y;
            a2 += xv.x * w0.z + xv.y * w1.z + xv.z * w2.z + xv.w * w3.z;
            a3 += xv.x * w0.w + xv.y * w1.w + xv.z * w2.w + xv.w * w3.w;
        }
    }
    float q0 = 0, q1 = 0, q2 = 0, q3 = 0;
    int eid = 0;
    int lrank = 0;
    if (valid) {
        float l0 = a0 + gb[0], l1 = a1 + gb[1], l2 = a2 + gb[2], l3 = a3 + gb[3];
        float m = fmaxf(fmaxf(l0, l1), fmaxf(l2, l3));
        float e0 = expf(l0 - m), e1 = expf(l1 - m), e2 = expf(l2 - m), e3 = expf(l3 - m);
        float ssum = e0 + e1 + e2 + e3;
        q0 = e0 / ssum; q1 = e1 / ssum; q2 = e2 / ssum; q3 = e3 / ssum;
        float bv = q0;
        if (q1 > bv) { bv = q1; eid = 1; }
        if (q2 > bv) { bv = q2; eid = 2; }
        if (q3 > bv) { bv = q3; eid = 3; }
        topval[t] = bv;
        lrank = atomicAdd(&lcount[eid], 1);
    }
    float r0 = wave_reduce(q0), r1 = wave_reduce(q1);
    float r2 = wave_reduce(q2), r3 = wave_reduce(q3);
    if ((tid & 63) == 0) {
        atomicAdd(&limp[0], r0); atomicAdd(&limp[1], r1);
        atomicAdd(&limp[2], r2); atomicAdd(&limp[3], r3);
    }
    __syncthreads();
    if (tid < 4) {
        lbase[tid] = atomicAdd(&counts[tid], lcount[tid]);
        atomicAdd(&imp[tid], limp[tid]);
    }
    __syncthreads();
    if (valid) buckets[eid * T + lbase[eid] + lrank] = t;
}

// ---------------- expert FFN (R9 structure) + FUSED moe_add epilogue:
// wave holds full token row (64 lanes x 4 cols) -> rmsnorm = one wave_reduce/token;
// A[t] += gelu(rmsnorm(x + ffn_out, gamma)) written directly, C eliminated. ----------
__global__ __launch_bounds__(256, 1)
void ffn_kernel(const float* __restrict__ xn2, const float* __restrict__ w1,
                const float* __restrict__ b1, const float* __restrict__ w2,
                const float* __restrict__ b2, const float* __restrict__ topval,
                const int* __restrict__ buckets, const int* __restrict__ counts,
                const float* __restrict__ gamma, float* __restrict__ A, int T) {
    int e = blockIdx.y;
    int cnt = counts[e];
    int base = blockIdx.x * 64;
    if (base >= cnt) return;
    __shared__ float tok[64][256];   // 64 KB; mid overwrites after barrier
    __shared__ int tids[64];
    if (threadIdx.x < 64) {
        int idx = base + threadIdx.x;
        tids[threadIdx.x] = (idx < cnt) ? buckets[e * T + idx] : -1;
    }
    __syncthreads();
    for (int v = threadIdx.x; v < 64 * 64; v += 256) {
        int i = v >> 6, c4 = v & 63;
        int t = tids[i];
        ((float4*)tok[i])[c4] = (t >= 0) ? ((const float4*)(xn2 + (size_t)t * 256))[c4]
                                         : make_float4(0.f, 0.f, 0.f, 0.f);
    }
    __syncthreads();
    int c0 = threadIdx.x & 63;   // cols 4*c0 .. 4*c0+3
    int g = threadIdx.x >> 6;    // wave id; tokens 16*g .. 16*g+15
    const float* W1 = w1 + (size_t)e * 65536;
    const float* W2 = w2 + (size_t)e * 65536;
    float acc[16][4];
#pragma unroll
    for (int i = 0; i < 16; i++)
#pragma unroll
        for (int j = 0; j < 4; j++) acc[i][j] = 0.0f;
    for (int d0 = 0; d0 < 256; d0 += 4) {
        float4 w[4];
#pragma unroll
        for (int u = 0; u < 4; u++) w[u] = ((const float4*)(W1 + (size_t)(d0 + u) * 256))[c0];
#pragma unroll
        for (int i = 0; i < 16; i++) {
            float4 v = *((const float4*)&tok[g * 16 + i][d0]);  // wave-uniform -> broadcast
            acc[i][0] += v.x * w[0].x; acc[i][1] += v.x * w[0].y;
            acc[i][2] += v.x * w[0].z; acc[i][3] += v.x * w[0].w;
            acc[i][0] += v.y * w[1].x; acc[i][1] += v.y * w[1].y;
            acc[i][2] += v.y * w[1].z; acc[i][3] += v.y * w[1].w;
            acc[i][0] += v.z * w[2].x; acc[i][1] += v.z * w[2].y;
            acc[i][2] += v.z * w[2].z; acc[i][3] += v.z * w[2].w;
            acc[i][0] += v.w * w[3].x; acc[i][1] += v.w * w[3].y;
            acc[i][2] += v.w * w[3].z; acc[i][3] += v.w * w[3].w;
        }
    }
    float4 bb = ((const float4*)(b1 + (size_t)e * 256))[c0];
    __syncthreads();  // phase-1 reads complete before overwriting tok with mid
#pragma unroll
    for (int i = 0; i < 16; i++) {
        float4 m;
        m.x = gelu_f(acc[i][0] + bb.x); m.y = gelu_f(acc[i][1] + bb.y);
        m.z = gelu_f(acc[i][2] + bb.z); m.w = gelu_f(acc[i][3] + bb.w);
        ((float4*)tok[g * 16 + i])[c0] = m;
    }
    __syncthreads();
#pragma unroll
    for (int i = 0; i < 16; i++)
#pragma unroll
        for (int j = 0; j < 4; j++) acc[i][j] = 0.0f;
    for (int d0 = 0; d0 < 256; d0 += 4) {
        float4 w[4];
#pragma unroll
        for (int u = 0; u < 4; u++) w[u] = ((const float4*)(W2 + (size_t)(d0 + u) * 256))[c0];
#pragma unroll
        for (int i = 0; i < 16; i++) {
            float4 v = *((const float4*)&tok[g * 16 + i][d0]);
            acc[i][0] += v.x * w[0].x; acc[i][1] += v.x * w[0].y;
            acc[i][2] += v.x * w[0].z; acc[i][3] += v.x * w[0].w;
            acc[i][0] += v.y * w[1].x; acc[i][1] += v.y * w[1].y;
            acc[i][2] += v.y * w[1].z; acc[i][3] += v.y * w[1].w;
            acc[i][0] += v.z * w[2].x; acc[i][1] += v.z * w[2].y;
            acc[i][2] += v.z * w[2].z; acc[i][3] += v.z * w[2].w;
            acc[i][0] += v.w * w[3].x; acc[i][1] += v.w * w[3].y;
            acc[i][2] += v.w * w[3].z; acc[i][3] += v.w * w[3].w;
        }
    }
    float4 bb2 = ((const float4*)(b2 + (size_t)e * 256))[c0];
    float4 gm = ((const float4*)gamma)[c0];
#pragma unroll
    for (int i = 0; i < 16; i++) {
        int t = tids[g * 16 + i];  // wave-uniform
        if (t < 0) continue;
        float tv = topval[t];
        float4 xv = ((const float4*)(xn2 + (size_t)t * 256))[c0];  // residual re-read (L2)
        float4 o;
        o.x = xv.x + (acc[i][0] + bb2.x) * tv;
        o.y = xv.y + (acc[i][1] + bb2.y) * tv;
        o.z = xv.z + (acc[i][2] + bb2.z) * tv;
        o.w = xv.w + (acc[i][3] + bb2.w) * tv;
        // fused rmsnorm over the token (whole row lives in this wave)
        float ss = o.x * o.x + o.y * o.y + o.z * o.z + o.w * o.w;
        ss = wave_reduce(ss);
        ss = __shfl(ss, 0, 64);
        float inv = 16.0f / fmaxf(sqrtf(ss), 1e-12f);
        float4* ap = (float4*)(A + (size_t)t * 256) + c0;
        float4 a = *ap;
        a.x += gelu_f(o.x * inv * gm.x);
        a.y += gelu_f(o.y * inv * gm.y);
        a.z += gelu_f(o.z * inv * gm.z);
        a.w += gelu_f(o.w * inv * gm.w);
        *ap = a;
    }
}

// ---------------- wave-per-token: end-score attn + head dot -> contribution ----------------
__global__ void endhead_kernel(const float* __restrict__ A, const float* __restrict__ w1,
                               const float* __restrict__ b1, const float* __restrict__ w2,
                               const float* __restrict__ b2, const float* __restrict__ hw,
                               const float* __restrict__ hb, float* __restrict__ contrib,
                               int T) {
    int wid = threadIdx.x >> 6, lane = threadIdx.x & 63;
    int t = blockIdx.x * 4 + wid;
    if (t >= T) return;
    float4 v = ((const float4*)(A + (size_t)t * 256))[lane];
    float p[8];
#pragma unroll
    for (int j = 0; j < 8; j++) p[j] = 0.0f;
    const float xv[4] = {v.x, v.y, v.z, v.w};
#pragma unroll
    for (int c = 0; c < 4; c++) {
        const float4* wr = (const float4*)(w1 + (4 * lane + c) * 8);
        float4 wa = wr[0], wb = wr[1];
        float xx = xv[c];
        p[0] += xx * wa.x; p[1] += xx * wa.y; p[2] += xx * wa.z; p[3] += xx * wa.w;
        p[4] += xx * wb.x; p[5] += xx * wb.y; p[6] += xx * wb.z; p[7] += xx * wb.w;
    }
    float4 h4 = ((const float4*)hw)[lane];
    float hp = gelu_f(v.x) * h4.x + gelu_f(v.y) * h4.y + gelu_f(v.z) * h4.z + gelu_f(v.w) * h4.w;
#pragma unroll
    for (int j = 0; j < 8; j++) p[j] = wave_reduce(p[j]);
    hp = wave_reduce(hp);
    if (lane == 0) {
        float z = b2[0];
#pragma unroll
        for (int j = 0; j < 8; j++) z += tanhf(p[j] + b1[j]) * w2[j];
        float sc = 1.0f / (1.0f + expf(-z));
        contrib[t] = (hp + hb[0]) * sc * (1.0f / (float)N1);
    }
}

// ---------------- per-batch sum of contributions + (block 0) load-balance loss --------
__global__ void finalsum_kernel(const float* __restrict__ contrib,
                                const float* __restrict__ imp, float* __restrict__ out) {
    int b = blockIdx.x, tid = threadIdx.x;
    __shared__ float red[4];
    const float* cb = contrib + (size_t)b * N1;
    float v = cb[tid] + cb[256 + tid];
    if (tid == 0) v += cb[512];
    float s = wave_reduce(v);
    int wid = tid >> 6, lane = tid & 63;
    if (lane == 0) red[wid] = s;
    __syncthreads();
    if (tid == 0) {
        out[b] = red[0] + red[1] + red[2] + red[3];
        if (b == 0) {
            float i0 = imp[0], i1 = imp[1], i2 = imp[2], i3 = imp[3];
            float mean = (i0 + i1 + i2 + i3) * 0.25f;
            float var = ((i0 - mean) * (i0 - mean) + (i1 - mean) * (i1 - mean) +
                         (i2 - mean) * (i2 - mean) + (i3 - mean) * (i3 - mean)) / 3.0f;
            out[64] = var / (mean * mean + 1e-10f);
        }
    }
}

extern "C" void kernel_launch(void* const* d_in, const int* in_sizes, int n_in,
                              void* d_out, int out_size, void* d_ws, size_t ws_size,
                              hipStream_t stream) {
    const float* x    = (const float*)d_in[0];
    const float* embw = (const float*)d_in[3];
    const float* embb = (const float*)d_in[4];
    const float* pos  = (const float*)d_in[5];
    const float* aw1  = (const float*)d_in[6];
    const float* ab1  = (const float*)d_in[7];
    const float* aw2  = (const float*)d_in[8];
    const float* ab2  = (const float*)d_in[9];
    const float* gw   = (const float*)d_in[10];
    const float* gb   = (const float*)d_in[11];
    const float* ew1  = (const float*)d_in[12];
    const float* eb1  = (const float*)d_in[13];
    const float* ew2  = (const float*)d_in[14];
    const float* eb2  = (const float*)d_in[15];
    const float* mg   = (const float*)d_in[16];
    const float* n1g  = (const float*)d_in[17];
    const float* n2g  = (const float*)d_in[18];
    const float* bott = (const float*)d_in[19];
    const float* cw39 = (const float*)d_in[20];
    const float* cw19 = (const float*)d_in[21];
    const float* cw9  = (const float*)d_in[22];
    const float* mpw  = (const float*)d_in[23];
    const float* bng  = (const float*)d_in[24];
    const float* bnb  = (const float*)d_in[25];
    const float* pjw  = (const float*)d_in[26];
    const float* pjb  = (const float*)d_in[27];
    const float* hw   = (const float*)d_in[28];
    const float* hb   = (const float*)d_in[29];
    float* out = (float*)d_out;

    float* W = (float*)d_ws;
    size_t off = 0;
    auto alloc = [&](size_t n) { float* p = W + off; off += n; return p; };
    float* A    = alloc((size_t)NTOK0 * 256);
    float* Bb   = alloc((size_t)NTOK0 * 256);
    float* CD   = alloc((size_t)NTOK1 * 256);
    float* XB   = alloc((size_t)NTOK0 * 32);
    float* sS   = alloc(NTOK0);
    float* ctb  = alloc(NTOK1);
    float* tval = alloc(NTOK1);
    float* imp  = alloc(4);
    float* part = alloc((size_t)BB * GCH * 4 * 256);
    float* wtE  = alloc(128 * 256);
    float* bwt0 = alloc(256 * 32);  float* bwt1 = alloc(256 * 32);
    float* mwt0 = alloc(256 * 32);  float* mwt1 = alloc(256 * 32);
    float* c39t0 = alloc(1248 * 32); float* c39t1 = alloc(1248 * 32);
    float* c19t0 = alloc(608 * 32);  float* c19t1 = alloc(608 * 32);
    float* c9t0  = alloc(288 * 32);  float* c9t1  = alloc(288 * 32);
    int* selpos  = (int*)(W + off); off += (size_t)BB * 1024;
    int* buckets = (int*)(W + off); off += (size_t)4 * NTOK1;
    int* counts  = (int*)(W + off); off += 4;

    zero_kernel<<<1, 64, 0, stream>>>(imp, counts);
    transpose_fused<<<792, 256, 0, stream>>>(embw, wtE, bott, bwt0, bwt1, mpw, mwt0, mwt1,
                                             cw39, c39t0, c39t1, cw19, c19t0, c19t1,
                                             cw9, c9t0, c9t1);

    // ===== layer 0 (N=1023) =====
    embed_kernel<<<dim3(64, BB), 256, 0, stream>>>(x, wtE, embb, pos, A);
    norm_attn_kernel<<<NTOK0 / 4, 256, 0, stream>>>(A, A, nullptr, n1g, aw1, ab1, aw2, ab2,
                                                    1, 0, Bb, n2g, NTOK0);
    pw_kernel<<<dim3(64, BB), 256, 0, stream>>>(Bb, bwt0, mwt0, bng, bnb, XB, CD, N0);
    conv_kernel<39, 19, 0><<<dim3(8, BB), 256, 0, stream>>>(XB, c39t0, bng, bnb, CD, N0);
    conv_kernel<19, 9, 32><<<dim3(8, BB), 256, 0, stream>>>(XB, c19t0, bng, bnb, CD, N0);
    conv_kernel<9, 4, 64><<<dim3(8, BB), 256, 0, stream>>>(XB, c9t0, bng, bnb, CD, N0);
    proj_kernel<<<(NTOK0 + 15) / 16, 256, 0, stream>>>(CD, pjw, pjb, A, NTOK0);

    // ===== layer 1 (prune to 513 tokens); gelu fused into load =====
    norm_attn_kernel<<<NTOK0 / 4, 256, 0, stream>>>(A, Bb, sS, n1g + 256, aw1, ab1, aw2, ab2,
                                                    0, 1, nullptr, nullptr, NTOK0);
    topk_kernel<<<BB, 1024, 0, stream>>>(sS, selpos);
    scatter_kernel<<<dim3(GCH, BB), 256, 0, stream>>>(Bb, sS, selpos, A, part);
    extra_kernel<<<BB, 256, 0, stream>>>(part, A);
    rmsnorm_kernel<<<NTOK1 / 4, 256, 0, stream>>>(A, Bb, n2g + 256, NTOK1);
    gate_kernel<<<(NTOK1 + 255) / 256, 256, 0, stream>>>(Bb, gw, gb, tval, buckets, counts, imp,
                                                         NTOK1);
    // ffn with fused moe_add: A[t] += gelu(rmsnorm(Bb[t] + ffn(Bb[t]), mg))
    ffn_kernel<<<dim3((NTOK1 + 63) / 64, 4), 256, 0, stream>>>(Bb, ew1, eb1, ew2, eb2, tval,
                                                               buckets, counts, mg, A, NTOK1);
    pw_kernel<<<dim3((N1 + 15) / 16, BB), 256, 0, stream>>>(Bb, bwt1, mwt1, bng + 128, bnb + 128,
                                                            XB, CD, N1);
    conv_kernel<39, 19, 0><<<dim3(5, BB), 256, 0, stream>>>(XB, c39t1, bng + 128, bnb + 128,
                                                            CD, N1);
    conv_kernel<19, 9, 32><<<dim3(5, BB), 256, 0, stream>>>(XB, c19t1, bng + 128, bnb + 128,
                                                            CD, N1);
    conv_kernel<9, 4, 64><<<dim3(5, BB), 256, 0, stream>>>(XB, c9t1, bng + 128, bnb + 128,
                                                           CD, N1);
    proj_kernel<<<(NTOK1 + 15) / 16, 256, 0, stream>>>(CD, pjw + 32768, pjb + 256, A, NTOK1);
    endhead_kernel<<<NTOK1 / 4, 256, 0, stream>>>(A, aw1, ab1, aw2, ab2, hw, hb, ctb, NTOK1);
    finalsum_kernel<<<BB, 256, 0, stream>>>(ctb, imp, out);
}

// Round 13
// 1226.056 us; speedup vs baseline: 1.1655x; 1.0007x over previous
//
#include <hip/hip_runtime.h>
#include <math.h>

#define BB 64
#define EMB 256
#define N0 1023
#define N1 513
#define NTOK0 (BB * N0)   // 65472
#define NTOK1 (BB * N1)   // 32832
#define GCH 16            // gather chunks per batch

__device__ __forceinline__ float gelu_f(float x) {
    return 0.5f * x * (1.0f + erff(x * 0.7071067811865476f));
}

__device__ __forceinline__ float4 gelu4(float4 v) {
    return make_float4(gelu_f(v.x), gelu_f(v.y), gelu_f(v.z), gelu_f(v.w));
}

__device__ __forceinline__ float wave_reduce(float v) {
#pragma unroll
    for (int o = 32; o > 0; o >>= 1) v += __shfl_down(v, o, 64);
    return v;
}

// bf16 helpers: pack with round-to-nearest-even; unpack = shift
__device__ __forceinline__ unsigned short f2bf(float f) {
    unsigned int u = __float_as_uint(f);
    u = (u + 0x7FFFu + ((u >> 16) & 1u)) >> 16;
    return (unsigned short)u;
}
__device__ __forceinline__ float bf2f(unsigned short h) {
    return __uint_as_float(((unsigned int)h) << 16);
}
__device__ __forceinline__ float4 bf4_to_f4(ushort4 h) {
    return make_float4(bf2f(h.x), bf2f(h.y), bf2f(h.z), bf2f(h.w));
}

// ---------------- fused weight transposes: in[o][ik] -> out[ik*O + o] ----------------
__global__ void transpose_fused(const float* __restrict__ embw, float* __restrict__ wtE,
                                const float* __restrict__ bott, float* __restrict__ bwt0,
                                float* __restrict__ bwt1,
                                const float* __restrict__ mpw, float* __restrict__ mwt0,
                                float* __restrict__ mwt1,
                                const float* __restrict__ cw39, float* __restrict__ c39t0,
                                float* __restrict__ c39t1,
                                const float* __restrict__ cw19, float* __restrict__ c19t0,
                                float* __restrict__ c19t1,
                                const float* __restrict__ cw9, float* __restrict__ c9t0,
                                float* __restrict__ c9t1) {
    int idx = blockIdx.x * 256 + threadIdx.x;
    const float* src; float* dst; int O, IK, base;
    if (idx < 32768)       { src = embw;         dst = wtE;   O = 256; IK = 128;  base = 0; }
    else if (idx < 40960)  { src = bott;         dst = bwt0;  O = 32;  IK = 256;  base = 32768; }
    else if (idx < 49152)  { src = bott + 8192;  dst = bwt1;  O = 32;  IK = 256;  base = 40960; }
    else if (idx < 57344)  { src = mpw;          dst = mwt0;  O = 32;  IK = 256;  base = 49152; }
    else if (idx < 65536)  { src = mpw + 8192;   dst = mwt1;  O = 32;  IK = 256;  base = 57344; }
    else if (idx < 105472) { src = cw39;         dst = c39t0; O = 32;  IK = 1248; base = 65536; }
    else if (idx < 145408) { src = cw39 + 39936; dst = c39t1; O = 32;  IK = 1248; base = 105472; }
    else if (idx < 164864) { src = cw19;         dst = c19t0; O = 32;  IK = 608;  base = 145408; }
    else if (idx < 184320) { src = cw19 + 19456; dst = c19t1; O = 32;  IK = 608;  base = 164864; }
    else if (idx < 193536) { src = cw9;          dst = c9t0;  O = 32;  IK = 288;  base = 184320; }
    else if (idx < 202752) { src = cw9 + 9216;   dst = c9t1;  O = 32;  IK = 288;  base = 193536; }
    else return;
    int local = idx - base;
    int o = local / IK, ik = local % IK;
    dst[ik * O + o] = src[local];
}

// ---------------- convert ffn/proj weights to bf16 (halves per-wave L1 stream) --------
__global__ void convert_bf16(const float* __restrict__ ew1, const float* __restrict__ ew2,
                             const float* __restrict__ pjw, unsigned short* __restrict__ ew1b,
                             unsigned short* __restrict__ ew2b,
                             unsigned short* __restrict__ pjwb) {
    int idx = blockIdx.x * 256 + threadIdx.x;
    if (idx < 262144) ew1b[idx] = f2bf(ew1[idx]);
    else if (idx < 524288) ew2b[idx - 262144] = f2bf(ew2[idx - 262144]);
    else if (idx < 589824) pjwb[idx - 524288] = f2bf(pjw[idx - 524288]);
}

// ---------------- zero accumulators ----------------
__global__ void zero_kernel(float* __restrict__ imp, int* __restrict__ counts) {
    int i = threadIdx.x;
    if (i < 4) { imp[i] = 0.0f; counts[i] = 0; }
}

// ---------------- embedding conv (stride 4, K=8, C=16) + bias + pos ----------------
__global__ void embed_kernel(const float* __restrict__ x, const float* __restrict__ wt,
                             const float* __restrict__ emb_b, const float* __restrict__ pos,
                             float* __restrict__ A) {
    int b = blockIdx.y;
    int n0 = blockIdx.x * 16;
    __shared__ float xl[16][68];
    int l0 = 4 * n0;
    for (int idx = threadIdx.x; idx < 16 * 68; idx += 256) {
        int c = idx / 68, j = idx % 68;
        int l = l0 + j;
        xl[c][j] = (l < 4096) ? x[((size_t)b * 16 + c) * 4096 + l] : 0.0f;
    }
    __syncthreads();
    int e = threadIdx.x;
    float acc[16];
#pragma unroll
    for (int i = 0; i < 16; i++) acc[i] = 0.0f;
    for (int k = 0; k < 128; k++) {
        float w = wt[k * 256 + e];
        int c = k >> 3, s = k & 7;
#pragma unroll
        for (int i = 0; i < 16; i++) acc[i] += xl[c][4 * i + s] * w;
    }
    float bb = emb_b[e];
    for (int i = 0; i < 16; i++) {
        int n = n0 + i;
        if (n < N0)
            A[((size_t)b * N0 + n) * 256 + e] = acc[i] + bb + pos[(size_t)n * 256 + e];
    }
}

// ---------------- wave-per-token: rmsnorm + attn score (+pregelu, +second norm) ------
__global__ void norm_attn_kernel(const float* __restrict__ in, float* __restrict__ outv,
                                 float* __restrict__ score_out, const float* __restrict__ g,
                                 const float* __restrict__ w1, const float* __restrict__ b1,
                                 const float* __restrict__ w2, const float* __restrict__ b2,
                                 int scale_out, int pregelu,
                                 float* __restrict__ outv2, const float* __restrict__ g2,
                                 int T) {
    int wid = threadIdx.x >> 6, lane = threadIdx.x & 63;
    int t = blockIdx.x * 4 + wid;
    if (t >= T) return;
    float4 v = ((const float4*)(in + (size_t)t * 256))[lane];
    if (pregelu) v = gelu4(v);
    float4 xn = v;
    if (g != nullptr) {
        float ss = v.x * v.x + v.y * v.y + v.z * v.z + v.w * v.w;
        ss = wave_reduce(ss);
        ss = __shfl(ss, 0, 64);
        float inv = 16.0f / fmaxf(sqrtf(ss), 1e-12f);
        float4 g4 = ((const float4*)g)[lane];
        xn.x = v.x * inv * g4.x; xn.y = v.y * inv * g4.y;
        xn.z = v.z * inv * g4.z; xn.w = v.w * inv * g4.w;
    }
    float p[8];
#pragma unroll
    for (int j = 0; j < 8; j++) p[j] = 0.0f;
    const float xv[4] = {xn.x, xn.y, xn.z, xn.w};
#pragma unroll
    for (int c = 0; c < 4; c++) {
        const float4* wr = (const float4*)(w1 + (4 * lane + c) * 8);
        float4 wa = wr[0], wb = wr[1];
        float xx = xv[c];
        p[0] += xx * wa.x; p[1] += xx * wa.y; p[2] += xx * wa.z; p[3] += xx * wa.w;
        p[4] += xx * wb.x; p[5] += xx * wb.y; p[6] += xx * wb.z; p[7] += xx * wb.w;
    }
#pragma unroll
    for (int j = 0; j < 8; j++) p[j] = wave_reduce(p[j]);
    float sc = 0.0f;
    if (lane == 0) {
        float z = b2[0];
#pragma unroll
        for (int j = 0; j < 8; j++) z += tanhf(p[j] + b1[j]) * w2[j];
        sc = 1.0f / (1.0f + expf(-z));
        if (score_out) score_out[t] = sc;
    }
    sc = __shfl(sc, 0, 64);
    if (outv) {
        float m = scale_out ? sc : 1.0f;
        float4 o = make_float4(xn.x * m, xn.y * m, xn.z * m, xn.w * m);
        ((float4*)(outv + (size_t)t * 256))[lane] = o;
    }
    if (outv2) {
        float ss2 = xn.x * xn.x + xn.y * xn.y + xn.z * xn.z + xn.w * xn.w;
        ss2 = wave_reduce(ss2);
        ss2 = __shfl(ss2, 0, 64);
        float inv2 = 16.0f / fmaxf(sqrtf(ss2), 1e-12f);
        float4 q4 = ((const float4*)g2)[lane];
        float4 o;
        o.x = xn.x * inv2 * q4.x; o.y = xn.y * inv2 * q4.y;
        o.z = xn.z * inv2 * q4.z; o.w = xn.w * inv2 * q4.w;
        ((float4*)(outv2 + (size_t)t * 256))[lane] = o;
    }
}

// ---------------- wave-per-token rmsnorm ----------------
__global__ void rmsnorm_kernel(const float* __restrict__ in, float* __restrict__ out,
                               const float* __restrict__ g, int T) {
    int wid = threadIdx.x >> 6, lane = threadIdx.x & 63;
    int t = blockIdx.x * 4 + wid;
    if (t >= T) return;
    float4 v = ((const float4*)(in + (size_t)t * 256))[lane];
    float ss = v.x * v.x + v.y * v.y + v.z * v.z + v.w * v.w;
    ss = wave_reduce(ss);
    ss = __shfl(ss, 0, 64);
    float inv = 16.0f / fmaxf(sqrtf(ss), 1e-12f);
    float4 g4 = ((const float4*)g)[lane];
    float4 o;
    o.x = v.x * inv * g4.x; o.y = v.y * inv * g4.y;
    o.z = v.z * inv * g4.z; o.w = v.w * inv * g4.w;
    ((float4*)(out + (size_t)t * 256))[lane] = o;
}

// ---------------- pointwise: bottleneck + maxpool path (round-5 proven version) -------
__global__ void pw_kernel(const float* __restrict__ xn, const float* __restrict__ bwt,
                          const float* __restrict__ mwt, const float* __restrict__ bng,
                          const float* __restrict__ bnb, float* __restrict__ xb,
                          float* __restrict__ cat, int N) {
    int b = blockIdx.y;
    int t0 = blockIdx.x * 16;
    const float* xbase = xn + (size_t)b * N * 256;
    __shared__ float xt[18][256];
    __shared__ float xm[16][256];
    for (int idx = threadIdx.x; idx < 18 * 256; idx += 256) {
        int r = idx >> 8, d = idx & 255;
        int t = t0 + r - 1;
        xt[r][d] = (t >= 0 && t < N) ? xbase[(size_t)t * 256 + d] : -INFINITY;
    }
    __syncthreads();
    for (int idx = threadIdx.x; idx < 16 * 256; idx += 256) {
        int r = idx >> 8, d = idx & 255;
        xm[r][d] = fmaxf(fmaxf(xt[r][d], xt[r + 1][d]), xt[r + 2][d]);
    }
    __syncthreads();
    int f = threadIdx.x & 31;
    int gI = threadIdx.x >> 5;
    float accb[2] = {0.0f, 0.0f}, accm[2] = {0.0f, 0.0f};
    for (int d0 = 0; d0 < 256; d0++) {
        float wb = bwt[d0 * 32 + f];
        float wm = mwt[d0 * 32 + f];
#pragma unroll
        for (int i = 0; i < 2; i++) {
            int tt = gI * 2 + i;
            accb[i] += xt[1 + tt][d0] * wb;
            accm[i] += xm[tt][d0] * wm;
        }
    }
    const float BN_DIV = 1.0000050f;
    float scl = bng[96 + f] / BN_DIV;
    float sh = bnb[96 + f];
    for (int i = 0; i < 2; i++) {
        int t = t0 + gI * 2 + i;
        if (t < N) {
            xb[((size_t)b * N + t) * 32 + f] = accb[i];
            cat[((size_t)b * N + t) * 128 + 96 + f] = gelu_f(accm[i] * scl + sh);
        }
    }
}

// ---------------- time conv: 128 tokens/block, 4 f-cols x 4 tokens per thread ---------
template <int K, int P, int COFF>
__global__ void conv_kernel(const float* __restrict__ xb, const float* __restrict__ wt,
                            const float* __restrict__ bng, const float* __restrict__ bnb,
                            float* __restrict__ cat, int N) {
    int b = blockIdx.y;
    int t0 = blockIdx.x * 128;
    const float* xbase = xb + (size_t)b * N * 32;
    const int ROWS = 128 + K;
    __shared__ float xl[ROWS][33];
    for (int idx = threadIdx.x; idx < ROWS * 32; idx += 256) {
        int r = idx >> 5, f = idx & 31;
        int t = t0 - P + r;
        xl[r][f] = (t >= 0 && t < N) ? xbase[(size_t)t * 32 + f] : 0.0f;
    }
    __syncthreads();
    int fg = threadIdx.x & 7;
    int tg = threadIdx.x >> 3;
    float acc[4][4];
#pragma unroll
    for (int j = 0; j < 4; j++)
#pragma unroll
        for (int c = 0; c < 4; c++) acc[j][c] = 0.0f;
    for (int fi = 0; fi < 32; fi++) {
        float win[4];
#pragma unroll
        for (int j = 0; j < 4; j++) win[j] = xl[tg * 4 + j][fi];
#pragma unroll
        for (int k = 0; k < K; k++) {
            float4 w = ((const float4*)(wt + (fi * K + k) * 32))[fg];
#pragma unroll
            for (int j = 0; j < 4; j++) {
                float xv = win[j];
                acc[j][0] += xv * w.x; acc[j][1] += xv * w.y;
                acc[j][2] += xv * w.z; acc[j][3] += xv * w.w;
            }
#pragma unroll
            for (int j = 0; j < 3; j++) win[j] = win[j + 1];
            win[3] = xl[tg * 4 + k + 4][fi];
        }
    }
    const float BN_DIV = 1.0000050f;
    float4 g4 = ((const float4*)(bng + COFF))[fg];
    float4 b4 = ((const float4*)(bnb + COFF))[fg];
    float sx = g4.x / BN_DIV, sy = g4.y / BN_DIV, sz = g4.z / BN_DIV, sw = g4.w / BN_DIV;
#pragma unroll
    for (int j = 0; j < 4; j++) {
        int t = t0 + tg * 4 + j;
        if (t < N) {
            float4 o;
            o.x = gelu_f(acc[j][0] * sx + b4.x);
            o.y = gelu_f(acc[j][1] * sy + b4.y);
            o.z = gelu_f(acc[j][2] * sz + b4.z);
            o.w = gelu_f(acc[j][3] * sw + b4.w);
            ((float4*)(cat + ((size_t)b * N + t) * 128 + COFF))[fg] = o;
        }
    }
}

// ---------------- proj: 4 cols x 4 tokens per thread, bf16 weights ----------------
__global__ void proj_kernel(const float* __restrict__ cat, const unsigned short* __restrict__ pw,
                            const float* __restrict__ pb, float* __restrict__ A, int TN) {
    int t0 = blockIdx.x * 16;
    __shared__ float cl[16][128];
    for (int v = threadIdx.x; v < 16 * 32; v += 256) {
        int r = v >> 5, c4 = v & 31;
        int t = t0 + r;
        ((float4*)cl[r])[c4] = (t < TN) ? ((const float4*)(cat + (size_t)t * 128))[c4]
                                        : make_float4(0.f, 0.f, 0.f, 0.f);
    }
    __syncthreads();
    int c0 = threadIdx.x & 63;
    int g = threadIdx.x >> 6;
    float acc[4][4];
#pragma unroll
    for (int i = 0; i < 4; i++)
#pragma unroll
        for (int j = 0; j < 4; j++) acc[i][j] = 0.0f;
    for (int f = 0; f < 128; f++) {
        float4 w = bf4_to_f4(((const ushort4*)(pw + (size_t)f * 256))[c0]);
        float v0 = cl[g * 4 + 0][f], v1 = cl[g * 4 + 1][f];
        float v2 = cl[g * 4 + 2][f], v3 = cl[g * 4 + 3][f];
        acc[0][0] += v0 * w.x; acc[0][1] += v0 * w.y; acc[0][2] += v0 * w.z; acc[0][3] += v0 * w.w;
        acc[1][0] += v1 * w.x; acc[1][1] += v1 * w.y; acc[1][2] += v1 * w.z; acc[1][3] += v1 * w.w;
        acc[2][0] += v2 * w.x; acc[2][1] += v2 * w.y; acc[2][2] += v2 * w.z; acc[2][3] += v2 * w.w;
        acc[3][0] += v3 * w.x; acc[3][1] += v3 * w.y; acc[3][2] += v3 * w.z; acc[3][3] += v3 * w.w;
    }
    float4 bias = ((const float4*)pb)[c0];
#pragma unroll
    for (int i = 0; i < 4; i++) {
        int t = t0 + g * 4 + i;
        if (t < TN) {
            float4* ap = (float4*)(A + (size_t)t * 256) + c0;
            float4 a = *ap;
            a.x += acc[i][0] + bias.x; a.y += acc[i][1] + bias.y;
            a.z += acc[i][2] + bias.z; a.w += acc[i][3] + bias.w;
            *ap = a;
        }
    }
}

// ---------------- top-512-of-1023 per batch ----------------
__global__ __launch_bounds__(1024) void topk_kernel(const float* __restrict__ s,
                                                    int* __restrict__ selpos) {
    int b = blockIdx.x;
    int tid = threadIdx.x;
    __shared__ float srt[1024];
    __shared__ int buf[1024];
    __shared__ int Gtot_s;
    float val = (tid < N0) ? s[(size_t)b * N0 + tid] : -INFINITY;
    srt[tid] = val;
    __syncthreads();
    for (int ksz = 2; ksz <= 1024; ksz <<= 1) {
        for (int j = ksz >> 1; j > 0; j >>= 1) {
            int ixj = tid ^ j;
            if (ixj > tid) {
                float a = srt[tid], c = srt[ixj];
                bool up = ((tid & ksz) == 0);
                if ((a > c) == up) { srt[tid] = c; srt[ixj] = a; }
            }
            __syncthreads();
        }
    }
    float thr = srt[512];
    __syncthreads();
    int isG = (val > thr) ? 1 : 0;
    int isE = (val == thr) ? 1 : 0;
    buf[tid] = isG;
    __syncthreads();
    for (int off = 1; off < 1024; off <<= 1) {
        int cur = buf[tid];
        int add = (tid >= off) ? buf[tid - off] : 0;
        __syncthreads();
        buf[tid] = cur + add;
        __syncthreads();
    }
    if (tid == 0) Gtot_s = buf[1023];
    __syncthreads();
    int Gtot = Gtot_s;
    int Eneed = 512 - Gtot;
    buf[tid] = isE;
    __syncthreads();
    for (int off = 1; off < 1024; off <<= 1) {
        int cur = buf[tid];
        int add = (tid >= off) ? buf[tid - off] : 0;
        __syncthreads();
        buf[tid] = cur + add;
        __syncthreads();
    }
    int eqExcl = buf[tid] - isE;
    int sel = (isG || (isE && eqExcl < Eneed)) ? 1 : 0;
    __syncthreads();
    buf[tid] = sel;
    __syncthreads();
    for (int off = 1; off < 1024; off <<= 1) {
        int cur = buf[tid];
        int add = (tid >= off) ? buf[tid - off] : 0;
        __syncthreads();
        buf[tid] = cur + add;
        __syncthreads();
    }
    int pos = buf[tid] - sel;
    selpos[b * 1024 + tid] = sel ? pos : -1;
}

// ---------------- scatter: 4 token-groups x float4; 4 partials per chunk ----------------
__global__ void scatter_kernel(const float* __restrict__ xn, const float* __restrict__ s,
                               const int* __restrict__ selpos, float* __restrict__ A,
                               float* __restrict__ part) {
    int b = blockIdx.y;
    int chunk = blockIdx.x;
    int wid = threadIdx.x >> 6, lane = threadIdx.x & 63;
    int t0 = chunk * 64;
    __shared__ float sl[64];
    __shared__ int pl[64];
    if (threadIdx.x < 64) {
        int t = t0 + threadIdx.x;
        sl[threadIdx.x] = (t < N0) ? s[(size_t)b * N0 + t] : 0.0f;
        pl[threadIdx.x] = (t < N0) ? selpos[b * 1024 + t] : -1;
    }
    __syncthreads();
    const float* xbase = xn + ((size_t)b * N0 + t0) * 256;
    float* obase = A + (size_t)b * N1 * 256;
    float4 nonsel = make_float4(0.f, 0.f, 0.f, 0.f);
    int tmax = (t0 + 64 <= N0) ? 64 : (N0 - t0);
    for (int i = wid; i < tmax; i += 4) {
        float sc = sl[i];
        float4 v = ((const float4*)(xbase + (size_t)i * 256))[lane];
        v.x *= sc; v.y *= sc; v.z *= sc; v.w *= sc;
        int p = pl[i];
        if (p >= 0) ((float4*)(obase + (size_t)p * 256))[lane] = v;
        else { nonsel.x += v.x; nonsel.y += v.y; nonsel.z += v.z; nonsel.w += v.w; }
    }
    ((float4*)(part + ((size_t)(b * GCH + chunk) * 4 + wid) * 256))[lane] = nonsel;
}

// ---------------- reduce chunk partials (64 per batch) -> extra row ----------------
__global__ void extra_kernel(const float* __restrict__ part, float* __restrict__ A) {
    int b = blockIdx.x, d = threadIdx.x;
    float acc = 0.0f;
    for (int c = 0; c < GCH * 4; c++) acc += part[((size_t)b * GCH * 4 + c) * 256 + d];
    A[((size_t)b * N1 + 512) * 256 + d] = acc;
}

// ---------------- gate: one token per thread, block-aggregated routing ----------------
__global__ void gate_kernel(const float* __restrict__ xn2, const float* __restrict__ gw,
                            const float* __restrict__ gb, float* __restrict__ topval,
                            int* __restrict__ buckets, int* __restrict__ counts,
                            float* __restrict__ imp, int T) {
    int tid = threadIdx.x;
    int t = blockIdx.x * 256 + tid;
    __shared__ float4 gws[256];
    __shared__ int lcount[4];
    __shared__ int lbase[4];
    __shared__ float limp[4];
    gws[tid] = ((const float4*)gw)[tid];
    if (tid < 4) { lcount[tid] = 0; limp[tid] = 0.0f; }
    __syncthreads();
    bool valid = (t < T);
    float a0 = 0, a1 = 0, a2 = 0, a3 = 0;
    if (valid) {
        const float4* xb4 = (const float4*)(xn2 + (size_t)t * 256);
#pragma unroll 8
        for (int d4 = 0; d4 < 64; d4++) {
            float4 xv = xb4[d4];
            float4 w0 = gws[4 * d4], w1 = gws[4 * d4 + 1];
            float4 w2 = gws[4 * d4 + 2], w3 = gws[4 * d4 + 3];
            a0 += xv.x * w0.x + xv.y * w1.x + xv.z * w2.x + xv.w * w3.x;
            a1 += xv.x * w0.y + xv.y * w1.y + xv.z * w2.y + xv.w * w3.y;
            a2 += xv.x * w0.z + xv.y * w1.z + xv.z * w2.z + xv.w * w3.z;
            a3 += xv.x * w0.w + xv.y * w1.w + xv.z * w2.w + xv.w * w3.w;
        }
    }
    float q0 = 0, q1 = 0, q2 = 0, q3 = 0;
    int eid = 0;
    int lrank = 0;
    if (valid) {
        float l0 = a0 + gb[0], l1 = a1 + gb[1], l2 = a2 + gb[2], l3 = a3 + gb[3];
        float m = fmaxf(fmaxf(l0, l1), fmaxf(l2, l3));
        float e0 = expf(l0 - m), e1 = expf(l1 - m), e2 = expf(l2 - m), e3 = expf(l3 - m);
        float ssum = e0 + e1 + e2 + e3;
        q0 = e0 / ssum; q1 = e1 / ssum; q2 = e2 / ssum; q3 = e3 / ssum;
        float bv = q0;
        if (q1 > bv) { bv = q1; eid = 1; }
        if (q2 > bv) { bv = q2; eid = 2; }
        if (q3 > bv) { bv = q3; eid = 3; }
        topval[t] = bv;
        lrank = atomicAdd(&lcount[eid], 1);
    }
    float r0 = wave_reduce(q0), r1 = wave_reduce(q1);
    float r2 = wave_reduce(q2), r3 = wave_reduce(q3);
    if ((tid & 63) == 0) {
        atomicAdd(&limp[0], r0); atomicAdd(&limp[1], r1);
        atomicAdd(&limp[2], r2); atomicAdd(&limp[3], r3);
    }
    __syncthreads();
    if (tid < 4) {
        lbase[tid] = atomicAdd(&counts[tid], lcount[tid]);
        atomicAdd(&imp[tid], limp[tid]);
    }
    __syncthreads();
    if (valid) buckets[eid * T + lbase[eid] + lrank] = t;
}

// ---------------- expert FFN: R9 structure, bf16 weights (halves weight bytes) --------
__global__ __launch_bounds__(256, 1)
void ffn_kernel(const float* __restrict__ xn2, const unsigned short* __restrict__ w1,
                const float* __restrict__ b1, const unsigned short* __restrict__ w2,
                const float* __restrict__ b2, const float* __restrict__ topval,
                const int* __restrict__ buckets, const int* __restrict__ counts,
                float* __restrict__ C, int T) {
    int e = blockIdx.y;
    int cnt = counts[e];
    int base = blockIdx.x * 64;
    if (base >= cnt) return;
    __shared__ float tok[64][256];   // 64 KB; mid overwrites after barrier
    __shared__ int tids[64];
    if (threadIdx.x < 64) {
        int idx = base + threadIdx.x;
        tids[threadIdx.x] = (idx < cnt) ? buckets[e * T + idx] : -1;
    }
    __syncthreads();
    for (int v = threadIdx.x; v < 64 * 64; v += 256) {
        int i = v >> 6, c4 = v & 63;
        int t = tids[i];
        ((float4*)tok[i])[c4] = (t >= 0) ? ((const float4*)(xn2 + (size_t)t * 256))[c4]
                                         : make_float4(0.f, 0.f, 0.f, 0.f);
    }
    __syncthreads();
    int c0 = threadIdx.x & 63;   // cols 4*c0 .. 4*c0+3
    int g = threadIdx.x >> 6;    // wave id; tokens 16*g .. 16*g+15
    const unsigned short* W1 = w1 + (size_t)e * 65536;
    const unsigned short* W2 = w2 + (size_t)e * 65536;
    float acc[16][4];
#pragma unroll
    for (int i = 0; i < 16; i++)
#pragma unroll
        for (int j = 0; j < 4; j++) acc[i][j] = 0.0f;
    for (int d0 = 0; d0 < 256; d0 += 4) {
        float4 w[4];
#pragma unroll
        for (int u = 0; u < 4; u++)
            w[u] = bf4_to_f4(((const ushort4*)(W1 + (size_t)(d0 + u) * 256))[c0]);
#pragma unroll
        for (int i = 0; i < 16; i++) {
            float4 v = *((const float4*)&tok[g * 16 + i][d0]);  // wave-uniform -> broadcast
            acc[i][0] += v.x * w[0].x; acc[i][1] += v.x * w[0].y;
            acc[i][2] += v.x * w[0].z; acc[i][3] += v.x * w[0].w;
            acc[i][0] += v.y * w[1].x; acc[i][1] += v.y * w[1].y;
            acc[i][2] += v.y * w[1].z; acc[i][3] += v.y * w[1].w;
            acc[i][0] += v.z * w[2].x; acc[i][1] += v.z * w[2].y;
            acc[i][2] += v.z * w[2].z; acc[i][3] += v.z * w[2].w;
            acc[i][0] += v.w * w[3].x; acc[i][1] += v.w * w[3].y;
            acc[i][2] += v.w * w[3].z; acc[i][3] += v.w * w[3].w;
        }
    }
    float4 bb = ((const float4*)(b1 + (size_t)e * 256))[c0];
    __syncthreads();  // phase-1 reads complete before overwriting tok with mid
#pragma unroll
    for (int i = 0; i < 16; i++) {
        float4 m;
        m.x = gelu_f(acc[i][0] + bb.x); m.y = gelu_f(acc[i][1] + bb.y);
        m.z = gelu_f(acc[i][2] + bb.z); m.w = gelu_f(acc[i][3] + bb.w);
        ((float4*)tok[g * 16 + i])[c0] = m;
    }
    __syncthreads();
#pragma unroll
    for (int i = 0; i < 16; i++)
#pragma unroll
        for (int j = 0; j < 4; j++) acc[i][j] = 0.0f;
    for (int d0 = 0; d0 < 256; d0 += 4) {
        float4 w[4];
#pragma unroll
        for (int u = 0; u < 4; u++)
            w[u] = bf4_to_f4(((const ushort4*)(W2 + (size_t)(d0 + u) * 256))[c0]);
#pragma unroll
        for (int i = 0; i < 16; i++) {
            float4 v = *((const float4*)&tok[g * 16 + i][d0]);
            acc[i][0] += v.x * w[0].x; acc[i][1] += v.x * w[0].y;
            acc[i][2] += v.x * w[0].z; acc[i][3] += v.x * w[0].w;
            acc[i][0] += v.y * w[1].x; acc[i][1] += v.y * w[1].y;
            acc[i][2] += v.y * w[1].z; acc[i][3] += v.y * w[1].w;
            acc[i][0] += v.z * w[2].x; acc[i][1] += v.z * w[2].y;
            acc[i][2] += v.z * w[2].z; acc[i][3] += v.z * w[2].w;
            acc[i][0] += v.w * w[3].x; acc[i][1] += v.w * w[3].y;
            acc[i][2] += v.w * w[3].z; acc[i][3] += v.w * w[3].w;
        }
    }
    float4 bb2 = ((const float4*)(b2 + (size_t)e * 256))[c0];
#pragma unroll
    for (int i = 0; i < 16; i++) {
        int t = tids[g * 16 + i];
        if (t >= 0) {
            float tv = topval[t];
            float4 xv = ((const float4*)(xn2 + (size_t)t * 256))[c0];  // residual re-read (L2)
            float4 o;
            o.x = xv.x + (acc[i][0] + bb2.x) * tv;
            o.y = xv.y + (acc[i][1] + bb2.y) * tv;
            o.z = xv.z + (acc[i][2] + bb2.z) * tv;
            o.w = xv.w + (acc[i][3] + bb2.w) * tv;
            ((float4*)(C + (size_t)t * 256))[c0] = o;
        }
    }
}

// ---------------- wave-per-token: A += gelu(rmsnorm(C, moe_gamma)) ----------------
__global__ void moe_add_kernel(const float* __restrict__ C, float* __restrict__ A,
                               const float* __restrict__ gamma, int T) {
    int wid = threadIdx.x >> 6, lane = threadIdx.x & 63;
    int t = blockIdx.x * 4 + wid;
    if (t >= T) return;
    float4 v = ((const float4*)(C + (size_t)t * 256))[lane];
    float ss = v.x * v.x + v.y * v.y + v.z * v.z + v.w * v.w;
    ss = wave_reduce(ss);
    ss = __shfl(ss, 0, 64);
    float inv = 16.0f / fmaxf(sqrtf(ss), 1e-12f);
    float4 g4 = ((const float4*)gamma)[lane];
    float4* ap = (float4*)(A + (size_t)t * 256) + lane;
    float4 a = *ap;
    a.x += gelu_f(v.x * inv * g4.x); a.y += gelu_f(v.y * inv * g4.y);
    a.z += gelu_f(v.z * inv * g4.z); a.w += gelu_f(v.w * inv * g4.w);
    *ap = a;
}

// ---------------- wave-per-token: end-score attn + head dot -> contribution ----------------
__global__ void endhead_kernel(const float* __restrict__ A, const float* __restrict__ w1,
                               const float* __restrict__ b1, const float* __restrict__ w2,
                               const float* __restrict__ b2, const float* __restrict__ hw,
                               const float* __restrict__ hb, float* __restrict__ contrib,
                               int T) {
    int wid = threadIdx.x >> 6, lane = threadIdx.x & 63;
    int t = blockIdx.x * 4 + wid;
    if (t >= T) return;
    float4 v = ((const float4*)(A + (size_t)t * 256))[lane];
    float p[8];
#pragma unroll
    for (int j = 0; j < 8; j++) p[j] = 0.0f;
    const float xv[4] = {v.x, v.y, v.z, v.w};
#pragma unroll
    for (int c = 0; c < 4; c++) {
        const float4* wr = (const float4*)(w1 + (4 * lane + c) * 8);
        float4 wa = wr[0], wb = wr[1];
        float xx = xv[c];
        p[0] += xx * wa.x; p[1] += xx * wa.y; p[2] += xx * wa.z; p[3] += xx * wa.w;
        p[4] += xx * wb.x; p[5] += xx * wb.y; p[6] += xx * wb.z; p[7] += xx * wb.w;
    }
    float4 h4 = ((const float4*)hw)[lane];
    float hp = gelu_f(v.x) * h4.x + gelu_f(v.y) * h4.y + gelu_f(v.z) * h4.z + gelu_f(v.w) * h4.w;
#pragma unroll
    for (int j = 0; j < 8; j++) p[j] = wave_reduce(p[j]);
    hp = wave_reduce(hp);
    if (lane == 0) {
        float z = b2[0];
#pragma unroll
        for (int j = 0; j < 8; j++) z += tanhf(p[j] + b1[j]) * w2[j];
        float sc = 1.0f / (1.0f + expf(-z));
        contrib[t] = (hp + hb[0]) * sc * (1.0f / (float)N1);
    }
}

// ---------------- per-batch sum of contributions + (block 0) load-balance loss --------
__global__ void finalsum_kernel(const float* __restrict__ contrib,
                                const float* __restrict__ imp, float* __restrict__ out) {
    int b = blockIdx.x, tid = threadIdx.x;
    __shared__ float red[4];
    const float* cb = contrib + (size_t)b * N1;
    float v = cb[tid] + cb[256 + tid];
    if (tid == 0) v += cb[512];
    float s = wave_reduce(v);
    int wid = tid >> 6, lane = tid & 63;
    if (lane == 0) red[wid] = s;
    __syncthreads();
    if (tid == 0) {
        out[b] = red[0] + red[1] + red[2] + red[3];
        if (b == 0) {
            float i0 = imp[0], i1 = imp[1], i2 = imp[2], i3 = imp[3];
            float mean = (i0 + i1 + i2 + i3) * 0.25f;
            float var = ((i0 - mean) * (i0 - mean) + (i1 - mean) * (i1 - mean) +
                         (i2 - mean) * (i2 - mean) + (i3 - mean) * (i3 - mean)) / 3.0f;
            out[64] = var / (mean * mean + 1e-10f);
        }
    }
}

extern "C" void kernel_launch(void* const* d_in, const int* in_sizes, int n_in,
                              void* d_out, int out_size, void* d_ws, size_t ws_size,
                              hipStream_t stream) {
    const float* x    = (const float*)d_in[0];
    const float* embw = (const float*)d_in[3];
    const float* embb = (const float*)d_in[4];
    const float* pos  = (const float*)d_in[5];
    const float* aw1  = (const float*)d_in[6];
    const float* ab1  = (const float*)d_in[7];
    const float* aw2  = (const float*)d_in[8];
    const float* ab2  = (const float*)d_in[9];
    const float* gw   = (const float*)d_in[10];
    const float* gb   = (const float*)d_in[11];
    const float* ew1  = (const float*)d_in[12];
    const float* eb1  = (const float*)d_in[13];
    const float* ew2  = (const float*)d_in[14];
    const float* eb2  = (const float*)d_in[15];
    const float* mg   = (const float*)d_in[16];
    const float* n1g  = (const float*)d_in[17];
    const float* n2g  = (const float*)d_in[18];
    const float* bott = (const float*)d_in[19];
    const float* cw39 = (const float*)d_in[20];
    const float* cw19 = (const float*)d_in[21];
    const float* cw9  = (const float*)d_in[22];
    const float* mpw  = (const float*)d_in[23];
    const float* bng  = (const float*)d_in[24];
    const float* bnb  = (const float*)d_in[25];
    const float* pjw  = (const float*)d_in[26];
    const float* pjb  = (const float*)d_in[27];
    const float* hw   = (const float*)d_in[28];
    const float* hb   = (const float*)d_in[29];
    float* out = (float*)d_out;

    float* W = (float*)d_ws;
    size_t off = 0;
    auto alloc = [&](size_t n) { float* p = W + off; off += n; return p; };
    float* A    = alloc((size_t)NTOK0 * 256);
    float* Bb   = alloc((size_t)NTOK0 * 256);
    float* CD   = alloc((size_t)NTOK1 * 256);
    float* XB   = alloc((size_t)NTOK0 * 32);
    float* sS   = alloc(NTOK0);
    float* ctb  = alloc(NTOK1);
    float* tval = alloc(NTOK1);
    float* imp  = alloc(4);
    float* part = alloc((size_t)BB * GCH * 4 * 256);
    float* wtE  = alloc(128 * 256);
    float* bwt0 = alloc(256 * 32);  float* bwt1 = alloc(256 * 32);
    float* mwt0 = alloc(256 * 32);  float* mwt1 = alloc(256 * 32);
    float* c39t0 = alloc(1248 * 32); float* c39t1 = alloc(1248 * 32);
    float* c19t0 = alloc(608 * 32);  float* c19t1 = alloc(608 * 32);
    float* c9t0  = alloc(288 * 32);  float* c9t1  = alloc(288 * 32);
    if (off & 1) off++;  // 8B-align for ushort4 loads
    unsigned short* ew1b = (unsigned short*)(W + off); off += 262144 / 2;
    unsigned short* ew2b = (unsigned short*)(W + off); off += 262144 / 2;
    unsigned short* pjwb = (unsigned short*)(W + off); off += 65536 / 2;
    int* selpos  = (int*)(W + off); off += (size_t)BB * 1024;
    int* buckets = (int*)(W + off); off += (size_t)4 * NTOK1;
    int* counts  = (int*)(W + off); off += 4;

    zero_kernel<<<1, 64, 0, stream>>>(imp, counts);
    transpose_fused<<<792, 256, 0, stream>>>(embw, wtE, bott, bwt0, bwt1, mpw, mwt0, mwt1,
                                             cw39, c39t0, c39t1, cw19, c19t0, c19t1,
                                             cw9, c9t0, c9t1);
    convert_bf16<<<2304, 256, 0, stream>>>(ew1, ew2, pjw, ew1b, ew2b, pjwb);

    // ===== layer 0 (N=1023) =====
    embed_kernel<<<dim3(64, BB), 256, 0, stream>>>(x, wtE, embb, pos, A);
    norm_attn_kernel<<<NTOK0 / 4, 256, 0, stream>>>(A, A, nullptr, n1g, aw1, ab1, aw2, ab2,
                                                    1, 0, Bb, n2g, NTOK0);
    pw_kernel<<<dim3(64, BB), 256, 0, stream>>>(Bb, bwt0, mwt0, bng, bnb, XB, CD, N0);
    conv_kernel<39, 19, 0><<<dim3(8, BB), 256, 0, stream>>>(XB, c39t0, bng, bnb, CD, N0);
    conv_kernel<19, 9, 32><<<dim3(8, BB), 256, 0, stream>>>(XB, c19t0, bng, bnb, CD, N0);
    conv_kernel<9, 4, 64><<<dim3(8, BB), 256, 0, stream>>>(XB, c9t0, bng, bnb, CD, N0);
    proj_kernel<<<(NTOK0 + 15) / 16, 256, 0, stream>>>(CD, pjwb, pjb, A, NTOK0);

    // ===== layer 1 (prune to 513 tokens); gelu fused into load =====
    norm_attn_kernel<<<NTOK0 / 4, 256, 0, stream>>>(A, Bb, sS, n1g + 256, aw1, ab1, aw2, ab2,
                                                    0, 1, nullptr, nullptr, NTOK0);
    topk_kernel<<<BB, 1024, 0, stream>>>(sS, selpos);
    scatter_kernel<<<dim3(GCH, BB), 256, 0, stream>>>(Bb, sS, selpos, A, part);
    extra_kernel<<<BB, 256, 0, stream>>>(part, A);
    rmsnorm_kernel<<<NTOK1 / 4, 256, 0, stream>>>(A, Bb, n2g + 256, NTOK1);
    gate_kernel<<<(NTOK1 + 255) / 256, 256, 0, stream>>>(Bb, gw, gb, tval, buckets, counts, imp,
                                                         NTOK1);
    ffn_kernel<<<dim3((NTOK1 + 63) / 64, 4), 256, 0, stream>>>(Bb, ew1b, eb1, ew2b, eb2, tval,
                                                               buckets, counts, CD, NTOK1);
    moe_add_kernel<<<NTOK1 / 4, 256, 0, stream>>>(CD, A, mg, NTOK1);
    pw_kernel<<<dim3((N1 + 15) / 16, BB), 256, 0, stream>>>(Bb, bwt1, mwt1, bng + 128, bnb + 128,
                                                            XB, CD, N1);
    conv_kernel<39, 19, 0><<<dim3(5, BB), 256, 0, stream>>>(XB, c39t1, bng + 128, bnb + 128,
                                                            CD, N1);
    conv_kernel<19, 9, 32><<<dim3(5, BB), 256, 0, stream>>>(XB, c19t1, bng + 128, bnb + 128,
                                                            CD, N1);
    conv_kernel<9, 4, 64><<<dim3(5, BB), 256, 0, stream>>>(XB, c9t1, bng + 128, bnb + 128,
                                                           CD, N1);
    proj_kernel<<<(NTOK1 + 15) / 16, 256, 0, stream>>>(CD, pjwb + 32768, pjb + 256, A, NTOK1);
    endhead_kernel<<<NTOK1 / 4, 256, 0, stream>>>(A, aw1, ab1, aw2, ab2, hw, hb, ctb, NTOK1);
    finalsum_kernel<<<BB, 256, 0, stream>>>(ctb, imp, out);
}

// Round 14
// 1215.848 us; speedup vs baseline: 1.1753x; 1.0084x over previous
//
#include <hip/hip_runtime.h>
#include <math.h>

#define BB 64
#define EMB 256
#define N0 1023
#define N1 513
#define NTOK0 (BB * N0)   // 65472
#define NTOK1 (BB * N1)   // 32832
#define GCH 16            // gather chunks per batch

__device__ __forceinline__ float gelu_f(float x) {
    return 0.5f * x * (1.0f + erff(x * 0.7071067811865476f));
}

__device__ __forceinline__ float4 gelu4(float4 v) {
    return make_float4(gelu_f(v.x), gelu_f(v.y), gelu_f(v.z), gelu_f(v.w));
}

__device__ __forceinline__ float wave_reduce(float v) {
#pragma unroll
    for (int o = 32; o > 0; o >>= 1) v += __shfl_down(v, o, 64);
    return v;
}

// bf16 helpers: pack with round-to-nearest-even; unpack = shift
__device__ __forceinline__ unsigned short f2bf(float f) {
    unsigned int u = __float_as_uint(f);
    u = (u + 0x7FFFu + ((u >> 16) & 1u)) >> 16;
    return (unsigned short)u;
}
__device__ __forceinline__ float bf2f(unsigned short h) {
    return __uint_as_float(((unsigned int)h) << 16);
}
__device__ __forceinline__ float4 bf4_to_f4(ushort4 h) {
    return make_float4(bf2f(h.x), bf2f(h.y), bf2f(h.z), bf2f(h.w));
}

// ---------------- fused weight transposes: in[o][ik] -> out[ik*O + o] ----------------
__global__ void transpose_fused(const float* __restrict__ embw, float* __restrict__ wtE,
                                const float* __restrict__ bott, float* __restrict__ bwt0,
                                float* __restrict__ bwt1,
                                const float* __restrict__ mpw, float* __restrict__ mwt0,
                                float* __restrict__ mwt1,
                                const float* __restrict__ cw39, float* __restrict__ c39t0,
                                float* __restrict__ c39t1,
                                const float* __restrict__ cw19, float* __restrict__ c19t0,
                                float* __restrict__ c19t1,
                                const float* __restrict__ cw9, float* __restrict__ c9t0,
                                float* __restrict__ c9t1) {
    int idx = blockIdx.x * 256 + threadIdx.x;
    const float* src; float* dst; int O, IK, base;
    if (idx < 32768)       { src = embw;         dst = wtE;   O = 256; IK = 128;  base = 0; }
    else if (idx < 40960)  { src = bott;         dst = bwt0;  O = 32;  IK = 256;  base = 32768; }
    else if (idx < 49152)  { src = bott + 8192;  dst = bwt1;  O = 32;  IK = 256;  base = 40960; }
    else if (idx < 57344)  { src = mpw;          dst = mwt0;  O = 32;  IK = 256;  base = 49152; }
    else if (idx < 65536)  { src = mpw + 8192;   dst = mwt1;  O = 32;  IK = 256;  base = 57344; }
    else if (idx < 105472) { src = cw39;         dst = c39t0; O = 32;  IK = 1248; base = 65536; }
    else if (idx < 145408) { src = cw39 + 39936; dst = c39t1; O = 32;  IK = 1248; base = 105472; }
    else if (idx < 164864) { src = cw19;         dst = c19t0; O = 32;  IK = 608;  base = 145408; }
    else if (idx < 184320) { src = cw19 + 19456; dst = c19t1; O = 32;  IK = 608;  base = 164864; }
    else if (idx < 193536) { src = cw9;          dst = c9t0;  O = 32;  IK = 288;  base = 184320; }
    else if (idx < 202752) { src = cw9 + 9216;   dst = c9t1;  O = 32;  IK = 288;  base = 193536; }
    else return;
    int local = idx - base;
    int o = local / IK, ik = local % IK;
    dst[ik * O + o] = src[local];
}

// ---------------- convert ffn/proj weights to bf16 ----------------
__global__ void convert_bf16(const float* __restrict__ ew1, const float* __restrict__ ew2,
                             const float* __restrict__ pjw, unsigned short* __restrict__ ew1b,
                             unsigned short* __restrict__ ew2b,
                             unsigned short* __restrict__ pjwb) {
    int idx = blockIdx.x * 256 + threadIdx.x;
    if (idx < 262144) ew1b[idx] = f2bf(ew1[idx]);
    else if (idx < 524288) ew2b[idx - 262144] = f2bf(ew2[idx - 262144]);
    else if (idx < 589824) pjwb[idx - 524288] = f2bf(pjw[idx - 524288]);
}

// ---------------- zero accumulators ----------------
__global__ void zero_kernel(float* __restrict__ imp, int* __restrict__ counts) {
    int i = threadIdx.x;
    if (i < 4) { imp[i] = 0.0f; counts[i] = 0; }
}

// ---------------- embedding conv (stride 4, K=8, C=16) + bias + pos ----------------
__global__ void embed_kernel(const float* __restrict__ x, const float* __restrict__ wt,
                             const float* __restrict__ emb_b, const float* __restrict__ pos,
                             float* __restrict__ A) {
    int b = blockIdx.y;
    int n0 = blockIdx.x * 16;
    __shared__ float xl[16][68];
    int l0 = 4 * n0;
    for (int idx = threadIdx.x; idx < 16 * 68; idx += 256) {
        int c = idx / 68, j = idx % 68;
        int l = l0 + j;
        xl[c][j] = (l < 4096) ? x[((size_t)b * 16 + c) * 4096 + l] : 0.0f;
    }
    __syncthreads();
    int e = threadIdx.x;
    float acc[16];
#pragma unroll
    for (int i = 0; i < 16; i++) acc[i] = 0.0f;
    for (int k = 0; k < 128; k++) {
        float w = wt[k * 256 + e];
        int c = k >> 3, s = k & 7;
#pragma unroll
        for (int i = 0; i < 16; i++) acc[i] += xl[c][4 * i + s] * w;
    }
    float bb = emb_b[e];
    for (int i = 0; i < 16; i++) {
        int n = n0 + i;
        if (n < N0)
            A[((size_t)b * N0 + n) * 256 + e] = acc[i] + bb + pos[(size_t)n * 256 + e];
    }
}

// ---------------- wave-per-token: rmsnorm + attn score (+pregelu, +second norm) ------
__global__ void norm_attn_kernel(const float* __restrict__ in, float* __restrict__ outv,
                                 float* __restrict__ score_out, const float* __restrict__ g,
                                 const float* __restrict__ w1, const float* __restrict__ b1,
                                 const float* __restrict__ w2, const float* __restrict__ b2,
                                 int scale_out, int pregelu,
                                 float* __restrict__ outv2, const float* __restrict__ g2,
                                 int T) {
    int wid = threadIdx.x >> 6, lane = threadIdx.x & 63;
    int t = blockIdx.x * 4 + wid;
    if (t >= T) return;
    float4 v = ((const float4*)(in + (size_t)t * 256))[lane];
    if (pregelu) v = gelu4(v);
    float4 xn = v;
    if (g != nullptr) {
        float ss = v.x * v.x + v.y * v.y + v.z * v.z + v.w * v.w;
        ss = wave_reduce(ss);
        ss = __shfl(ss, 0, 64);
        float inv = 16.0f / fmaxf(sqrtf(ss), 1e-12f);
        float4 g4 = ((const float4*)g)[lane];
        xn.x = v.x * inv * g4.x; xn.y = v.y * inv * g4.y;
        xn.z = v.z * inv * g4.z; xn.w = v.w * inv * g4.w;
    }
    float p[8];
#pragma unroll
    for (int j = 0; j < 8; j++) p[j] = 0.0f;
    const float xv[4] = {xn.x, xn.y, xn.z, xn.w};
#pragma unroll
    for (int c = 0; c < 4; c++) {
        const float4* wr = (const float4*)(w1 + (4 * lane + c) * 8);
        float4 wa = wr[0], wb = wr[1];
        float xx = xv[c];
        p[0] += xx * wa.x; p[1] += xx * wa.y; p[2] += xx * wa.z; p[3] += xx * wa.w;
        p[4] += xx * wb.x; p[5] += xx * wb.y; p[6] += xx * wb.z; p[7] += xx * wb.w;
    }
#pragma unroll
    for (int j = 0; j < 8; j++) p[j] = wave_reduce(p[j]);
    float sc = 0.0f;
    if (lane == 0) {
        float z = b2[0];
#pragma unroll
        for (int j = 0; j < 8; j++) z += tanhf(p[j] + b1[j]) * w2[j];
        sc = 1.0f / (1.0f + expf(-z));
        if (score_out) score_out[t] = sc;
    }
    sc = __shfl(sc, 0, 64);
    if (outv) {
        float m = scale_out ? sc : 1.0f;
        float4 o = make_float4(xn.x * m, xn.y * m, xn.z * m, xn.w * m);
        ((float4*)(outv + (size_t)t * 256))[lane] = o;
    }
    if (outv2) {
        float ss2 = xn.x * xn.x + xn.y * xn.y + xn.z * xn.z + xn.w * xn.w;
        ss2 = wave_reduce(ss2);
        ss2 = __shfl(ss2, 0, 64);
        float inv2 = 16.0f / fmaxf(sqrtf(ss2), 1e-12f);
        float4 q4 = ((const float4*)g2)[lane];
        float4 o;
        o.x = xn.x * inv2 * q4.x; o.y = xn.y * inv2 * q4.y;
        o.z = xn.z * inv2 * q4.z; o.w = xn.w * inv2 * q4.w;
        ((float4*)(outv2 + (size_t)t * 256))[lane] = o;
    }
}

// ---------------- wave-per-token rmsnorm ----------------
__global__ void rmsnorm_kernel(const float* __restrict__ in, float* __restrict__ out,
                               const float* __restrict__ g, int T) {
    int wid = threadIdx.x >> 6, lane = threadIdx.x & 63;
    int t = blockIdx.x * 4 + wid;
    if (t >= T) return;
    float4 v = ((const float4*)(in + (size_t)t * 256))[lane];
    float ss = v.x * v.x + v.y * v.y + v.z * v.z + v.w * v.w;
    ss = wave_reduce(ss);
    ss = __shfl(ss, 0, 64);
    float inv = 16.0f / fmaxf(sqrtf(ss), 1e-12f);
    float4 g4 = ((const float4*)g)[lane];
    float4 o;
    o.x = v.x * inv * g4.x; o.y = v.y * inv * g4.y;
    o.z = v.z * inv * g4.z; o.w = v.w * inv * g4.w;
    ((float4*)(out + (size_t)t * 256))[lane] = o;
}

// ---------------- pointwise: bottleneck + maxpool path (round-5 proven version) -------
__global__ void pw_kernel(const float* __restrict__ xn, const float* __restrict__ bwt,
                          const float* __restrict__ mwt, const float* __restrict__ bng,
                          const float* __restrict__ bnb, float* __restrict__ xb,
                          float* __restrict__ cat, int N) {
    int b = blockIdx.y;
    int t0 = blockIdx.x * 16;
    const float* xbase = xn + (size_t)b * N * 256;
    __shared__ float xt[18][256];
    __shared__ float xm[16][256];
    for (int idx = threadIdx.x; idx < 18 * 256; idx += 256) {
        int r = idx >> 8, d = idx & 255;
        int t = t0 + r - 1;
        xt[r][d] = (t >= 0 && t < N) ? xbase[(size_t)t * 256 + d] : -INFINITY;
    }
    __syncthreads();
    for (int idx = threadIdx.x; idx < 16 * 256; idx += 256) {
        int r = idx >> 8, d = idx & 255;
        xm[r][d] = fmaxf(fmaxf(xt[r][d], xt[r + 1][d]), xt[r + 2][d]);
    }
    __syncthreads();
    int f = threadIdx.x & 31;
    int gI = threadIdx.x >> 5;
    float accb[2] = {0.0f, 0.0f}, accm[2] = {0.0f, 0.0f};
    for (int d0 = 0; d0 < 256; d0++) {
        float wb = bwt[d0 * 32 + f];
        float wm = mwt[d0 * 32 + f];
#pragma unroll
        for (int i = 0; i < 2; i++) {
            int tt = gI * 2 + i;
            accb[i] += xt[1 + tt][d0] * wb;
            accm[i] += xm[tt][d0] * wm;
        }
    }
    const float BN_DIV = 1.0000050f;
    float scl = bng[96 + f] / BN_DIV;
    float sh = bnb[96 + f];
    for (int i = 0; i < 2; i++) {
        int t = t0 + gI * 2 + i;
        if (t < N) {
            xb[((size_t)b * N + t) * 32 + f] = accb[i];
            cat[((size_t)b * N + t) * 128 + 96 + f] = gelu_f(accm[i] * scl + sh);
        }
    }
}

// ---------------- time conv: 128 tokens/block, 4 f-cols x 4 tokens per thread ---------
template <int K, int P, int COFF>
__global__ void conv_kernel(const float* __restrict__ xb, const float* __restrict__ wt,
                            const float* __restrict__ bng, const float* __restrict__ bnb,
                            float* __restrict__ cat, int N) {
    int b = blockIdx.y;
    int t0 = blockIdx.x * 128;
    const float* xbase = xb + (size_t)b * N * 32;
    const int ROWS = 128 + K;
    __shared__ float xl[ROWS][33];
    for (int idx = threadIdx.x; idx < ROWS * 32; idx += 256) {
        int r = idx >> 5, f = idx & 31;
        int t = t0 - P + r;
        xl[r][f] = (t >= 0 && t < N) ? xbase[(size_t)t * 32 + f] : 0.0f;
    }
    __syncthreads();
    int fg = threadIdx.x & 7;
    int tg = threadIdx.x >> 3;
    float acc[4][4];
#pragma unroll
    for (int j = 0; j < 4; j++)
#pragma unroll
        for (int c = 0; c < 4; c++) acc[j][c] = 0.0f;
    for (int fi = 0; fi < 32; fi++) {
        float win[4];
#pragma unroll
        for (int j = 0; j < 4; j++) win[j] = xl[tg * 4 + j][fi];
#pragma unroll
        for (int k = 0; k < K; k++) {
            float4 w = ((const float4*)(wt + (fi * K + k) * 32))[fg];
#pragma unroll
            for (int j = 0; j < 4; j++) {
                float xv = win[j];
                acc[j][0] += xv * w.x; acc[j][1] += xv * w.y;
                acc[j][2] += xv * w.z; acc[j][3] += xv * w.w;
            }
#pragma unroll
            for (int j = 0; j < 3; j++) win[j] = win[j + 1];
            win[3] = xl[tg * 4 + k + 4][fi];
        }
    }
    const float BN_DIV = 1.0000050f;
    float4 g4 = ((const float4*)(bng + COFF))[fg];
    float4 b4 = ((const float4*)(bnb + COFF))[fg];
    float sx = g4.x / BN_DIV, sy = g4.y / BN_DIV, sz = g4.z / BN_DIV, sw = g4.w / BN_DIV;
#pragma unroll
    for (int j = 0; j < 4; j++) {
        int t = t0 + tg * 4 + j;
        if (t < N) {
            float4 o;
            o.x = gelu_f(acc[j][0] * sx + b4.x);
            o.y = gelu_f(acc[j][1] * sy + b4.y);
            o.z = gelu_f(acc[j][2] * sz + b4.z);
            o.w = gelu_f(acc[j][3] * sw + b4.w);
            ((float4*)(cat + ((size_t)b * N + t) * 128 + COFF))[fg] = o;
        }
    }
}

// ---------------- proj: 4 cols x 4 tokens per thread, bf16 weights ----------------
__global__ void proj_kernel(const float* __restrict__ cat, const unsigned short* __restrict__ pw,
                            const float* __restrict__ pb, float* __restrict__ A, int TN) {
    int t0 = blockIdx.x * 16;
    __shared__ float cl[16][128];
    for (int v = threadIdx.x; v < 16 * 32; v += 256) {
        int r = v >> 5, c4 = v & 31;
        int t = t0 + r;
        ((float4*)cl[r])[c4] = (t < TN) ? ((const float4*)(cat + (size_t)t * 128))[c4]
                                        : make_float4(0.f, 0.f, 0.f, 0.f);
    }
    __syncthreads();
    int c0 = threadIdx.x & 63;
    int g = threadIdx.x >> 6;
    float acc[4][4];
#pragma unroll
    for (int i = 0; i < 4; i++)
#pragma unroll
        for (int j = 0; j < 4; j++) acc[i][j] = 0.0f;
    for (int f = 0; f < 128; f++) {
        float4 w = bf4_to_f4(((const ushort4*)(pw + (size_t)f * 256))[c0]);
        float v0 = cl[g * 4 + 0][f], v1 = cl[g * 4 + 1][f];
        float v2 = cl[g * 4 + 2][f], v3 = cl[g * 4 + 3][f];
        acc[0][0] += v0 * w.x; acc[0][1] += v0 * w.y; acc[0][2] += v0 * w.z; acc[0][3] += v0 * w.w;
        acc[1][0] += v1 * w.x; acc[1][1] += v1 * w.y; acc[1][2] += v1 * w.z; acc[1][3] += v1 * w.w;
        acc[2][0] += v2 * w.x; acc[2][1] += v2 * w.y; acc[2][2] += v2 * w.z; acc[2][3] += v2 * w.w;
        acc[3][0] += v3 * w.x; acc[3][1] += v3 * w.y; acc[3][2] += v3 * w.z; acc[3][3] += v3 * w.w;
    }
    float4 bias = ((const float4*)pb)[c0];
#pragma unroll
    for (int i = 0; i < 4; i++) {
        int t = t0 + g * 4 + i;
        if (t < TN) {
            float4* ap = (float4*)(A + (size_t)t * 256) + c0;
            float4 a = *ap;
            a.x += acc[i][0] + bias.x; a.y += acc[i][1] + bias.y;
            a.z += acc[i][2] + bias.z; a.w += acc[i][3] + bias.w;
            *ap = a;
        }
    }
}

// ---------------- top-512-of-1023 per batch ----------------
__global__ __launch_bounds__(1024) void topk_kernel(const float* __restrict__ s,
                                                    int* __restrict__ selpos) {
    int b = blockIdx.x;
    int tid = threadIdx.x;
    __shared__ float srt[1024];
    __shared__ int buf[1024];
    __shared__ int Gtot_s;
    float val = (tid < N0) ? s[(size_t)b * N0 + tid] : -INFINITY;
    srt[tid] = val;
    __syncthreads();
    for (int ksz = 2; ksz <= 1024; ksz <<= 1) {
        for (int j = ksz >> 1; j > 0; j >>= 1) {
            int ixj = tid ^ j;
            if (ixj > tid) {
                float a = srt[tid], c = srt[ixj];
                bool up = ((tid & ksz) == 0);
                if ((a > c) == up) { srt[tid] = c; srt[ixj] = a; }
            }
            __syncthreads();
        }
    }
    float thr = srt[512];
    __syncthreads();
    int isG = (val > thr) ? 1 : 0;
    int isE = (val == thr) ? 1 : 0;
    buf[tid] = isG;
    __syncthreads();
    for (int off = 1; off < 1024; off <<= 1) {
        int cur = buf[tid];
        int add = (tid >= off) ? buf[tid - off] : 0;
        __syncthreads();
        buf[tid] = cur + add;
        __syncthreads();
    }
    if (tid == 0) Gtot_s = buf[1023];
    __syncthreads();
    int Gtot = Gtot_s;
    int Eneed = 512 - Gtot;
    buf[tid] = isE;
    __syncthreads();
    for (int off = 1; off < 1024; off <<= 1) {
        int cur = buf[tid];
        int add = (tid >= off) ? buf[tid - off] : 0;
        __syncthreads();
        buf[tid] = cur + add;
        __syncthreads();
    }
    int eqExcl = buf[tid] - isE;
    int sel = (isG || (isE && eqExcl < Eneed)) ? 1 : 0;
    __syncthreads();
    buf[tid] = sel;
    __syncthreads();
    for (int off = 1; off < 1024; off <<= 1) {
        int cur = buf[tid];
        int add = (tid >= off) ? buf[tid - off] : 0;
        __syncthreads();
        buf[tid] = cur + add;
        __syncthreads();
    }
    int pos = buf[tid] - sel;
    selpos[b * 1024 + tid] = sel ? pos : -1;
}

// ---------------- scatter: 4 token-groups x float4; 4 partials per chunk ----------------
__global__ void scatter_kernel(const float* __restrict__ xn, const float* __restrict__ s,
                               const int* __restrict__ selpos, float* __restrict__ A,
                               float* __restrict__ part) {
    int b = blockIdx.y;
    int chunk = blockIdx.x;
    int wid = threadIdx.x >> 6, lane = threadIdx.x & 63;
    int t0 = chunk * 64;
    __shared__ float sl[64];
    __shared__ int pl[64];
    if (threadIdx.x < 64) {
        int t = t0 + threadIdx.x;
        sl[threadIdx.x] = (t < N0) ? s[(size_t)b * N0 + t] : 0.0f;
        pl[threadIdx.x] = (t < N0) ? selpos[b * 1024 + t] : -1;
    }
    __syncthreads();
    const float* xbase = xn + ((size_t)b * N0 + t0) * 256;
    float* obase = A + (size_t)b * N1 * 256;
    float4 nonsel = make_float4(0.f, 0.f, 0.f, 0.f);
    int tmax = (t0 + 64 <= N0) ? 64 : (N0 - t0);
    for (int i = wid; i < tmax; i += 4) {
        float sc = sl[i];
        float4 v = ((const float4*)(xbase + (size_t)i * 256))[lane];
        v.x *= sc; v.y *= sc; v.z *= sc; v.w *= sc;
        int p = pl[i];
        if (p >= 0) ((float4*)(obase + (size_t)p * 256))[lane] = v;
        else { nonsel.x += v.x; nonsel.y += v.y; nonsel.z += v.z; nonsel.w += v.w; }
    }
    ((float4*)(part + ((size_t)(b * GCH + chunk) * 4 + wid) * 256))[lane] = nonsel;
}

// ---------------- reduce chunk partials (64 per batch) -> extra row ----------------
__global__ void extra_kernel(const float* __restrict__ part, float* __restrict__ A) {
    int b = blockIdx.x, d = threadIdx.x;
    float acc = 0.0f;
    for (int c = 0; c < GCH * 4; c++) acc += part[((size_t)b * GCH * 4 + c) * 256 + d];
    A[((size_t)b * N1 + 512) * 256 + d] = acc;
}

// ---------------- gate: one token per thread, block-aggregated routing ----------------
__global__ void gate_kernel(const float* __restrict__ xn2, const float* __restrict__ gw,
                            const float* __restrict__ gb, float* __restrict__ topval,
                            int* __restrict__ buckets, int* __restrict__ counts,
                            float* __restrict__ imp, int T) {
    int tid = threadIdx.x;
    int t = blockIdx.x * 256 + tid;
    __shared__ float4 gws[256];
    __shared__ int lcount[4];
    __shared__ int lbase[4];
    __shared__ float limp[4];
    gws[tid] = ((const float4*)gw)[tid];
    if (tid < 4) { lcount[tid] = 0; limp[tid] = 0.0f; }
    __syncthreads();
    bool valid = (t < T);
    float a0 = 0, a1 = 0, a2 = 0, a3 = 0;
    if (valid) {
        const float4* xb4 = (const float4*)(xn2 + (size_t)t * 256);
#pragma unroll 8
        for (int d4 = 0; d4 < 64; d4++) {
            float4 xv = xb4[d4];
            float4 w0 = gws[4 * d4], w1 = gws[4 * d4 + 1];
            float4 w2 = gws[4 * d4 + 2], w3 = gws[4 * d4 + 3];
            a0 += xv.x * w0.x + xv.y * w1.x + xv.z * w2.x + xv.w * w3.x;
            a1 += xv.x * w0.y + xv.y * w1.y + xv.z * w2.y + xv.w * w3.y;
            a2 += xv.x * w0.z + xv.y * w1.z + xv.z * w2.z + xv.w * w3.z;
            a3 += xv.x * w0.w + xv.y * w1.w + xv.z * w2.w + xv.w * w3.w;
        }
    }
    float q0 = 0, q1 = 0, q2 = 0, q3 = 0;
    int eid = 0;
    int lrank = 0;
    if (valid) {
        float l0 = a0 + gb[0], l1 = a1 + gb[1], l2 = a2 + gb[2], l3 = a3 + gb[3];
        float m = fmaxf(fmaxf(l0, l1), fmaxf(l2, l3));
        float e0 = expf(l0 - m), e1 = expf(l1 - m), e2 = expf(l2 - m), e3 = expf(l3 - m);
        float ssum = e0 + e1 + e2 + e3;
        q0 = e0 / ssum; q1 = e1 / ssum; q2 = e2 / ssum; q3 = e3 / ssum;
        float bv = q0;
        if (q1 > bv) { bv = q1; eid = 1; }
        if (q2 > bv) { bv = q2; eid = 2; }
        if (q3 > bv) { bv = q3; eid = 3; }
        topval[t] = bv;
        lrank = atomicAdd(&lcount[eid], 1);
    }
    float r0 = wave_reduce(q0), r1 = wave_reduce(q1);
    float r2 = wave_reduce(q2), r3 = wave_reduce(q3);
    if ((tid & 63) == 0) {
        atomicAdd(&limp[0], r0); atomicAdd(&limp[1], r1);
        atomicAdd(&limp[2], r2); atomicAdd(&limp[3], r3);
    }
    __syncthreads();
    if (tid < 4) {
        lbase[tid] = atomicAdd(&counts[tid], lcount[tid]);
        atomicAdd(&imp[tid], limp[tid]);
    }
    __syncthreads();
    if (valid) buckets[eid * T + lbase[eid] + lrank] = t;
}

// ---------------- expert FFN: 512 threads = 8 waves x 8 tokens, bf16 weights.
// 2 waves/SIMD to hide ds_read stalls; weight stream/wave halves vs R7-style. ----------
__global__ __launch_bounds__(512, 1)
void ffn_kernel(const float* __restrict__ xn2, const unsigned short* __restrict__ w1,
                const float* __restrict__ b1, const unsigned short* __restrict__ w2,
                const float* __restrict__ b2, const float* __restrict__ topval,
                const int* __restrict__ buckets, const int* __restrict__ counts,
                float* __restrict__ C, int T) {
    int e = blockIdx.y;
    int cnt = counts[e];
    int base = blockIdx.x * 64;
    if (base >= cnt) return;
    __shared__ float tok[64][256];   // 64 KB; mid overwrites after barrier
    __shared__ int tids[64];
    if (threadIdx.x < 64) {
        int idx = base + threadIdx.x;
        tids[threadIdx.x] = (idx < cnt) ? buckets[e * T + idx] : -1;
    }
    __syncthreads();
    for (int v = threadIdx.x; v < 64 * 64; v += 512) {
        int i = v >> 6, c4 = v & 63;
        int t = tids[i];
        ((float4*)tok[i])[c4] = (t >= 0) ? ((const float4*)(xn2 + (size_t)t * 256))[c4]
                                         : make_float4(0.f, 0.f, 0.f, 0.f);
    }
    __syncthreads();
    int c0 = threadIdx.x & 63;   // cols 4*c0 .. 4*c0+3
    int g = threadIdx.x >> 6;    // wave id 0..7; tokens 8*g .. 8*g+7
    const unsigned short* W1 = w1 + (size_t)e * 65536;
    const unsigned short* W2 = w2 + (size_t)e * 65536;
    float acc[8][4];
#pragma unroll
    for (int i = 0; i < 8; i++)
#pragma unroll
        for (int j = 0; j < 4; j++) acc[i][j] = 0.0f;
    for (int d0 = 0; d0 < 256; d0 += 4) {
        float4 w[4];
#pragma unroll
        for (int u = 0; u < 4; u++)
            w[u] = bf4_to_f4(((const ushort4*)(W1 + (size_t)(d0 + u) * 256))[c0]);
#pragma unroll
        for (int i = 0; i < 8; i++) {
            float4 v = *((const float4*)&tok[g * 8 + i][d0]);  // wave-uniform -> broadcast
            acc[i][0] += v.x * w[0].x; acc[i][1] += v.x * w[0].y;
            acc[i][2] += v.x * w[0].z; acc[i][3] += v.x * w[0].w;
            acc[i][0] += v.y * w[1].x; acc[i][1] += v.y * w[1].y;
            acc[i][2] += v.y * w[1].z; acc[i][3] += v.y * w[1].w;
            acc[i][0] += v.z * w[2].x; acc[i][1] += v.z * w[2].y;
            acc[i][2] += v.z * w[2].z; acc[i][3] += v.z * w[2].w;
            acc[i][0] += v.w * w[3].x; acc[i][1] += v.w * w[3].y;
            acc[i][2] += v.w * w[3].z; acc[i][3] += v.w * w[3].w;
        }
    }
    float4 bb = ((const float4*)(b1 + (size_t)e * 256))[c0];
    __syncthreads();  // phase-1 reads complete before overwriting tok with mid
#pragma unroll
    for (int i = 0; i < 8; i++) {
        float4 m;
        m.x = gelu_f(acc[i][0] + bb.x); m.y = gelu_f(acc[i][1] + bb.y);
        m.z = gelu_f(acc[i][2] + bb.z); m.w = gelu_f(acc[i][3] + bb.w);
        ((float4*)tok[g * 8 + i])[c0] = m;
    }
    __syncthreads();
#pragma unroll
    for (int i = 0; i < 8; i++)
#pragma unroll
        for (int j = 0; j < 4; j++) acc[i][j] = 0.0f;
    for (int d0 = 0; d0 < 256; d0 += 4) {
        float4 w[4];
#pragma unroll
        for (int u = 0; u < 4; u++)
            w[u] = bf4_to_f4(((const ushort4*)(W2 + (size_t)(d0 + u) * 256))[c0]);
#pragma unroll
        for (int i = 0; i < 8; i++) {
            float4 v = *((const float4*)&tok[g * 8 + i][d0]);
            acc[i][0] += v.x * w[0].x; acc[i][1] += v.x * w[0].y;
            acc[i][2] += v.x * w[0].z; acc[i][3] += v.x * w[0].w;
            acc[i][0] += v.y * w[1].x; acc[i][1] += v.y * w[1].y;
            acc[i][2] += v.y * w[1].z; acc[i][3] += v.y * w[1].w;
            acc[i][0] += v.z * w[2].x; acc[i][1] += v.z * w[2].y;
            acc[i][2] += v.z * w[2].z; acc[i][3] += v.z * w[2].w;
            acc[i][0] += v.w * w[3].x; acc[i][1] += v.w * w[3].y;
            acc[i][2] += v.w * w[3].z; acc[i][3] += v.w * w[3].w;
        }
    }
    float4 bb2 = ((const float4*)(b2 + (size_t)e * 256))[c0];
#pragma unroll
    for (int i = 0; i < 8; i++) {
        int t = tids[g * 8 + i];
        if (t >= 0) {
            float tv = topval[t];
            float4 xv = ((const float4*)(xn2 + (size_t)t * 256))[c0];  // residual re-read (L2)
            float4 o;
            o.x = xv.x + (acc[i][0] + bb2.x) * tv;
            o.y = xv.y + (acc[i][1] + bb2.y) * tv;
            o.z = xv.z + (acc[i][2] + bb2.z) * tv;
            o.w = xv.w + (acc[i][3] + bb2.w) * tv;
            ((float4*)(C + (size_t)t * 256))[c0] = o;
        }
    }
}

// ---------------- wave-per-token: A += gelu(rmsnorm(C, moe_gamma)) ----------------
__global__ void moe_add_kernel(const float* __restrict__ C, float* __restrict__ A,
                               const float* __restrict__ gamma, int T) {
    int wid = threadIdx.x >> 6, lane = threadIdx.x & 63;
    int t = blockIdx.x * 4 + wid;
    if (t >= T) return;
    float4 v = ((const float4*)(C + (size_t)t * 256))[lane];
    float ss = v.x * v.x + v.y * v.y + v.z * v.z + v.w * v.w;
    ss = wave_reduce(ss);
    ss = __shfl(ss, 0, 64);
    float inv = 16.0f / fmaxf(sqrtf(ss), 1e-12f);
    float4 g4 = ((const float4*)gamma)[lane];
    float4* ap = (float4*)(A + (size_t)t * 256) + lane;
    float4 a = *ap;
    a.x += gelu_f(v.x * inv * g4.x); a.y += gelu_f(v.y * inv * g4.y);
    a.z += gelu_f(v.z * inv * g4.z); a.w += gelu_f(v.w * inv * g4.w);
    *ap = a;
}

// ---------------- wave-per-token: end-score attn + head dot -> contribution ----------------
__global__ void endhead_kernel(const float* __restrict__ A, const float* __restrict__ w1,
                               const float* __restrict__ b1, const float* __restrict__ w2,
                               const float* __restrict__ b2, const float* __restrict__ hw,
                               const float* __restrict__ hb, float* __restrict__ contrib,
                               int T) {
    int wid = threadIdx.x >> 6, lane = threadIdx.x & 63;
    int t = blockIdx.x * 4 + wid;
    if (t >= T) return;
    float4 v = ((const float4*)(A + (size_t)t * 256))[lane];
    float p[8];
#pragma unroll
    for (int j = 0; j < 8; j++) p[j] = 0.0f;
    const float xv[4] = {v.x, v.y, v.z, v.w};
#pragma unroll
    for (int c = 0; c < 4; c++) {
        const float4* wr = (const float4*)(w1 + (4 * lane + c) * 8);
        float4 wa = wr[0], wb = wr[1];
        float xx = xv[c];
        p[0] += xx * wa.x; p[1] += xx * wa.y; p[2] += xx * wa.z; p[3] += xx * wa.w;
        p[4] += xx * wb.x; p[5] += xx * wb.y; p[6] += xx * wb.z; p[7] += xx * wb.w;
    }
    float4 h4 = ((const float4*)hw)[lane];
    float hp = gelu_f(v.x) * h4.x + gelu_f(v.y) * h4.y + gelu_f(v.z) * h4.z + gelu_f(v.w) * h4.w;
#pragma unroll
    for (int j = 0; j < 8; j++) p[j] = wave_reduce(p[j]);
    hp = wave_reduce(hp);
    if (lane == 0) {
        float z = b2[0];
#pragma unroll
        for (int j = 0; j < 8; j++) z += tanhf(p[j] + b1[j]) * w2[j];
        float sc = 1.0f / (1.0f + expf(-z));
        contrib[t] = (hp + hb[0]) * sc * (1.0f / (float)N1);
    }
}

// ---------------- per-batch sum of contributions + (block 0) load-balance loss --------
__global__ void finalsum_kernel(const float* __restrict__ contrib,
                                const float* __restrict__ imp, float* __restrict__ out) {
    int b = blockIdx.x, tid = threadIdx.x;
    __shared__ float red[4];
    const float* cb = contrib + (size_t)b * N1;
    float v = cb[tid] + cb[256 + tid];
    if (tid == 0) v += cb[512];
    float s = wave_reduce(v);
    int wid = tid >> 6, lane = tid & 63;
    if (lane == 0) red[wid] = s;
    __syncthreads();
    if (tid == 0) {
        out[b] = red[0] + red[1] + red[2] + red[3];
        if (b == 0) {
            float i0 = imp[0], i1 = imp[1], i2 = imp[2], i3 = imp[3];
            float mean = (i0 + i1 + i2 + i3) * 0.25f;
            float var = ((i0 - mean) * (i0 - mean) + (i1 - mean) * (i1 - mean) +
                         (i2 - mean) * (i2 - mean) + (i3 - mean) * (i3 - mean)) / 3.0f;
            out[64] = var / (mean * mean + 1e-10f);
        }
    }
}

extern "C" void kernel_launch(void* const* d_in, const int* in_sizes, int n_in,
                              void* d_out, int out_size, void* d_ws, size_t ws_size,
                              hipStream_t stream) {
    const float* x    = (const float*)d_in[0];
    const float* embw = (const float*)d_in[3];
    const float* embb = (const float*)d_in[4];
    const float* pos  = (const float*)d_in[5];
    const float* aw1  = (const float*)d_in[6];
    const float* ab1  = (const float*)d_in[7];
    const float* aw2  = (const float*)d_in[8];
    const float* ab2  = (const float*)d_in[9];
    const float* gw   = (const float*)d_in[10];
    const float* gb   = (const float*)d_in[11];
    const float* ew1  = (const float*)d_in[12];
    const float* eb1  = (const float*)d_in[13];
    const float* ew2  = (const float*)d_in[14];
    const float* eb2  = (const float*)d_in[15];
    const float* mg   = (const float*)d_in[16];
    const float* n1g  = (const float*)d_in[17];
    const float* n2g  = (const float*)d_in[18];
    const float* bott = (const float*)d_in[19];
    const float* cw39 = (const float*)d_in[20];
    const float* cw19 = (const float*)d_in[21];
    const float* cw9  = (const float*)d_in[22];
    const float* mpw  = (const float*)d_in[23];
    const float* bng  = (const float*)d_in[24];
    const float* bnb  = (const float*)d_in[25];
    const float* pjw  = (const float*)d_in[26];
    const float* pjb  = (const float*)d_in[27];
    const float* hw   = (const float*)d_in[28];
    const float* hb   = (const float*)d_in[29];
    float* out = (float*)d_out;

    float* W = (float*)d_ws;
    size_t off = 0;
    auto alloc = [&](size_t n) { float* p = W + off; off += n; return p; };
    float* A    = alloc((size_t)NTOK0 * 256);
    float* Bb   = alloc((size_t)NTOK0 * 256);
    float* CD   = alloc((size_t)NTOK1 * 256);
    float* XB   = alloc((size_t)NTOK0 * 32);
    float* sS   = alloc(NTOK0);
    float* ctb  = alloc(NTOK1);
    float* tval = alloc(NTOK1);
    float* imp  = alloc(4);
    float* part = alloc((size_t)BB * GCH * 4 * 256);
    float* wtE  = alloc(128 * 256);
    float* bwt0 = alloc(256 * 32);  float* bwt1 = alloc(256 * 32);
    float* mwt0 = alloc(256 * 32);  float* mwt1 = alloc(256 * 32);
    float* c39t0 = alloc(1248 * 32); float* c39t1 = alloc(1248 * 32);
    float* c19t0 = alloc(608 * 32);  float* c19t1 = alloc(608 * 32);
    float* c9t0  = alloc(288 * 32);  float* c9t1  = alloc(288 * 32);
    if (off & 1) off++;  // 8B-align for ushort4 loads
    unsigned short* ew1b = (unsigned short*)(W + off); off += 262144 / 2;
    unsigned short* ew2b = (unsigned short*)(W + off); off += 262144 / 2;
    unsigned short* pjwb = (unsigned short*)(W + off); off += 65536 / 2;
    int* selpos  = (int*)(W + off); off += (size_t)BB * 1024;
    int* buckets = (int*)(W + off); off += (size_t)4 * NTOK1;
    int* counts  = (int*)(W + off); off += 4;

    zero_kernel<<<1, 64, 0, stream>>>(imp, counts);
    transpose_fused<<<792, 256, 0, stream>>>(embw, wtE, bott, bwt0, bwt1, mpw, mwt0, mwt1,
                                             cw39, c39t0, c39t1, cw19, c19t0, c19t1,
                                             cw9, c9t0, c9t1);
    convert_bf16<<<2304, 256, 0, stream>>>(ew1, ew2, pjw, ew1b, ew2b, pjwb);

    // ===== layer 0 (N=1023) =====
    embed_kernel<<<dim3(64, BB), 256, 0, stream>>>(x, wtE, embb, pos, A);
    norm_attn_kernel<<<NTOK0 / 4, 256, 0, stream>>>(A, A, nullptr, n1g, aw1, ab1, aw2, ab2,
                                                    1, 0, Bb, n2g, NTOK0);
    pw_kernel<<<dim3(64, BB), 256, 0, stream>>>(Bb, bwt0, mwt0, bng, bnb, XB, CD, N0);
    conv_kernel<39, 19, 0><<<dim3(8, BB), 256, 0, stream>>>(XB, c39t0, bng, bnb, CD, N0);
    conv_kernel<19, 9, 32><<<dim3(8, BB), 256, 0, stream>>>(XB, c19t0, bng, bnb, CD, N0);
    conv_kernel<9, 4, 64><<<dim3(8, BB), 256, 0, stream>>>(XB, c9t0, bng, bnb, CD, N0);
    proj_kernel<<<(NTOK0 + 15) / 16, 256, 0, stream>>>(CD, pjwb, pjb, A, NTOK0);

    // ===== layer 1 (prune to 513 tokens); gelu fused into load =====
    norm_attn_kernel<<<NTOK0 / 4, 256, 0, stream>>>(A, Bb, sS, n1g + 256, aw1, ab1, aw2, ab2,
                                                    0, 1, nullptr, nullptr, NTOK0);
    topk_kernel<<<BB, 1024, 0, stream>>>(sS, selpos);
    scatter_kernel<<<dim3(GCH, BB), 256, 0, stream>>>(Bb, sS, selpos, A, part);
    extra_kernel<<<BB, 256, 0, stream>>>(part, A);
    rmsnorm_kernel<<<NTOK1 / 4, 256, 0, stream>>>(A, Bb, n2g + 256, NTOK1);
    gate_kernel<<<(NTOK1 + 255) / 256, 256, 0, stream>>>(Bb, gw, gb, tval, buckets, counts, imp,
                                                         NTOK1);
    ffn_kernel<<<dim3((NTOK1 + 63) / 64, 4), 512, 0, stream>>>(Bb, ew1b, eb1, ew2b, eb2, tval,
                                                               buckets, counts, CD, NTOK1);
    moe_add_kernel<<<NTOK1 / 4, 256, 0, stream>>>(CD, A, mg, NTOK1);
    pw_kernel<<<dim3((N1 + 15) / 16, BB), 256, 0, stream>>>(Bb, bwt1, mwt1, bng + 128, bnb + 128,
                                                            XB, CD, N1);
    conv_kernel<39, 19, 0><<<dim3(5, BB), 256, 0, stream>>>(XB, c39t1, bng + 128, bnb + 128,
                                                            CD, N1);
    conv_kernel<19, 9, 32><<<dim3(5, BB), 256, 0, stream>>>(XB, c19t1, bng + 128, bnb + 128,
                                                            CD, N1);
    conv_kernel<9, 4, 64><<<dim3(5, BB), 256, 0, stream>>>(XB, c9t1, bng + 128, bnb + 128,
                                                           CD, N1);
    proj_kernel<<<(NTOK1 + 15) / 16, 256, 0, stream>>>(CD, pjwb + 32768, pjb + 256, A, NTOK1);
    endhead_kernel<<<NTOK1 / 4, 256, 0, stream>>>(A, aw1, ab1, aw2, ab2, hw, hb, ctb, NTOK1);
    finalsum_kernel<<<BB, 256, 0, stream>>>(ctb, imp, out);
}

// Round 15
// 1165.724 us; speedup vs baseline: 1.2259x; 1.0430x over previous
//
#include <hip/hip_runtime.h>
#include <math.h>

#define BB 64
#define EMB 256
#define N0 1023
#define N1 513
#define NTOK0 (BB * N0)   // 65472
#define NTOK1 (BB * N1)   // 32832
#define GCH 16            // gather chunks per batch

__device__ __forceinline__ float gelu_f(float x) {
    return 0.5f * x * (1.0f + erff(x * 0.7071067811865476f));
}

__device__ __forceinline__ float4 gelu4(float4 v) {
    return make_float4(gelu_f(v.x), gelu_f(v.y), gelu_f(v.z), gelu_f(v.w));
}

__device__ __forceinline__ float wave_reduce(float v) {
#pragma unroll
    for (int o = 32; o > 0; o >>= 1) v += __shfl_down(v, o, 64);
    return v;
}

// bf16 helpers: pack with round-to-nearest-even; unpack = shift
__device__ __forceinline__ unsigned short f2bf(float f) {
    unsigned int u = __float_as_uint(f);
    u = (u + 0x7FFFu + ((u >> 16) & 1u)) >> 16;
    return (unsigned short)u;
}
__device__ __forceinline__ float bf2f(unsigned short h) {
    return __uint_as_float(((unsigned int)h) << 16);
}
__device__ __forceinline__ float4 bf4_to_f4(ushort4 h) {
    return make_float4(bf2f(h.x), bf2f(h.y), bf2f(h.z), bf2f(h.w));
}

// ---------------- fused weight transposes + accumulator zeroing ----------------
__global__ void transpose_fused(const float* __restrict__ embw, float* __restrict__ wtE,
                                const float* __restrict__ bott, float* __restrict__ bwt0,
                                float* __restrict__ bwt1,
                                const float* __restrict__ mpw, float* __restrict__ mwt0,
                                float* __restrict__ mwt1,
                                const float* __restrict__ cw39, float* __restrict__ c39t0,
                                float* __restrict__ c39t1,
                                const float* __restrict__ cw19, float* __restrict__ c19t0,
                                float* __restrict__ c19t1,
                                const float* __restrict__ cw9, float* __restrict__ c9t0,
                                float* __restrict__ c9t1,
                                float* __restrict__ imp, int* __restrict__ counts) {
    int idx = blockIdx.x * 256 + threadIdx.x;
    if (blockIdx.x == 0 && threadIdx.x >= 252) {
        int i = threadIdx.x - 252;
        imp[i] = 0.0f; counts[i] = 0;
    }
    const float* src; float* dst; int O, IK, base;
    if (idx < 32768)       { src = embw;         dst = wtE;   O = 256; IK = 128;  base = 0; }
    else if (idx < 40960)  { src = bott;         dst = bwt0;  O = 32;  IK = 256;  base = 32768; }
    else if (idx < 49152)  { src = bott + 8192;  dst = bwt1;  O = 32;  IK = 256;  base = 40960; }
    else if (idx < 57344)  { src = mpw;          dst = mwt0;  O = 32;  IK = 256;  base = 49152; }
    else if (idx < 65536)  { src = mpw + 8192;   dst = mwt1;  O = 32;  IK = 256;  base = 57344; }
    else if (idx < 105472) { src = cw39;         dst = c39t0; O = 32;  IK = 1248; base = 65536; }
    else if (idx < 145408) { src = cw39 + 39936; dst = c39t1; O = 32;  IK = 1248; base = 105472; }
    else if (idx < 164864) { src = cw19;         dst = c19t0; O = 32;  IK = 608;  base = 145408; }
    else if (idx < 184320) { src = cw19 + 19456; dst = c19t1; O = 32;  IK = 608;  base = 164864; }
    else if (idx < 193536) { src = cw9;          dst = c9t0;  O = 32;  IK = 288;  base = 184320; }
    else if (idx < 202752) { src = cw9 + 9216;   dst = c9t1;  O = 32;  IK = 288;  base = 193536; }
    else return;
    int local = idx - base;
    int o = local / IK, ik = local % IK;
    dst[ik * O + o] = src[local];
}

// ---------------- convert ffn/proj weights to bf16 ----------------
__global__ void convert_bf16(const float* __restrict__ ew1, const float* __restrict__ ew2,
                             const float* __restrict__ pjw, unsigned short* __restrict__ ew1b,
                             unsigned short* __restrict__ ew2b,
                             unsigned short* __restrict__ pjwb) {
    int idx = blockIdx.x * 256 + threadIdx.x;
    if (idx < 262144) ew1b[idx] = f2bf(ew1[idx]);
    else if (idx < 524288) ew2b[idx - 262144] = f2bf(ew2[idx - 262144]);
    else if (idx < 589824) pjwb[idx - 524288] = f2bf(pjw[idx - 524288]);
}

// ---------------- embedding conv (stride 4, K=8, C=16) + bias + pos ----------------
__global__ void embed_kernel(const float* __restrict__ x, const float* __restrict__ wt,
                             const float* __restrict__ emb_b, const float* __restrict__ pos,
                             float* __restrict__ A) {
    int b = blockIdx.y;
    int n0 = blockIdx.x * 16;
    __shared__ float xl[16][68];
    int l0 = 4 * n0;
    for (int idx = threadIdx.x; idx < 16 * 68; idx += 256) {
        int c = idx / 68, j = idx % 68;
        int l = l0 + j;
        xl[c][j] = (l < 4096) ? x[((size_t)b * 16 + c) * 4096 + l] : 0.0f;
    }
    __syncthreads();
    int e = threadIdx.x;
    float acc[16];
#pragma unroll
    for (int i = 0; i < 16; i++) acc[i] = 0.0f;
    for (int k = 0; k < 128; k++) {
        float w = wt[k * 256 + e];
        int c = k >> 3, s = k & 7;
#pragma unroll
        for (int i = 0; i < 16; i++) acc[i] += xl[c][4 * i + s] * w;
    }
    float bb = emb_b[e];
    for (int i = 0; i < 16; i++) {
        int n = n0 + i;
        if (n < N0)
            A[((size_t)b * N0 + n) * 256 + e] = acc[i] + bb + pos[(size_t)n * 256 + e];
    }
}

// ---------------- wave-per-token: rmsnorm + attn score (+pregelu, +second norm) ------
__global__ void norm_attn_kernel(const float* __restrict__ in, float* __restrict__ outv,
                                 float* __restrict__ score_out, const float* __restrict__ g,
                                 const float* __restrict__ w1, const float* __restrict__ b1,
                                 const float* __restrict__ w2, const float* __restrict__ b2,
                                 int scale_out, int pregelu,
                                 float* __restrict__ outv2, const float* __restrict__ g2,
                                 int T) {
    int wid = threadIdx.x >> 6, lane = threadIdx.x & 63;
    int t = blockIdx.x * 4 + wid;
    if (t >= T) return;
    float4 v = ((const float4*)(in + (size_t)t * 256))[lane];
    if (pregelu) v = gelu4(v);
    float4 xn = v;
    if (g != nullptr) {
        float ss = v.x * v.x + v.y * v.y + v.z * v.z + v.w * v.w;
        ss = wave_reduce(ss);
        ss = __shfl(ss, 0, 64);
        float inv = 16.0f / fmaxf(sqrtf(ss), 1e-12f);
        float4 g4 = ((const float4*)g)[lane];
        xn.x = v.x * inv * g4.x; xn.y = v.y * inv * g4.y;
        xn.z = v.z * inv * g4.z; xn.w = v.w * inv * g4.w;
    }
    float p[8];
#pragma unroll
    for (int j = 0; j < 8; j++) p[j] = 0.0f;
    const float xv[4] = {xn.x, xn.y, xn.z, xn.w};
#pragma unroll
    for (int c = 0; c < 4; c++) {
        const float4* wr = (const float4*)(w1 + (4 * lane + c) * 8);
        float4 wa = wr[0], wb = wr[1];
        float xx = xv[c];
        p[0] += xx * wa.x; p[1] += xx * wa.y; p[2] += xx * wa.z; p[3] += xx * wa.w;
        p[4] += xx * wb.x; p[5] += xx * wb.y; p[6] += xx * wb.z; p[7] += xx * wb.w;
    }
#pragma unroll
    for (int j = 0; j < 8; j++) p[j] = wave_reduce(p[j]);
    float sc = 0.0f;
    if (lane == 0) {
        float z = b2[0];
#pragma unroll
        for (int j = 0; j < 8; j++) z += tanhf(p[j] + b1[j]) * w2[j];
        sc = 1.0f / (1.0f + expf(-z));
        if (score_out) score_out[t] = sc;
    }
    sc = __shfl(sc, 0, 64);
    if (outv) {
        float m = scale_out ? sc : 1.0f;
        float4 o = make_float4(xn.x * m, xn.y * m, xn.z * m, xn.w * m);
        ((float4*)(outv + (size_t)t * 256))[lane] = o;
    }
    if (outv2) {
        float ss2 = xn.x * xn.x + xn.y * xn.y + xn.z * xn.z + xn.w * xn.w;
        ss2 = wave_reduce(ss2);
        ss2 = __shfl(ss2, 0, 64);
        float inv2 = 16.0f / fmaxf(sqrtf(ss2), 1e-12f);
        float4 q4 = ((const float4*)g2)[lane];
        float4 o;
        o.x = xn.x * inv2 * q4.x; o.y = xn.y * inv2 * q4.y;
        o.z = xn.z * inv2 * q4.z; o.w = xn.w * inv2 * q4.w;
        ((float4*)(outv2 + (size_t)t * 256))[lane] = o;
    }
}

// ---------------- wave-per-token rmsnorm ----------------
__global__ void rmsnorm_kernel(const float* __restrict__ in, float* __restrict__ out,
                               const float* __restrict__ g, int T) {
    int wid = threadIdx.x >> 6, lane = threadIdx.x & 63;
    int t = blockIdx.x * 4 + wid;
    if (t >= T) return;
    float4 v = ((const float4*)(in + (size_t)t * 256))[lane];
    float ss = v.x * v.x + v.y * v.y + v.z * v.z + v.w * v.w;
    ss = wave_reduce(ss);
    ss = __shfl(ss, 0, 64);
    float inv = 16.0f / fmaxf(sqrtf(ss), 1e-12f);
    float4 g4 = ((const float4*)g)[lane];
    float4 o;
    o.x = v.x * inv * g4.x; o.y = v.y * inv * g4.y;
    o.z = v.z * inv * g4.z; o.w = v.w * inv * g4.w;
    ((float4*)(out + (size_t)t * 256))[lane] = o;
}

// ---------------- pointwise: bottleneck + maxpool path (round-5 proven version) -------
__global__ void pw_kernel(const float* __restrict__ xn, const float* __restrict__ bwt,
                          const float* __restrict__ mwt, const float* __restrict__ bng,
                          const float* __restrict__ bnb, float* __restrict__ xb,
                          float* __restrict__ cat, int N) {
    int b = blockIdx.y;
    int t0 = blockIdx.x * 16;
    const float* xbase = xn + (size_t)b * N * 256;
    __shared__ float xt[18][256];
    __shared__ float xm[16][256];
    for (int idx = threadIdx.x; idx < 18 * 256; idx += 256) {
        int r = idx >> 8, d = idx & 255;
        int t = t0 + r - 1;
        xt[r][d] = (t >= 0 && t < N) ? xbase[(size_t)t * 256 + d] : -INFINITY;
    }
    __syncthreads();
    for (int idx = threadIdx.x; idx < 16 * 256; idx += 256) {
        int r = idx >> 8, d = idx & 255;
        xm[r][d] = fmaxf(fmaxf(xt[r][d], xt[r + 1][d]), xt[r + 2][d]);
    }
    __syncthreads();
    int f = threadIdx.x & 31;
    int gI = threadIdx.x >> 5;
    float accb[2] = {0.0f, 0.0f}, accm[2] = {0.0f, 0.0f};
    for (int d0 = 0; d0 < 256; d0++) {
        float wb = bwt[d0 * 32 + f];
        float wm = mwt[d0 * 32 + f];
#pragma unroll
        for (int i = 0; i < 2; i++) {
            int tt = gI * 2 + i;
            accb[i] += xt[1 + tt][d0] * wb;
            accm[i] += xm[tt][d0] * wm;
        }
    }
    const float BN_DIV = 1.0000050f;
    float scl = bng[96 + f] / BN_DIV;
    float sh = bnb[96 + f];
    for (int i = 0; i < 2; i++) {
        int t = t0 + gI * 2 + i;
        if (t < N) {
            xb[((size_t)b * N + t) * 32 + f] = accb[i];
            cat[((size_t)b * N + t) * 128 + 96 + f] = gelu_f(accm[i] * scl + sh);
        }
    }
}

// ---------------- time conv body (shared LDS buffer, row stride 33) ----------------
template <int K, int P, int COFF>
__device__ __forceinline__ void conv_body(float* __restrict__ xl,
                                          const float* __restrict__ xb,
                                          const float* __restrict__ wt,
                                          const float* __restrict__ bng,
                                          const float* __restrict__ bnb,
                                          float* __restrict__ cat, int N) {
    int b = blockIdx.y;
    int t0 = blockIdx.x * 128;
    const float* xbase = xb + (size_t)b * N * 32;
    const int ROWS = 128 + K;
    for (int idx = threadIdx.x; idx < ROWS * 32; idx += 256) {
        int r = idx >> 5, f = idx & 31;
        int t = t0 - P + r;
        xl[r * 33 + f] = (t >= 0 && t < N) ? xbase[(size_t)t * 32 + f] : 0.0f;
    }
    __syncthreads();
    int fg = threadIdx.x & 7;
    int tg = threadIdx.x >> 3;
    float acc[4][4];
#pragma unroll
    for (int j = 0; j < 4; j++)
#pragma unroll
        for (int c = 0; c < 4; c++) acc[j][c] = 0.0f;
    for (int fi = 0; fi < 32; fi++) {
        float win[4];
#pragma unroll
        for (int j = 0; j < 4; j++) win[j] = xl[(tg * 4 + j) * 33 + fi];
#pragma unroll
        for (int k = 0; k < K; k++) {
            float4 w = ((const float4*)(wt + (fi * K + k) * 32))[fg];
#pragma unroll
            for (int j = 0; j < 4; j++) {
                float xv = win[j];
                acc[j][0] += xv * w.x; acc[j][1] += xv * w.y;
                acc[j][2] += xv * w.z; acc[j][3] += xv * w.w;
            }
#pragma unroll
            for (int j = 0; j < 3; j++) win[j] = win[j + 1];
            win[3] = xl[(tg * 4 + k + 4) * 33 + fi];
        }
    }
    const float BN_DIV = 1.0000050f;
    float4 g4 = ((const float4*)(bng + COFF))[fg];
    float4 b4 = ((const float4*)(bnb + COFF))[fg];
    float sx = g4.x / BN_DIV, sy = g4.y / BN_DIV, sz = g4.z / BN_DIV, sw = g4.w / BN_DIV;
#pragma unroll
    for (int j = 0; j < 4; j++) {
        int t = t0 + tg * 4 + j;
        if (t < N) {
            float4 o;
            o.x = gelu_f(acc[j][0] * sx + b4.x);
            o.y = gelu_f(acc[j][1] * sy + b4.y);
            o.z = gelu_f(acc[j][2] * sz + b4.z);
            o.w = gelu_f(acc[j][3] * sw + b4.w);
            ((float4*)(cat + ((size_t)b * N + t) * 128 + COFF))[fg] = o;
        }
    }
}

// ---------------- fused conv dispatch: blockIdx.z selects branch (fill 256 CUs) -------
__global__ void conv_fused(const float* __restrict__ xb, const float* __restrict__ w39,
                           const float* __restrict__ w19, const float* __restrict__ w9,
                           const float* __restrict__ bng, const float* __restrict__ bnb,
                           float* __restrict__ cat, int N) {
    __shared__ float xl[(128 + 39) * 33];  // max ROWS (K=39) * 33
    if (blockIdx.z == 0) conv_body<39, 19, 0>(xl, xb, w39, bng, bnb, cat, N);
    else if (blockIdx.z == 1) conv_body<19, 9, 32>(xl, xb, w19, bng, bnb, cat, N);
    else conv_body<9, 4, 64>(xl, xb, w9, bng, bnb, cat, N);
}

// ---------------- proj: 4 cols x 4 tokens per thread, bf16 weights ----------------
__global__ void proj_kernel(const float* __restrict__ cat, const unsigned short* __restrict__ pw,
                            const float* __restrict__ pb, float* __restrict__ A, int TN) {
    int t0 = blockIdx.x * 16;
    __shared__ float cl[16][128];
    for (int v = threadIdx.x; v < 16 * 32; v += 256) {
        int r = v >> 5, c4 = v & 31;
        int t = t0 + r;
        ((float4*)cl[r])[c4] = (t < TN) ? ((const float4*)(cat + (size_t)t * 128))[c4]
                                        : make_float4(0.f, 0.f, 0.f, 0.f);
    }
    __syncthreads();
    int c0 = threadIdx.x & 63;
    int g = threadIdx.x >> 6;
    float acc[4][4];
#pragma unroll
    for (int i = 0; i < 4; i++)
#pragma unroll
        for (int j = 0; j < 4; j++) acc[i][j] = 0.0f;
    for (int f = 0; f < 128; f++) {
        float4 w = bf4_to_f4(((const ushort4*)(pw + (size_t)f * 256))[c0]);
        float v0 = cl[g * 4 + 0][f], v1 = cl[g * 4 + 1][f];
        float v2 = cl[g * 4 + 2][f], v3 = cl[g * 4 + 3][f];
        acc[0][0] += v0 * w.x; acc[0][1] += v0 * w.y; acc[0][2] += v0 * w.z; acc[0][3] += v0 * w.w;
        acc[1][0] += v1 * w.x; acc[1][1] += v1 * w.y; acc[1][2] += v1 * w.z; acc[1][3] += v1 * w.w;
        acc[2][0] += v2 * w.x; acc[2][1] += v2 * w.y; acc[2][2] += v2 * w.z; acc[2][3] += v2 * w.w;
        acc[3][0] += v3 * w.x; acc[3][1] += v3 * w.y; acc[3][2] += v3 * w.z; acc[3][3] += v3 * w.w;
    }
    float4 bias = ((const float4*)pb)[c0];
#pragma unroll
    for (int i = 0; i < 4; i++) {
        int t = t0 + g * 4 + i;
        if (t < TN) {
            float4* ap = (float4*)(A + (size_t)t * 256) + c0;
            float4 a = *ap;
            a.x += acc[i][0] + bias.x; a.y += acc[i][1] + bias.y;
            a.z += acc[i][2] + bias.z; a.w += acc[i][3] + bias.w;
            *ap = a;
        }
    }
}

// ---------------- top-512-of-1023 per batch ----------------
__global__ __launch_bounds__(1024) void topk_kernel(const float* __restrict__ s,
                                                    int* __restrict__ selpos) {
    int b = blockIdx.x;
    int tid = threadIdx.x;
    __shared__ float srt[1024];
    __shared__ int buf[1024];
    __shared__ int Gtot_s;
    float val = (tid < N0) ? s[(size_t)b * N0 + tid] : -INFINITY;
    srt[tid] = val;
    __syncthreads();
    for (int ksz = 2; ksz <= 1024; ksz <<= 1) {
        for (int j = ksz >> 1; j > 0; j >>= 1) {
            int ixj = tid ^ j;
            if (ixj > tid) {
                float a = srt[tid], c = srt[ixj];
                bool up = ((tid & ksz) == 0);
                if ((a > c) == up) { srt[tid] = c; srt[ixj] = a; }
            }
            __syncthreads();
        }
    }
    float thr = srt[512];
    __syncthreads();
    int isG = (val > thr) ? 1 : 0;
    int isE = (val == thr) ? 1 : 0;
    buf[tid] = isG;
    __syncthreads();
    for (int off = 1; off < 1024; off <<= 1) {
        int cur = buf[tid];
        int add = (tid >= off) ? buf[tid - off] : 0;
        __syncthreads();
        buf[tid] = cur + add;
        __syncthreads();
    }
    if (tid == 0) Gtot_s = buf[1023];
    __syncthreads();
    int Gtot = Gtot_s;
    int Eneed = 512 - Gtot;
    buf[tid] = isE;
    __syncthreads();
    for (int off = 1; off < 1024; off <<= 1) {
        int cur = buf[tid];
        int add = (tid >= off) ? buf[tid - off] : 0;
        __syncthreads();
        buf[tid] = cur + add;
        __syncthreads();
    }
    int eqExcl = buf[tid] - isE;
    int sel = (isG || (isE && eqExcl < Eneed)) ? 1 : 0;
    __syncthreads();
    buf[tid] = sel;
    __syncthreads();
    for (int off = 1; off < 1024; off <<= 1) {
        int cur = buf[tid];
        int add = (tid >= off) ? buf[tid - off] : 0;
        __syncthreads();
        buf[tid] = cur + add;
        __syncthreads();
    }
    int pos = buf[tid] - sel;
    selpos[b * 1024 + tid] = sel ? pos : -1;
}

// ---------------- scatter: 4 token-groups x float4; 4 partials per chunk ----------------
__global__ void scatter_kernel(const float* __restrict__ xn, const float* __restrict__ s,
                               const int* __restrict__ selpos, float* __restrict__ A,
                               float* __restrict__ part) {
    int b = blockIdx.y;
    int chunk = blockIdx.x;
    int wid = threadIdx.x >> 6, lane = threadIdx.x & 63;
    int t0 = chunk * 64;
    __shared__ float sl[64];
    __shared__ int pl[64];
    if (threadIdx.x < 64) {
        int t = t0 + threadIdx.x;
        sl[threadIdx.x] = (t < N0) ? s[(size_t)b * N0 + t] : 0.0f;
        pl[threadIdx.x] = (t < N0) ? selpos[b * 1024 + t] : -1;
    }
    __syncthreads();
    const float* xbase = xn + ((size_t)b * N0 + t0) * 256;
    float* obase = A + (size_t)b * N1 * 256;
    float4 nonsel = make_float4(0.f, 0.f, 0.f, 0.f);
    int tmax = (t0 + 64 <= N0) ? 64 : (N0 - t0);
    for (int i = wid; i < tmax; i += 4) {
        float sc = sl[i];
        float4 v = ((const float4*)(xbase + (size_t)i * 256))[lane];
        v.x *= sc; v.y *= sc; v.z *= sc; v.w *= sc;
        int p = pl[i];
        if (p >= 0) ((float4*)(obase + (size_t)p * 256))[lane] = v;
        else { nonsel.x += v.x; nonsel.y += v.y; nonsel.z += v.z; nonsel.w += v.w; }
    }
    ((float4*)(part + ((size_t)(b * GCH + chunk) * 4 + wid) * 256))[lane] = nonsel;
}

// ---------------- reduce chunk partials (64 per batch) -> extra row ----------------
__global__ void extra_kernel(const float* __restrict__ part, float* __restrict__ A) {
    int b = blockIdx.x, d = threadIdx.x;
    float acc = 0.0f;
    for (int c = 0; c < GCH * 4; c++) acc += part[((size_t)b * GCH * 4 + c) * 256 + d];
    A[((size_t)b * N1 + 512) * 256 + d] = acc;
}

// ---------------- gate: one token per thread, block-aggregated routing ----------------
__global__ void gate_kernel(const float* __restrict__ xn2, const float* __restrict__ gw,
                            const float* __restrict__ gb, float* __restrict__ topval,
                            int* __restrict__ buckets, int* __restrict__ counts,
                            float* __restrict__ imp, int T) {
    int tid = threadIdx.x;
    int t = blockIdx.x * 256 + tid;
    __shared__ float4 gws[256];
    __shared__ int lcount[4];
    __shared__ int lbase[4];
    __shared__ float limp[4];
    gws[tid] = ((const float4*)gw)[tid];
    if (tid < 4) { lcount[tid] = 0; limp[tid] = 0.0f; }
    __syncthreads();
    bool valid = (t < T);
    float a0 = 0, a1 = 0, a2 = 0, a3 = 0;
    if (valid) {
        const float4* xb4 = (const float4*)(xn2 + (size_t)t * 256);
#pragma unroll 8
        for (int d4 = 0; d4 < 64; d4++) {
            float4 xv = xb4[d4];
            float4 w0 = gws[4 * d4], w1 = gws[4 * d4 + 1];
            float4 w2 = gws[4 * d4 + 2], w3 = gws[4 * d4 + 3];
            a0 += xv.x * w0.x + xv.y * w1.x + xv.z * w2.x + xv.w * w3.x;
            a1 += xv.x * w0.y + xv.y * w1.y + xv.z * w2.y + xv.w * w3.y;
            a2 += xv.x * w0.z + xv.y * w1.z + xv.z * w2.z + xv.w * w3.z;
            a3 += xv.x * w0.w + xv.y * w1.w + xv.z * w2.w + xv.w * w3.w;
        }
    }
    float q0 = 0, q1 = 0, q2 = 0, q3 = 0;
    int eid = 0;
    int lrank = 0;
    if (valid) {
        float l0 = a0 + gb[0], l1 = a1 + gb[1], l2 = a2 + gb[2], l3 = a3 + gb[3];
        float m = fmaxf(fmaxf(l0, l1), fmaxf(l2, l3));
        float e0 = expf(l0 - m), e1 = expf(l1 - m), e2 = expf(l2 - m), e3 = expf(l3 - m);
        float ssum = e0 + e1 + e2 + e3;
        q0 = e0 / ssum; q1 = e1 / ssum; q2 = e2 / ssum; q3 = e3 / ssum;
        float bv = q0;
        if (q1 > bv) { bv = q1; eid = 1; }
        if (q2 > bv) { bv = q2; eid = 2; }
        if (q3 > bv) { bv = q3; eid = 3; }
        topval[t] = bv;
        lrank = atomicAdd(&lcount[eid], 1);
    }
    float r0 = wave_reduce(q0), r1 = wave_reduce(q1);
    float r2 = wave_reduce(q2), r3 = wave_reduce(q3);
    if ((tid & 63) == 0) {
        atomicAdd(&limp[0], r0); atomicAdd(&limp[1], r1);
        atomicAdd(&limp[2], r2); atomicAdd(&limp[3], r3);
    }
    __syncthreads();
    if (tid < 4) {
        lbase[tid] = atomicAdd(&counts[tid], lcount[tid]);
        atomicAdd(&imp[tid], limp[tid]);
    }
    __syncthreads();
    if (valid) buckets[eid * T + lbase[eid] + lrank] = t;
}

// ---------------- expert FFN: 512 threads = 8 waves x 8 tokens, bf16 weights ----------
__global__ __launch_bounds__(512, 1)
void ffn_kernel(const float* __restrict__ xn2, const unsigned short* __restrict__ w1,
                const float* __restrict__ b1, const unsigned short* __restrict__ w2,
                const float* __restrict__ b2, const float* __restrict__ topval,
                const int* __restrict__ buckets, const int* __restrict__ counts,
                float* __restrict__ C, int T) {
    int e = blockIdx.y;
    int cnt = counts[e];
    int base = blockIdx.x * 64;
    if (base >= cnt) return;
    __shared__ float tok[64][256];   // 64 KB; mid overwrites after barrier
    __shared__ int tids[64];
    if (threadIdx.x < 64) {
        int idx = base + threadIdx.x;
        tids[threadIdx.x] = (idx < cnt) ? buckets[e * T + idx] : -1;
    }
    __syncthreads();
    for (int v = threadIdx.x; v < 64 * 64; v += 512) {
        int i = v >> 6, c4 = v & 63;
        int t = tids[i];
        ((float4*)tok[i])[c4] = (t >= 0) ? ((const float4*)(xn2 + (size_t)t * 256))[c4]
                                         : make_float4(0.f, 0.f, 0.f, 0.f);
    }
    __syncthreads();
    int c0 = threadIdx.x & 63;   // cols 4*c0 .. 4*c0+3
    int g = threadIdx.x >> 6;    // wave id 0..7; tokens 8*g .. 8*g+7
    const unsigned short* W1 = w1 + (size_t)e * 65536;
    const unsigned short* W2 = w2 + (size_t)e * 65536;
    float acc[8][4];
#pragma unroll
    for (int i = 0; i < 8; i++)
#pragma unroll
        for (int j = 0; j < 4; j++) acc[i][j] = 0.0f;
    for (int d0 = 0; d0 < 256; d0 += 4) {
        float4 w[4];
#pragma unroll
        for (int u = 0; u < 4; u++)
            w[u] = bf4_to_f4(((const ushort4*)(W1 + (size_t)(d0 + u) * 256))[c0]);
#pragma unroll
        for (int i = 0; i < 8; i++) {
            float4 v = *((const float4*)&tok[g * 8 + i][d0]);  // wave-uniform -> broadcast
            acc[i][0] += v.x * w[0].x; acc[i][1] += v.x * w[0].y;
            acc[i][2] += v.x * w[0].z; acc[i][3] += v.x * w[0].w;
            acc[i][0] += v.y * w[1].x; acc[i][1] += v.y * w[1].y;
            acc[i][2] += v.y * w[1].z; acc[i][3] += v.y * w[1].w;
            acc[i][0] += v.z * w[2].x; acc[i][1] += v.z * w[2].y;
            acc[i][2] += v.z * w[2].z; acc[i][3] += v.z * w[2].w;
            acc[i][0] += v.w * w[3].x; acc[i][1] += v.w * w[3].y;
            acc[i][2] += v.w * w[3].z; acc[i][3] += v.w * w[3].w;
        }
    }
    float4 bb = ((const float4*)(b1 + (size_t)e * 256))[c0];
    __syncthreads();  // phase-1 reads complete before overwriting tok with mid
#pragma unroll
    for (int i = 0; i < 8; i++) {
        float4 m;
        m.x = gelu_f(acc[i][0] + bb.x); m.y = gelu_f(acc[i][1] + bb.y);
        m.z = gelu_f(acc[i][2] + bb.z); m.w = gelu_f(acc[i][3] + bb.w);
        ((float4*)tok[g * 8 + i])[c0] = m;
    }
    __syncthreads();
#pragma unroll
    for (int i = 0; i < 8; i++)
#pragma unroll
        for (int j = 0; j < 4; j++) acc[i][j] = 0.0f;
    for (int d0 = 0; d0 < 256; d0 += 4) {
        float4 w[4];
#pragma unroll
        for (int u = 0; u < 4; u++)
            w[u] = bf4_to_f4(((const ushort4*)(W2 + (size_t)(d0 + u) * 256))[c0]);
#pragma unroll
        for (int i = 0; i < 8; i++) {
            float4 v = *((const float4*)&tok[g * 8 + i][d0]);
            acc[i][0] += v.x * w[0].x; acc[i][1] += v.x * w[0].y;
            acc[i][2] += v.x * w[0].z; acc[i][3] += v.x * w[0].w;
            acc[i][0] += v.y * w[1].x; acc[i][1] += v.y * w[1].y;
            acc[i][2] += v.y * w[1].z; acc[i][3] += v.y * w[1].w;
            acc[i][0] += v.z * w[2].x; acc[i][1] += v.z * w[2].y;
            acc[i][2] += v.z * w[2].z; acc[i][3] += v.z * w[2].w;
            acc[i][0] += v.w * w[3].x; acc[i][1] += v.w * w[3].y;
            acc[i][2] += v.w * w[3].z; acc[i][3] += v.w * w[3].w;
        }
    }
    float4 bb2 = ((const float4*)(b2 + (size_t)e * 256))[c0];
#pragma unroll
    for (int i = 0; i < 8; i++) {
        int t = tids[g * 8 + i];
        if (t >= 0) {
            float tv = topval[t];
            float4 xv = ((const float4*)(xn2 + (size_t)t * 256))[c0];  // residual re-read (L2)
            float4 o;
            o.x = xv.x + (acc[i][0] + bb2.x) * tv;
            o.y = xv.y + (acc[i][1] + bb2.y) * tv;
            o.z = xv.z + (acc[i][2] + bb2.z) * tv;
            o.w = xv.w + (acc[i][3] + bb2.w) * tv;
            ((float4*)(C + (size_t)t * 256))[c0] = o;
        }
    }
}

// ---------------- wave-per-token: A += gelu(rmsnorm(C, moe_gamma)) ----------------
__global__ void moe_add_kernel(const float* __restrict__ C, float* __restrict__ A,
                               const float* __restrict__ gamma, int T) {
    int wid = threadIdx.x >> 6, lane = threadIdx.x & 63;
    int t = blockIdx.x * 4 + wid;
    if (t >= T) return;
    float4 v = ((const float4*)(C + (size_t)t * 256))[lane];
    float ss = v.x * v.x + v.y * v.y + v.z * v.z + v.w * v.w;
    ss = wave_reduce(ss);
    ss = __shfl(ss, 0, 64);
    float inv = 16.0f / fmaxf(sqrtf(ss), 1e-12f);
    float4 g4 = ((const float4*)gamma)[lane];
    float4* ap = (float4*)(A + (size_t)t * 256) + lane;
    float4 a = *ap;
    a.x += gelu_f(v.x * inv * g4.x); a.y += gelu_f(v.y * inv * g4.y);
    a.z += gelu_f(v.z * inv * g4.z); a.w += gelu_f(v.w * inv * g4.w);
    *ap = a;
}

// ---------------- wave-per-token: end-score attn + head dot -> contribution ----------------
__global__ void endhead_kernel(const float* __restrict__ A, const float* __restrict__ w1,
                               const float* __restrict__ b1, const float* __restrict__ w2,
                               const float* __restrict__ b2, const float* __restrict__ hw,
                               const float* __restrict__ hb, float* __restrict__ contrib,
                               int T) {
    int wid = threadIdx.x >> 6, lane = threadIdx.x & 63;
    int t = blockIdx.x * 4 + wid;
    if (t >= T) return;
    float4 v = ((const float4*)(A + (size_t)t * 256))[lane];
    float p[8];
#pragma unroll
    for (int j = 0; j < 8; j++) p[j] = 0.0f;
    const float xv[4] = {v.x, v.y, v.z, v.w};
#pragma unroll
    for (int c = 0; c < 4; c++) {
        const float4* wr = (const float4*)(w1 + (4 * lane + c) * 8);
        float4 wa = wr[0], wb = wr[1];
        float xx = xv[c];
        p[0] += xx * wa.x; p[1] += xx * wa.y; p[2] += xx * wa.z; p[3] += xx * wa.w;
        p[4] += xx * wb.x; p[5] += xx * wb.y; p[6] += xx * wb.z; p[7] += xx * wb.w;
    }
    float4 h4 = ((const float4*)hw)[lane];
    float hp = gelu_f(v.x) * h4.x + gelu_f(v.y) * h4.y + gelu_f(v.z) * h4.z + gelu_f(v.w) * h4.w;
#pragma unroll
    for (int j = 0; j < 8; j++) p[j] = wave_reduce(p[j]);
    hp = wave_reduce(hp);
    if (lane == 0) {
        float z = b2[0];
#pragma unroll
        for (int j = 0; j < 8; j++) z += tanhf(p[j] + b1[j]) * w2[j];
        float sc = 1.0f / (1.0f + expf(-z));
        contrib[t] = (hp + hb[0]) * sc * (1.0f / (float)N1);
    }
}

// ---------------- per-batch sum of contributions + (block 0) load-balance loss --------
__global__ void finalsum_kernel(const float* __restrict__ contrib,
                                const float* __restrict__ imp, float* __restrict__ out) {
    int b = blockIdx.x, tid = threadIdx.x;
    __shared__ float red[4];
    const float* cb = contrib + (size_t)b * N1;
    float v = cb[tid] + cb[256 + tid];
    if (tid == 0) v += cb[512];
    float s = wave_reduce(v);
    int wid = tid >> 6, lane = tid & 63;
    if (lane == 0) red[wid] = s;
    __syncthreads();
    if (tid == 0) {
        out[b] = red[0] + red[1] + red[2] + red[3];
        if (b == 0) {
            float i0 = imp[0], i1 = imp[1], i2 = imp[2], i3 = imp[3];
            float mean = (i0 + i1 + i2 + i3) * 0.25f;
            float var = ((i0 - mean) * (i0 - mean) + (i1 - mean) * (i1 - mean) +
                         (i2 - mean) * (i2 - mean) + (i3 - mean) * (i3 - mean)) / 3.0f;
            out[64] = var / (mean * mean + 1e-10f);
        }
    }
}

extern "C" void kernel_launch(void* const* d_in, const int* in_sizes, int n_in,
                              void* d_out, int out_size, void* d_ws, size_t ws_size,
                              hipStream_t stream) {
    const float* x    = (const float*)d_in[0];
    const float* embw = (const float*)d_in[3];
    const float* embb = (const float*)d_in[4];
    const float* pos  = (const float*)d_in[5];
    const float* aw1  = (const float*)d_in[6];
    const float* ab1  = (const float*)d_in[7];
    const float* aw2  = (const float*)d_in[8];
    const float* ab2  = (const float*)d_in[9];
    const float* gw   = (const float*)d_in[10];
    const float* gb   = (const float*)d_in[11];
    const float* ew1  = (const float*)d_in[12];
    const float* eb1  = (const float*)d_in[13];
    const float* ew2  = (const float*)d_in[14];
    const float* eb2  = (const float*)d_in[15];
    const float* mg   = (const float*)d_in[16];
    const float* n1g  = (const float*)d_in[17];
    const float* n2g  = (const float*)d_in[18];
    const float* bott = (const float*)d_in[19];
    const float* cw39 = (const float*)d_in[20];
    const float* cw19 = (const float*)d_in[21];
    const float* cw9  = (const float*)d_in[22];
    const float* mpw  = (const float*)d_in[23];
    const float* bng  = (const float*)d_in[24];
    const float* bnb  = (const float*)d_in[25];
    const float* pjw  = (const float*)d_in[26];
    const float* pjb  = (const float*)d_in[27];
    const float* hw   = (const float*)d_in[28];
    const float* hb   = (const float*)d_in[29];
    float* out = (float*)d_out;

    float* W = (float*)d_ws;
    size_t off = 0;
    auto alloc = [&](size_t n) { float* p = W + off; off += n; return p; };
    float* A    = alloc((size_t)NTOK0 * 256);
    float* Bb   = alloc((size_t)NTOK0 * 256);
    float* CD   = alloc((size_t)NTOK1 * 256);
    float* XB   = alloc((size_t)NTOK0 * 32);
    float* sS   = alloc(NTOK0);
    float* ctb  = alloc(NTOK1);
    float* tval = alloc(NTOK1);
    float* imp  = alloc(4);
    float* part = alloc((size_t)BB * GCH * 4 * 256);
    float* wtE  = alloc(128 * 256);
    float* bwt0 = alloc(256 * 32);  float* bwt1 = alloc(256 * 32);
    float* mwt0 = alloc(256 * 32);  float* mwt1 = alloc(256 * 32);
    float* c39t0 = alloc(1248 * 32); float* c39t1 = alloc(1248 * 32);
    float* c19t0 = alloc(608 * 32);  float* c19t1 = alloc(608 * 32);
    float* c9t0  = alloc(288 * 32);  float* c9t1  = alloc(288 * 32);
    if (off & 1) off++;  // 8B-align for ushort4 loads
    unsigned short* ew1b = (unsigned short*)(W + off); off += 262144 / 2;
    unsigned short* ew2b = (unsigned short*)(W + off); off += 262144 / 2;
    unsigned short* pjwb = (unsigned short*)(W + off); off += 65536 / 2;
    int* selpos  = (int*)(W + off); off += (size_t)BB * 1024;
    int* buckets = (int*)(W + off); off += (size_t)4 * NTOK1;
    int* counts  = (int*)(W + off); off += 4;

    transpose_fused<<<792, 256, 0, stream>>>(embw, wtE, bott, bwt0, bwt1, mpw, mwt0, mwt1,
                                             cw39, c39t0, c39t1, cw19, c19t0, c19t1,
                                             cw9, c9t0, c9t1, imp, counts);
    convert_bf16<<<2304, 256, 0, stream>>>(ew1, ew2, pjw, ew1b, ew2b, pjwb);

    // ===== layer 0 (N=1023) =====
    embed_kernel<<<dim3(64, BB), 256, 0, stream>>>(x, wtE, embb, pos, A);
    norm_attn_kernel<<<NTOK0 / 4, 256, 0, stream>>>(A, A, nullptr, n1g, aw1, ab1, aw2, ab2,
                                                    1, 0, Bb, n2g, NTOK0);
    pw_kernel<<<dim3(64, BB), 256, 0, stream>>>(Bb, bwt0, mwt0, bng, bnb, XB, CD, N0);
    conv_fused<<<dim3(8, BB, 3), 256, 0, stream>>>(XB, c39t0, c19t0, c9t0, bng, bnb, CD, N0);
    proj_kernel<<<(NTOK0 + 15) / 16, 256, 0, stream>>>(CD, pjwb, pjb, A, NTOK0);

    // ===== layer 1 (prune to 513 tokens); gelu fused into load =====
    norm_attn_kernel<<<NTOK0 / 4, 256, 0, stream>>>(A, Bb, sS, n1g + 256, aw1, ab1, aw2, ab2,
                                                    0, 1, nullptr, nullptr, NTOK0);
    topk_kernel<<<BB, 1024, 0, stream>>>(sS, selpos);
    scatter_kernel<<<dim3(GCH, BB), 256, 0, stream>>>(Bb, sS, selpos, A, part);
    extra_kernel<<<BB, 256, 0, stream>>>(part, A);
    rmsnorm_kernel<<<NTOK1 / 4, 256, 0, stream>>>(A, Bb, n2g + 256, NTOK1);
    gate_kernel<<<(NTOK1 + 255) / 256, 256, 0, stream>>>(Bb, gw, gb, tval, buckets, counts, imp,
                                                         NTOK1);
    ffn_kernel<<<dim3((NTOK1 + 63) / 64, 4), 512, 0, stream>>>(Bb, ew1b, eb1, ew2b, eb2, tval,
                                                               buckets, counts, CD, NTOK1);
    moe_add_kernel<<<NTOK1 / 4, 256, 0, stream>>>(CD, A, mg, NTOK1);
    pw_kernel<<<dim3((N1 + 15) / 16, BB), 256, 0, stream>>>(Bb, bwt1, mwt1, bng + 128, bnb + 128,
                                                            XB, CD, N1);
    conv_fused<<<dim3(5, BB, 3), 256, 0, stream>>>(XB, c39t1, c19t1, c9t1, bng + 128, bnb + 128,
                                                   CD, N1);
    proj_kernel<<<(NTOK1 + 15) / 16, 256, 0, stream>>>(CD, pjwb + 32768, pjb + 256, A, NTOK1);
    endhead_kernel<<<NTOK1 / 4, 256, 0, stream>>>(A, aw1, ab1, aw2, ab2, hw, hb, ctb, NTOK1);
    finalsum_kernel<<<BB, 256, 0, stream>>>(ctb, imp, out);
}